// Round 1
// baseline (3065.816 us; speedup 1.0000x reference)
//
#include <hip/hip_runtime.h>
#include <math.h>

// ---------------------------------------------------------------------------
// SNN forward: psp (K=100 alpha FIR) -> conv/pool/fc -> spike (refractory scan)
// All arithmetic mirrors the JAX reference's f32 association order.
// ---------------------------------------------------------------------------

#define THETA 10.0f

// hh table: hh[q] = h[q-3] for q-3 in [0,99], else 0.  h[k] = (k/10)*exp(1-k/10)
// rk table: rk[i] = REF_KERNEL[i+1] = (-40*(i+1))*exp(1-(i+1)),  i=0..14
__global__ void init_tables(float* hh, float* rk) {
    int i = threadIdx.x;
    if (i < 112) {
        int q = i - 3;
        float val = 0.0f;
        if (q >= 0 && q <= 99) {
            float tf = (float)q;
            float x = tf / 10.0f;                      // f32 divide, matches jnp
            val = x * (float)exp((double)(1.0f - x));  // correctly-rounded expf
        }
        hh[i] = val;
    }
    if (i < 15) {
        float t = (float)(i + 1);
        rk[i] = (-40.0f * t) * (float)exp((double)(1.0f - t));
    }
}

// ---------------------------------------------------------------------------
// psp: causal FIR along T (T=200).  Block = 4 neurons x 64 lanes.
// Lane l (<50) computes outputs t0..t0+3 (t0=4l). x staged in LDS, read b128.
// h window index is thread-uniform -> scalar loads.
// ---------------------------------------------------------------------------
__global__ __launch_bounds__(256) void psp_kernel(const float* __restrict__ in,
                                                  float* __restrict__ out,
                                                  const float* __restrict__ hh,
                                                  int n_neurons) {
    __shared__ __align__(16) float xl[4 * 200];
    const int w = threadIdx.x >> 6;
    const int l = threadIdx.x & 63;
    const long base = (long)blockIdx.x * 800;
    for (int i = threadIdx.x; i < 800; i += 256) xl[i] = in[base + i];
    __syncthreads();
    if (l < 50) {
        const int t0 = l * 4;
        const float* xs = &xl[w * 200];
        float a0 = 0.f, a1 = 0.f, a2 = 0.f, a3 = 0.f;
        const int gmax = (l < 25) ? l : 25;
        for (int g = 0; g <= gmax; ++g) {
            const float4 q = *reinterpret_cast<const float4*>(xs + (t0 - 4 * g));
            const int m0 = 4 * g;
            // d=0 : v = q.w, k base m0-3
            a0 = fmaf(hh[m0 + 0], q.w, a0);
            a1 = fmaf(hh[m0 + 1], q.w, a1);
            a2 = fmaf(hh[m0 + 2], q.w, a2);
            a3 = fmaf(hh[m0 + 3], q.w, a3);
            // d=1 : v = q.z
            a0 = fmaf(hh[m0 + 1], q.z, a0);
            a1 = fmaf(hh[m0 + 2], q.z, a1);
            a2 = fmaf(hh[m0 + 3], q.z, a2);
            a3 = fmaf(hh[m0 + 4], q.z, a3);
            // d=2 : v = q.y
            a0 = fmaf(hh[m0 + 2], q.y, a0);
            a1 = fmaf(hh[m0 + 3], q.y, a1);
            a2 = fmaf(hh[m0 + 4], q.y, a2);
            a3 = fmaf(hh[m0 + 5], q.y, a3);
            // d=3 : v = q.x
            a0 = fmaf(hh[m0 + 3], q.x, a0);
            a1 = fmaf(hh[m0 + 4], q.x, a1);
            a2 = fmaf(hh[m0 + 5], q.x, a2);
            a3 = fmaf(hh[m0 + 6], q.x, a3);
        }
        const long ob = base + (long)w * 200 + t0;
        out[ob + 0] = a0; out[ob + 1] = a1; out[ob + 2] = a2; out[ob + 3] = a3;
    }
}

// ---------------------------------------------------------------------------
// Fused psp -> 2x2 sum-pool (*11).  Per-pixel psp kept in separate
// accumulators, summed row-major at the end => bit-identical to unfused.
// Block = 4 output neurons x 64 lanes; 16 input series staged in LDS.
// ---------------------------------------------------------------------------
__global__ __launch_bounds__(256) void psppool_kernel(const float* __restrict__ in,
                                                      float* __restrict__ out,
                                                      const float* __restrict__ hh,
                                                      int C, int HO, int WO) {
    __shared__ __align__(16) float xl[16 * 200];
    const int w = threadIdx.x >> 6;
    const int l = threadIdx.x & 63;
    const int o0 = blockIdx.x * 4;
    const int H = 2 * HO, W = 2 * WO;
    for (int i = threadIdx.x; i < 3200; i += 256) {
        int px = i / 200, off = i - px * 200;
        int o = o0 + (px >> 2);
        int wi = px & 3;
        int wo = o % WO; int tmp = o / WO;
        int ho = tmp % HO; tmp /= HO;
        int c = tmp % C;  int b = tmp / C;
        int hin = 2 * ho + (wi >> 1), win = 2 * wo + (wi & 1);
        long nin = (((long)(b * C + c) * H + hin) * W + win);
        xl[i] = in[nin * 200 + off];
    }
    __syncthreads();
    if (l < 50) {
        const int t0 = l * 4;
        const float* xs = &xl[(w * 4) * 200];
        float a[4][4];
        #pragma unroll
        for (int i = 0; i < 4; ++i)
            #pragma unroll
            for (int p = 0; p < 4; ++p) a[i][p] = 0.0f;
        const int gmax = (l < 25) ? l : 25;
        for (int g = 0; g <= gmax; ++g) {
            const int m0 = 4 * g;
            #pragma unroll
            for (int p = 0; p < 4; ++p) {
                const float4 q = *reinterpret_cast<const float4*>(xs + p * 200 + (t0 - 4 * g));
                float vv[4] = {q.w, q.z, q.y, q.x};
                #pragma unroll
                for (int d = 0; d < 4; ++d) {
                    #pragma unroll
                    for (int i = 0; i < 4; ++i)
                        a[i][p] = fmaf(hh[m0 + d + i], vv[d], a[i][p]);
                }
            }
        }
        const long ob = (long)(o0 + w) * 200 + t0;
        #pragma unroll
        for (int i = 0; i < 4; ++i) {
            float s = ((a[i][0] + a[i][1]) + a[i][2]) + a[i][3];
            out[ob + i] = s * 11.0f;
        }
    }
}

// ---------------------------------------------------------------------------
// Spatial conv at each t.  Thread = 64 t-lanes (coalesced), 4 co accumulators.
// Skipping OOB taps == zero-padding bitwise (adds exact 0).
// ---------------------------------------------------------------------------
template <int K, int PAD>
__global__ __launch_bounds__(64) void conv_kernel(const float* __restrict__ x,
                                                  const float* __restrict__ wt,
                                                  float* __restrict__ out,
                                                  int Ci, int Co, int H, int W,
                                                  int HO, int WO) {
    const int l = threadIdx.x;
    const int wo = blockIdx.x % WO;
    const int ho = blockIdx.x / WO;
    const int co0 = blockIdx.y * 4;
    const int b = blockIdx.z;
    const long wstride = (long)Ci * K * K;
    for (int tt = l; tt < 200; tt += 64) {
        float a0 = 0.f, a1 = 0.f, a2 = 0.f, a3 = 0.f;
        for (int ci = 0; ci < Ci; ++ci) {
            #pragma unroll
            for (int kh = 0; kh < K; ++kh) {
                const int hi = ho + kh - PAD;
                if (hi < 0 || hi >= H) continue;
                #pragma unroll
                for (int kw = 0; kw < K; ++kw) {
                    const int wi = wo + kw - PAD;
                    if (wi < 0 || wi >= W) continue;
                    const float v = x[(((long)(b * Ci + ci) * H + hi) * W + wi) * 200 + tt];
                    const float* wp = &wt[((long)co0 * Ci + ci) * K * K + kh * K + kw];
                    a0 = fmaf(wp[0], v, a0);
                    a1 = fmaf(wp[wstride], v, a1);
                    a2 = fmaf(wp[2 * wstride], v, a2);
                    a3 = fmaf(wp[3 * wstride], v, a3);
                }
            }
        }
        const long hwN = (long)HO * WO;
        const long ob = ((long)(b * Co + co0) * HO + ho) * WO + wo;
        out[ob * 200 + tt]              = a0;
        out[(ob + hwN) * 200 + tt]      = a1;
        out[(ob + 2 * hwN) * 200 + tt]  = a2;
        out[(ob + 3 * hwN) * 200 + tt]  = a3;
    }
}

// ---------------------------------------------------------------------------
// Refractory spike scan: thread per neuron, 15-register pend shift, branchless.
// fmaf(s, rk, p) is bit-exact vs (s*rk)+p for s in {0,1}.  In-place safe.
// ---------------------------------------------------------------------------
__global__ __launch_bounds__(256) void spike_kernel(float* v, float* s,
                                                    const float* __restrict__ rkt,
                                                    int n) {
    const int nid = blockIdx.x * 256 + threadIdx.x;
    if (nid >= n) return;
    float rk[15];
    #pragma unroll
    for (int i = 0; i < 15; ++i) rk[i] = rkt[i];
    float p[15];
    #pragma unroll
    for (int i = 0; i < 15; ++i) p[i] = 0.0f;
    float* vp = v + (long)nid * 200;
    float* sp = s + (long)nid * 200;
    for (int t = 0; t < 200; ++t) {
        const float u = vp[t] + p[0];
        const float sv = (u >= THETA) ? 1.0f : 0.0f;
        sp[t] = sv;
        #pragma unroll
        for (int i = 0; i < 14; ++i) p[i] = fmaf(sv, rk[i], p[i + 1]);
        p[14] = sv * rk[14];
    }
}

// ---------------------------------------------------------------------------
// FC: out[b,k,t] = sum_{c,h,w} x[b,c,h,w,t] * Wfc[k,c,h,w]
// ---------------------------------------------------------------------------
__global__ __launch_bounds__(64) void fc_kernel(const float* __restrict__ x,
                                                const float* __restrict__ wf,
                                                float* __restrict__ out) {
    const int k = blockIdx.x, b = blockIdx.y, l = threadIdx.x;
    for (int tt = l; tt < 200; tt += 64) {
        float acc = 0.0f;
        for (int c = 0; c < 64; ++c)
            #pragma unroll
            for (int h = 0; h < 6; ++h)
                #pragma unroll
                for (int w = 0; w < 6; ++w) {
                    const float v = x[(((long)(b * 64 + c) * 6 + h) * 6 + w) * 200 + tt];
                    acc = fmaf(wf[((k * 64 + c) * 6 + h) * 6 + w], v, acc);
                }
        out[((long)b * 10 + k) * 200 + tt] = acc;
    }
}

extern "C" void kernel_launch(void* const* d_in, const int* in_sizes, int n_in,
                              void* d_out, int out_size, void* d_ws, size_t ws_size,
                              hipStream_t stream) {
    const float* x_in = (const float*)d_in[0];  // (4,2,50,50,200)
    const float* W1 = (const float*)d_in[1];    // (16,2,5,5)
    const float* W2 = (const float*)d_in[2];    // (32,16,3,3)
    const float* W3 = (const float*)d_in[3];    // (64,32,3,3)
    const float* W4 = (const float*)d_in[4];    // (64,64,3,3)
    const float* Wfc = (const float*)d_in[5];   // (10,64,6,6)
    float* outp = (float*)d_out;                // (4,10,200)

    float* ws = (float*)d_ws;
    float* hh = ws;                 // 112
    float* rk = ws + 112;           // 15
    float* A = ws + 128;            // 7,372,800
    float* B = A + 7372800;         // 29,491,200
    float* C = B + 29491200;        // 14,745,600

    hipLaunchKernelGGL(init_tables, dim3(1), dim3(128), 0, stream, hh, rk);

    // p0 = psp(input): 4*2*50*50 = 20000 neurons
    hipLaunchKernelGGL(psp_kernel, dim3(5000), dim3(256), 0, stream, x_in, A, hh, 20000);
    // c1 = conv1(p0): (4,16,48,48,200)
    hipLaunchKernelGGL((conv_kernel<5, 1>), dim3(48 * 48, 4, 4), dim3(64), 0, stream,
                       A, W1, B, 2, 16, 50, 50, 48, 48);
    // s1 = spike(c1) in-place: 147456 neurons
    hipLaunchKernelGGL(spike_kernel, dim3((147456 + 255) / 256), dim3(256), 0, stream, B, B, rk, 147456);
    // o1 = pool(psp(s1)): out (4,16,24,24,200) = 36864 neurons
    hipLaunchKernelGGL(psppool_kernel, dim3(36864 / 4), dim3(256), 0, stream, B, A, hh, 16, 24, 24);
    // s2 = spike(o1)
    hipLaunchKernelGGL(spike_kernel, dim3((36864 + 255) / 256), dim3(256), 0, stream, A, A, rk, 36864);
    // p2 = psp(s2)
    hipLaunchKernelGGL(psp_kernel, dim3(36864 / 4), dim3(256), 0, stream, A, B, hh, 36864);
    // c2 = conv2(p2): (4,32,24,24,200)
    hipLaunchKernelGGL((conv_kernel<3, 1>), dim3(24 * 24, 8, 4), dim3(64), 0, stream,
                       B, W2, C, 16, 32, 24, 24, 24, 24);
    // s3 = spike(c2): 73728
    hipLaunchKernelGGL(spike_kernel, dim3((73728 + 255) / 256), dim3(256), 0, stream, C, C, rk, 73728);
    // o2 = pool(psp(s3)): out (4,32,12,12,200) = 18432
    hipLaunchKernelGGL(psppool_kernel, dim3(18432 / 4), dim3(256), 0, stream, C, A, hh, 32, 12, 12);
    // s4
    hipLaunchKernelGGL(spike_kernel, dim3((18432 + 255) / 256), dim3(256), 0, stream, A, A, rk, 18432);
    // p4 = psp(s4)
    hipLaunchKernelGGL(psp_kernel, dim3(18432 / 4), dim3(256), 0, stream, A, B, hh, 18432);
    // c3 = conv3(p4): (4,64,12,12,200)
    hipLaunchKernelGGL((conv_kernel<3, 1>), dim3(12 * 12, 16, 4), dim3(64), 0, stream,
                       B, W3, C, 32, 64, 12, 12, 12, 12);
    // s5: 36864
    hipLaunchKernelGGL(spike_kernel, dim3((36864 + 255) / 256), dim3(256), 0, stream, C, C, rk, 36864);
    // o3 = pool(psp(s5)): out (4,64,6,6,200) = 9216
    hipLaunchKernelGGL(psppool_kernel, dim3(9216 / 4), dim3(256), 0, stream, C, A, hh, 64, 6, 6);
    // s6
    hipLaunchKernelGGL(spike_kernel, dim3((9216 + 255) / 256), dim3(256), 0, stream, A, A, rk, 9216);
    // p6 = psp(s6)
    hipLaunchKernelGGL(psp_kernel, dim3(9216 / 4), dim3(256), 0, stream, A, B, hh, 9216);
    // c4 = conv4(p6): (4,64,6,6,200)
    hipLaunchKernelGGL((conv_kernel<3, 1>), dim3(6 * 6, 16, 4), dim3(64), 0, stream,
                       B, W4, C, 64, 64, 6, 6, 6, 6);
    // s7: 9216
    hipLaunchKernelGGL(spike_kernel, dim3((9216 + 255) / 256), dim3(256), 0, stream, C, C, rk, 9216);
    // p7 = psp(s7)
    hipLaunchKernelGGL(psp_kernel, dim3(9216 / 4), dim3(256), 0, stream, C, B, hh, 9216);
    // fc: (4,10,200)
    hipLaunchKernelGGL(fc_kernel, dim3(10, 4), dim3(64), 0, stream, B, Wfc, A);
    // final spike -> d_out: 40 neurons
    hipLaunchKernelGGL(spike_kernel, dim3(1), dim3(256), 0, stream, A, outp, rk, 40);
    (void)in_sizes; (void)n_in; (void)out_size; (void)ws_size;
}

// Round 2
// 1716.330 us; speedup vs baseline: 1.7863x; 1.7863x over previous
//
#include <hip/hip_runtime.h>
#include <math.h>

// ---------------------------------------------------------------------------
// SNN forward: psp (K=100 alpha FIR) -> conv/pool/fc -> spike (refractory scan)
// All arithmetic mirrors the JAX reference's f32 association order.
// Round 2: conv rewritten — float4-of-t per thread, transposed weights
// (scalar s_loads), 8/16 co accumulators => 32/64 FMA per 16B load.
// ---------------------------------------------------------------------------

#define THETA 10.0f

// hh table: hh[q] = h[q-3] for q-3 in [0,99], else 0.  h[k] = (k/10)*exp(1-k/10)
// rk table: rk[i] = REF_KERNEL[i+1] = (-40*(i+1))*exp(1-(i+1)),  i=0..14
__global__ void init_tables(float* hh, float* rk) {
    int i = threadIdx.x;
    if (i < 112) {
        int q = i - 3;
        float val = 0.0f;
        if (q >= 0 && q <= 99) {
            float tf = (float)q;
            float x = tf / 10.0f;                      // f32 divide, matches jnp
            val = x * (float)exp((double)(1.0f - x));  // correctly-rounded expf
        }
        hh[i] = val;
    }
    if (i < 15) {
        float t = (float)(i + 1);
        rk[i] = (-40.0f * t) * (float)exp((double)(1.0f - t));
    }
}

// wt_t[tap*Co + co] = w[co*tapN + tap]
__global__ void transpose_w(const float* __restrict__ w, float* __restrict__ o,
                            int Co, int tapN) {
    int i = blockIdx.x * 256 + threadIdx.x;
    if (i < Co * tapN) {
        int co = i / tapN, tp = i - co * tapN;
        o[tp * Co + co] = w[i];
    }
}

// ---------------------------------------------------------------------------
// psp: causal FIR along T (T=200).  Block = 4 neurons x 64 lanes.
// Lane l (<50) computes outputs t0..t0+3 (t0=4l). x staged in LDS, read b128.
// ---------------------------------------------------------------------------
__global__ __launch_bounds__(256) void psp_kernel(const float* __restrict__ in,
                                                  float* __restrict__ out,
                                                  const float* __restrict__ hh,
                                                  int n_neurons) {
    __shared__ __align__(16) float xl[4 * 200];
    const int w = threadIdx.x >> 6;
    const int l = threadIdx.x & 63;
    const long base = (long)blockIdx.x * 800;
    for (int i = threadIdx.x; i < 800; i += 256) xl[i] = in[base + i];
    __syncthreads();
    if (l < 50) {
        const int t0 = l * 4;
        const float* xs = &xl[w * 200];
        float a0 = 0.f, a1 = 0.f, a2 = 0.f, a3 = 0.f;
        const int gmax = (l < 25) ? l : 25;
        for (int g = 0; g <= gmax; ++g) {
            const float4 q = *reinterpret_cast<const float4*>(xs + (t0 - 4 * g));
            const int m0 = 4 * g;
            a0 = fmaf(hh[m0 + 0], q.w, a0);
            a1 = fmaf(hh[m0 + 1], q.w, a1);
            a2 = fmaf(hh[m0 + 2], q.w, a2);
            a3 = fmaf(hh[m0 + 3], q.w, a3);
            a0 = fmaf(hh[m0 + 1], q.z, a0);
            a1 = fmaf(hh[m0 + 2], q.z, a1);
            a2 = fmaf(hh[m0 + 3], q.z, a2);
            a3 = fmaf(hh[m0 + 4], q.z, a3);
            a0 = fmaf(hh[m0 + 2], q.y, a0);
            a1 = fmaf(hh[m0 + 3], q.y, a1);
            a2 = fmaf(hh[m0 + 4], q.y, a2);
            a3 = fmaf(hh[m0 + 5], q.y, a3);
            a0 = fmaf(hh[m0 + 3], q.x, a0);
            a1 = fmaf(hh[m0 + 4], q.x, a1);
            a2 = fmaf(hh[m0 + 5], q.x, a2);
            a3 = fmaf(hh[m0 + 6], q.x, a3);
        }
        const long ob = base + (long)w * 200 + t0;
        out[ob + 0] = a0; out[ob + 1] = a1; out[ob + 2] = a2; out[ob + 3] = a3;
    }
}

// ---------------------------------------------------------------------------
// Fused psp -> 2x2 sum-pool (*11).  Bit-identical to unfused (separate
// per-pixel accumulators, row-major final sum).
// ---------------------------------------------------------------------------
__global__ __launch_bounds__(256) void psppool_kernel(const float* __restrict__ in,
                                                      float* __restrict__ out,
                                                      const float* __restrict__ hh,
                                                      int C, int HO, int WO) {
    __shared__ __align__(16) float xl[16 * 200];
    const int w = threadIdx.x >> 6;
    const int l = threadIdx.x & 63;
    const int o0 = blockIdx.x * 4;
    const int H = 2 * HO, W = 2 * WO;
    for (int i = threadIdx.x; i < 3200; i += 256) {
        int px = i / 200, off = i - px * 200;
        int o = o0 + (px >> 2);
        int wi = px & 3;
        int wo = o % WO; int tmp = o / WO;
        int ho = tmp % HO; tmp /= HO;
        int c = tmp % C;  int b = tmp / C;
        int hin = 2 * ho + (wi >> 1), win = 2 * wo + (wi & 1);
        long nin = (((long)(b * C + c) * H + hin) * W + win);
        xl[i] = in[nin * 200 + off];
    }
    __syncthreads();
    if (l < 50) {
        const int t0 = l * 4;
        const float* xs = &xl[(w * 4) * 200];
        float a[4][4];
        #pragma unroll
        for (int i = 0; i < 4; ++i)
            #pragma unroll
            for (int p = 0; p < 4; ++p) a[i][p] = 0.0f;
        const int gmax = (l < 25) ? l : 25;
        for (int g = 0; g <= gmax; ++g) {
            const int m0 = 4 * g;
            #pragma unroll
            for (int p = 0; p < 4; ++p) {
                const float4 q = *reinterpret_cast<const float4*>(xs + p * 200 + (t0 - 4 * g));
                float vv[4] = {q.w, q.z, q.y, q.x};
                #pragma unroll
                for (int d = 0; d < 4; ++d) {
                    #pragma unroll
                    for (int i = 0; i < 4; ++i)
                        a[i][p] = fmaf(hh[m0 + d + i], vv[d], a[i][p]);
                }
            }
        }
        const long ob = (long)(o0 + w) * 200 + t0;
        #pragma unroll
        for (int i = 0; i < 4; ++i) {
            float s = ((a[i][0] + a[i][1]) + a[i][2]) + a[i][3];
            out[ob + i] = s * 11.0f;
        }
    }
}

// ---------------------------------------------------------------------------
// Spatial conv.  Block = 256 thr = 4 waves = 4 output pixels.  Lane covers
// 4 consecutive t (float4 load, coalesced).  COG co-accumulators per thread;
// weights pre-transposed to [tap][Co] => thread-uniform s_loads.
// FMA order per (co,t): ci,kh,kw ascending — identical to reference path.
// ---------------------------------------------------------------------------
template <int K, int PAD, int CI, int COG>
__global__ __launch_bounds__(256) void conv_kernel(const float* __restrict__ x,
                                                   const float* __restrict__ wt,
                                                   float* __restrict__ out,
                                                   int Co, int H, int W,
                                                   int HO, int WO) {
    const int l = threadIdx.x & 63;
    const int wv = threadIdx.x >> 6;
    if (l >= 50) return;
    const int p = blockIdx.x * 4 + wv;
    const int wo = p % WO, ho = p / WO;
    const int co0 = blockIdx.y * COG;
    const int b = blockIdx.z;
    const int t0 = l * 4;
    float4 acc[COG];
    #pragma unroll
    for (int c = 0; c < COG; ++c) acc[c] = make_float4(0.f, 0.f, 0.f, 0.f);
    const float* xb = x + ((long)b * CI * H * W) * 200 + t0;
    for (int ci = 0; ci < CI; ++ci) {
        #pragma unroll
        for (int kh = 0; kh < K; ++kh) {
            const int hi = ho + kh - PAD;
            if (hi < 0 || hi >= H) continue;
            #pragma unroll
            for (int kw = 0; kw < K; ++kw) {
                const int wi = wo + kw - PAD;
                if (wi < 0 || wi >= W) continue;
                const float4 v = *reinterpret_cast<const float4*>(
                    xb + ((long)(ci * H + hi) * W + wi) * 200);
                const float* wp = wt + ((ci * K + kh) * K + kw) * Co + co0;
                #pragma unroll
                for (int c = 0; c < COG; ++c) {
                    const float wv_ = wp[c];
                    acc[c].x = fmaf(wv_, v.x, acc[c].x);
                    acc[c].y = fmaf(wv_, v.y, acc[c].y);
                    acc[c].z = fmaf(wv_, v.z, acc[c].z);
                    acc[c].w = fmaf(wv_, v.w, acc[c].w);
                }
            }
        }
    }
    const long hwN = (long)HO * WO;
    const long ob = ((long)(b * Co + co0) * HO + ho) * WO + wo;
    #pragma unroll
    for (int c = 0; c < COG; ++c)
        *reinterpret_cast<float4*>(out + (ob + c * hwN) * 200 + t0) = acc[c];
}

// ---------------------------------------------------------------------------
// Refractory spike scan: thread per neuron, 15-register pend shift, branchless.
// ---------------------------------------------------------------------------
__global__ __launch_bounds__(256) void spike_kernel(float* v, float* s,
                                                    const float* __restrict__ rkt,
                                                    int n) {
    const int nid = blockIdx.x * 256 + threadIdx.x;
    if (nid >= n) return;
    float rk[15];
    #pragma unroll
    for (int i = 0; i < 15; ++i) rk[i] = rkt[i];
    float p[15];
    #pragma unroll
    for (int i = 0; i < 15; ++i) p[i] = 0.0f;
    float* vp = v + (long)nid * 200;
    float* sp = s + (long)nid * 200;
    for (int t = 0; t < 200; ++t) {
        const float u = vp[t] + p[0];
        const float sv = (u >= THETA) ? 1.0f : 0.0f;
        sp[t] = sv;
        #pragma unroll
        for (int i = 0; i < 14; ++i) p[i] = fmaf(sv, rk[i], p[i + 1]);
        p[14] = sv * rk[14];
    }
}

// ---------------------------------------------------------------------------
// FC: out[b,k,t] = sum_{c,h,w} x[b,c,h,w,t] * Wfc[k,c,h,w]   (float4 over t)
// ---------------------------------------------------------------------------
__global__ __launch_bounds__(64) void fc_kernel(const float* __restrict__ x,
                                                const float* __restrict__ wf,
                                                float* __restrict__ out) {
    const int k = blockIdx.x, b = blockIdx.y, l = threadIdx.x;
    if (l >= 50) return;
    const int t0 = l * 4;
    float4 acc = make_float4(0.f, 0.f, 0.f, 0.f);
    for (int c = 0; c < 64; ++c)
        #pragma unroll
        for (int h = 0; h < 6; ++h)
            #pragma unroll
            for (int w = 0; w < 6; ++w) {
                const float4 v = *reinterpret_cast<const float4*>(
                    x + (((long)(b * 64 + c) * 6 + h) * 6 + w) * 200 + t0);
                const float wv_ = wf[((k * 64 + c) * 6 + h) * 6 + w];
                acc.x = fmaf(wv_, v.x, acc.x);
                acc.y = fmaf(wv_, v.y, acc.y);
                acc.z = fmaf(wv_, v.z, acc.z);
                acc.w = fmaf(wv_, v.w, acc.w);
            }
    *reinterpret_cast<float4*>(out + ((long)b * 10 + k) * 200 + t0) = acc;
}

extern "C" void kernel_launch(void* const* d_in, const int* in_sizes, int n_in,
                              void* d_out, int out_size, void* d_ws, size_t ws_size,
                              hipStream_t stream) {
    const float* x_in = (const float*)d_in[0];  // (4,2,50,50,200)
    const float* W1 = (const float*)d_in[1];    // (16,2,5,5)
    const float* W2 = (const float*)d_in[2];    // (32,16,3,3)
    const float* W3 = (const float*)d_in[3];    // (64,32,3,3)
    const float* W4 = (const float*)d_in[4];    // (64,64,3,3)
    const float* Wfc = (const float*)d_in[5];   // (10,64,6,6)
    float* outp = (float*)d_out;                // (4,10,200)

    float* ws = (float*)d_ws;
    float* hh  = ws;                  // 112
    float* rk  = ws + 112;            // 15 (+1 pad)
    float* wt1 = ws + 128;            // 16*50   = 800
    float* wt2 = wt1 + 800;           // 32*144  = 4608
    float* wt3 = wt2 + 4608;          // 64*288  = 18432
    float* wt4 = wt3 + 18432;         // 64*576  = 36864
    float* A   = wt4 + 36864;         // 7,372,800   (offset 60832, 16-aligned)
    float* B   = A + 7372800;         // 29,491,200
    float* C   = B + 29491200;        // 14,745,600

    hipLaunchKernelGGL(init_tables, dim3(1), dim3(128), 0, stream, hh, rk);
    hipLaunchKernelGGL(transpose_w, dim3(4),   dim3(256), 0, stream, W1, wt1, 16, 50);
    hipLaunchKernelGGL(transpose_w, dim3(18),  dim3(256), 0, stream, W2, wt2, 32, 144);
    hipLaunchKernelGGL(transpose_w, dim3(72),  dim3(256), 0, stream, W3, wt3, 64, 288);
    hipLaunchKernelGGL(transpose_w, dim3(144), dim3(256), 0, stream, W4, wt4, 64, 576);

    // p0 = psp(input): 20000 neurons
    hipLaunchKernelGGL(psp_kernel, dim3(5000), dim3(256), 0, stream, x_in, A, hh, 20000);
    // c1 = conv1(p0): (4,16,48,48,200)
    hipLaunchKernelGGL((conv_kernel<5, 1, 2, 16>), dim3(2304 / 4, 1, 4), dim3(256), 0, stream,
                       A, wt1, B, 16, 50, 50, 48, 48);
    // s1 = spike(c1) in-place: 147456 neurons
    hipLaunchKernelGGL(spike_kernel, dim3(576), dim3(256), 0, stream, B, B, rk, 147456);
    // o1 = pool(psp(s1)): (4,16,24,24,200) = 36864 neurons
    hipLaunchKernelGGL(psppool_kernel, dim3(36864 / 4), dim3(256), 0, stream, B, A, hh, 16, 24, 24);
    // s2 = spike(o1)
    hipLaunchKernelGGL(spike_kernel, dim3(144), dim3(256), 0, stream, A, A, rk, 36864);
    // p2 = psp(s2)
    hipLaunchKernelGGL(psp_kernel, dim3(36864 / 4), dim3(256), 0, stream, A, B, hh, 36864);
    // c2 = conv2(p2): (4,32,24,24,200)
    hipLaunchKernelGGL((conv_kernel<3, 1, 16, 16>), dim3(576 / 4, 2, 4), dim3(256), 0, stream,
                       B, wt2, C, 32, 24, 24, 24, 24);
    // s3 = spike(c2): 73728
    hipLaunchKernelGGL(spike_kernel, dim3(288), dim3(256), 0, stream, C, C, rk, 73728);
    // o2 = pool(psp(s3)): (4,32,12,12,200) = 18432
    hipLaunchKernelGGL(psppool_kernel, dim3(18432 / 4), dim3(256), 0, stream, C, A, hh, 32, 12, 12);
    // s4
    hipLaunchKernelGGL(spike_kernel, dim3(72), dim3(256), 0, stream, A, A, rk, 18432);
    // p4 = psp(s4)
    hipLaunchKernelGGL(psp_kernel, dim3(18432 / 4), dim3(256), 0, stream, A, B, hh, 18432);
    // c3 = conv3(p4): (4,64,12,12,200)
    hipLaunchKernelGGL((conv_kernel<3, 1, 32, 8>), dim3(144 / 4, 8, 4), dim3(256), 0, stream,
                       B, wt3, C, 64, 12, 12, 12, 12);
    // s5: 36864
    hipLaunchKernelGGL(spike_kernel, dim3(144), dim3(256), 0, stream, C, C, rk, 36864);
    // o3 = pool(psp(s5)): (4,64,6,6,200) = 9216
    hipLaunchKernelGGL(psppool_kernel, dim3(9216 / 4), dim3(256), 0, stream, C, A, hh, 64, 6, 6);
    // s6
    hipLaunchKernelGGL(spike_kernel, dim3(36), dim3(256), 0, stream, A, A, rk, 9216);
    // p6 = psp(s6)
    hipLaunchKernelGGL(psp_kernel, dim3(9216 / 4), dim3(256), 0, stream, A, B, hh, 9216);
    // c4 = conv4(p6): (4,64,6,6,200)
    hipLaunchKernelGGL((conv_kernel<3, 1, 64, 8>), dim3(36 / 4, 8, 4), dim3(256), 0, stream,
                       B, wt4, C, 64, 6, 6, 6, 6);
    // s7: 9216
    hipLaunchKernelGGL(spike_kernel, dim3(36), dim3(256), 0, stream, C, C, rk, 9216);
    // p7 = psp(s7)
    hipLaunchKernelGGL(psp_kernel, dim3(9216 / 4), dim3(256), 0, stream, C, B, hh, 9216);
    // fc: (4,10,200)
    hipLaunchKernelGGL(fc_kernel, dim3(10, 4), dim3(64), 0, stream, B, Wfc, A);
    // final spike -> d_out: 40 neurons
    hipLaunchKernelGGL(spike_kernel, dim3(1), dim3(256), 0, stream, A, outp, rk, 40);
    (void)in_sizes; (void)n_in; (void)out_size; (void)ws_size;
}

// Round 3
// 1106.092 us; speedup vs baseline: 2.7718x; 1.5517x over previous
//
#include <hip/hip_runtime.h>
#include <math.h>

// ---------------------------------------------------------------------------
// SNN forward: psp (K=100 alpha FIR) -> conv/pool/fc -> spike (refractory scan)
// All arithmetic mirrors the JAX reference's f32 association order.
// Round 3: spike rewritten — LDS-staged t-chunks, coalesced float4 global
// loads/stores (fixes 7.3x write amplification); psp/psppool float4 stores.
// ---------------------------------------------------------------------------

#define THETA 10.0f

// hh table: hh[q] = h[q-3] for q-3 in [0,99], else 0.  h[k] = (k/10)*exp(1-k/10)
// rk table: rk[i] = REF_KERNEL[i+1] = (-40*(i+1))*exp(1-(i+1)),  i=0..14
__global__ void init_tables(float* hh, float* rk) {
    int i = threadIdx.x;
    if (i < 112) {
        int q = i - 3;
        float val = 0.0f;
        if (q >= 0 && q <= 99) {
            float tf = (float)q;
            float x = tf / 10.0f;                      // f32 divide, matches jnp
            val = x * (float)exp((double)(1.0f - x));  // correctly-rounded expf
        }
        hh[i] = val;
    }
    if (i < 15) {
        float t = (float)(i + 1);
        rk[i] = (-40.0f * t) * (float)exp((double)(1.0f - t));
    }
}

// wt_t[tap*Co + co] = w[co*tapN + tap]
__global__ void transpose_w(const float* __restrict__ w, float* __restrict__ o,
                            int Co, int tapN) {
    int i = blockIdx.x * 256 + threadIdx.x;
    if (i < Co * tapN) {
        int co = i / tapN, tp = i - co * tapN;
        o[tp * Co + co] = w[i];
    }
}

// ---------------------------------------------------------------------------
// psp: causal FIR along T (T=200).  Block = 4 neurons x 64 lanes.
// Lane l (<50) computes outputs t0..t0+3 (t0=4l). x staged in LDS, read b128.
// ---------------------------------------------------------------------------
__global__ __launch_bounds__(256) void psp_kernel(const float* __restrict__ in,
                                                  float* __restrict__ out,
                                                  const float* __restrict__ hh,
                                                  int n_neurons) {
    __shared__ __align__(16) float xl[4 * 200];
    const int w = threadIdx.x >> 6;
    const int l = threadIdx.x & 63;
    const long base = (long)blockIdx.x * 800;
    for (int i = threadIdx.x; i < 800; i += 256) xl[i] = in[base + i];
    __syncthreads();
    if (l < 50) {
        const int t0 = l * 4;
        const float* xs = &xl[w * 200];
        float a0 = 0.f, a1 = 0.f, a2 = 0.f, a3 = 0.f;
        const int gmax = (l < 25) ? l : 25;
        for (int g = 0; g <= gmax; ++g) {
            const float4 q = *reinterpret_cast<const float4*>(xs + (t0 - 4 * g));
            const int m0 = 4 * g;
            a0 = fmaf(hh[m0 + 0], q.w, a0);
            a1 = fmaf(hh[m0 + 1], q.w, a1);
            a2 = fmaf(hh[m0 + 2], q.w, a2);
            a3 = fmaf(hh[m0 + 3], q.w, a3);
            a0 = fmaf(hh[m0 + 1], q.z, a0);
            a1 = fmaf(hh[m0 + 2], q.z, a1);
            a2 = fmaf(hh[m0 + 3], q.z, a2);
            a3 = fmaf(hh[m0 + 4], q.z, a3);
            a0 = fmaf(hh[m0 + 2], q.y, a0);
            a1 = fmaf(hh[m0 + 3], q.y, a1);
            a2 = fmaf(hh[m0 + 4], q.y, a2);
            a3 = fmaf(hh[m0 + 5], q.y, a3);
            a0 = fmaf(hh[m0 + 3], q.x, a0);
            a1 = fmaf(hh[m0 + 4], q.x, a1);
            a2 = fmaf(hh[m0 + 5], q.x, a2);
            a3 = fmaf(hh[m0 + 6], q.x, a3);
        }
        *reinterpret_cast<float4*>(out + base + (long)w * 200 + t0) =
            make_float4(a0, a1, a2, a3);
    }
}

// ---------------------------------------------------------------------------
// Fused psp -> 2x2 sum-pool (*11).  Bit-identical to unfused (separate
// per-pixel accumulators, row-major final sum).
// ---------------------------------------------------------------------------
__global__ __launch_bounds__(256) void psppool_kernel(const float* __restrict__ in,
                                                      float* __restrict__ out,
                                                      const float* __restrict__ hh,
                                                      int C, int HO, int WO) {
    __shared__ __align__(16) float xl[16 * 200];
    const int w = threadIdx.x >> 6;
    const int l = threadIdx.x & 63;
    const int o0 = blockIdx.x * 4;
    const int H = 2 * HO, W = 2 * WO;
    for (int i = threadIdx.x; i < 3200; i += 256) {
        int px = i / 200, off = i - px * 200;
        int o = o0 + (px >> 2);
        int wi = px & 3;
        int wo = o % WO; int tmp = o / WO;
        int ho = tmp % HO; tmp /= HO;
        int c = tmp % C;  int b = tmp / C;
        int hin = 2 * ho + (wi >> 1), win = 2 * wo + (wi & 1);
        long nin = (((long)(b * C + c) * H + hin) * W + win);
        xl[i] = in[nin * 200 + off];
    }
    __syncthreads();
    if (l < 50) {
        const int t0 = l * 4;
        const float* xs = &xl[(w * 4) * 200];
        float a[4][4];
        #pragma unroll
        for (int i = 0; i < 4; ++i)
            #pragma unroll
            for (int p = 0; p < 4; ++p) a[i][p] = 0.0f;
        const int gmax = (l < 25) ? l : 25;
        for (int g = 0; g <= gmax; ++g) {
            const int m0 = 4 * g;
            #pragma unroll
            for (int p = 0; p < 4; ++p) {
                const float4 q = *reinterpret_cast<const float4*>(xs + p * 200 + (t0 - 4 * g));
                float vv[4] = {q.w, q.z, q.y, q.x};
                #pragma unroll
                for (int d = 0; d < 4; ++d) {
                    #pragma unroll
                    for (int i = 0; i < 4; ++i)
                        a[i][p] = fmaf(hh[m0 + d + i], vv[d], a[i][p]);
                }
            }
        }
        float r[4];
        #pragma unroll
        for (int i = 0; i < 4; ++i) {
            float s = ((a[i][0] + a[i][1]) + a[i][2]) + a[i][3];
            r[i] = s * 11.0f;
        }
        *reinterpret_cast<float4*>(out + (long)(o0 + w) * 200 + t0) =
            make_float4(r[0], r[1], r[2], r[3]);
    }
}

// ---------------------------------------------------------------------------
// Spatial conv.  Block = 256 thr = 4 waves = 4 output pixels.  Lane covers
// 4 consecutive t (float4 load, coalesced).  COG co-accumulators per thread;
// weights pre-transposed to [tap][Co] => thread-uniform s_loads.
// ---------------------------------------------------------------------------
template <int K, int PAD, int CI, int COG>
__global__ __launch_bounds__(256) void conv_kernel(const float* __restrict__ x,
                                                   const float* __restrict__ wt,
                                                   float* __restrict__ out,
                                                   int Co, int H, int W,
                                                   int HO, int WO) {
    const int l = threadIdx.x & 63;
    const int wv = threadIdx.x >> 6;
    if (l >= 50) return;
    const int p = blockIdx.x * 4 + wv;
    const int wo = p % WO, ho = p / WO;
    const int co0 = blockIdx.y * COG;
    const int b = blockIdx.z;
    const int t0 = l * 4;
    float4 acc[COG];
    #pragma unroll
    for (int c = 0; c < COG; ++c) acc[c] = make_float4(0.f, 0.f, 0.f, 0.f);
    const float* xb = x + ((long)b * CI * H * W) * 200 + t0;
    for (int ci = 0; ci < CI; ++ci) {
        #pragma unroll
        for (int kh = 0; kh < K; ++kh) {
            const int hi = ho + kh - PAD;
            if (hi < 0 || hi >= H) continue;
            #pragma unroll
            for (int kw = 0; kw < K; ++kw) {
                const int wi = wo + kw - PAD;
                if (wi < 0 || wi >= W) continue;
                const float4 v = *reinterpret_cast<const float4*>(
                    xb + ((long)(ci * H + hi) * W + wi) * 200);
                const float* wp = wt + ((ci * K + kh) * K + kw) * Co + co0;
                #pragma unroll
                for (int c = 0; c < COG; ++c) {
                    const float wv_ = wp[c];
                    acc[c].x = fmaf(wv_, v.x, acc[c].x);
                    acc[c].y = fmaf(wv_, v.y, acc[c].y);
                    acc[c].z = fmaf(wv_, v.z, acc[c].z);
                    acc[c].w = fmaf(wv_, v.w, acc[c].w);
                }
            }
        }
    }
    const long hwN = (long)HO * WO;
    const long ob = ((long)(b * Co + co0) * HO + ho) * WO + wo;
    #pragma unroll
    for (int c = 0; c < COG; ++c)
        *reinterpret_cast<float4*>(out + (ob + c * hwN) * 200 + t0) = acc[c];
}

// ---------------------------------------------------------------------------
// Refractory spike scan, LDS-staged.  Wave = 64 neurons; t processed in
// chunks of 16.  Global I/O is float4, 4 lanes per neuron row (full 64B
// lines -> no write amplification).  LDS tile transposed [t][65] so the
// scan reads/writes are conflict-free.  Per-element math identical to the
// register version: u = v + p0; s = (u>=theta); p = shift(p) + s*rk.
// In-place safe (chunk staged before overwrite).
// ---------------------------------------------------------------------------
__global__ __launch_bounds__(256) void spike_kernel(const float* __restrict__ v,
                                                    float* __restrict__ s,
                                                    const float* __restrict__ rkt,
                                                    int n) {
    __shared__ __align__(16) float xt[4][16 * 65];
    const int wv = threadIdx.x >> 6;
    const int l = threadIdx.x & 63;
    const int g0 = blockIdx.x * 256 + wv * 64;
    float rk[15];
    #pragma unroll
    for (int i = 0; i < 15; ++i) rk[i] = rkt[i];
    float p[15];
    #pragma unroll
    for (int i = 0; i < 15; ++i) p[i] = 0.0f;
    const int myn = g0 + l;
    float* tile = xt[wv];
    for (int t0 = 0; t0 < 200; t0 += 16) {
        // stage: 64 rows x up to 16 t, coalesced (4 lanes per row)
        #pragma unroll
        for (int it = 0; it < 4; ++it) {
            const int idx = it * 64 + l;
            const int r = idx >> 2;
            const int c = (idx & 3) * 4;
            const int gn = g0 + r;
            if (gn < n && t0 + c < 200) {
                const float4 q = *reinterpret_cast<const float4*>(v + (long)gn * 200 + t0 + c);
                tile[(c + 0) * 65 + r] = q.x;
                tile[(c + 1) * 65 + r] = q.y;
                tile[(c + 2) * 65 + r] = q.z;
                tile[(c + 3) * 65 + r] = q.w;
            }
        }
        __syncthreads();
        const int tm = (200 - t0 < 16) ? (200 - t0) : 16;
        if (myn < n) {
            for (int tt = 0; tt < tm; ++tt) {
                const float u = tile[tt * 65 + l] + p[0];
                const float sv = (u >= THETA) ? 1.0f : 0.0f;
                tile[tt * 65 + l] = sv;
                #pragma unroll
                for (int i = 0; i < 14; ++i) p[i] = fmaf(sv, rk[i], p[i + 1]);
                p[14] = sv * rk[14];
            }
        }
        __syncthreads();
        // store back, coalesced
        #pragma unroll
        for (int it = 0; it < 4; ++it) {
            const int idx = it * 64 + l;
            const int r = idx >> 2;
            const int c = (idx & 3) * 4;
            const int gn = g0 + r;
            if (gn < n && t0 + c < 200) {
                float4 q;
                q.x = tile[(c + 0) * 65 + r];
                q.y = tile[(c + 1) * 65 + r];
                q.z = tile[(c + 2) * 65 + r];
                q.w = tile[(c + 3) * 65 + r];
                *reinterpret_cast<float4*>(s + (long)gn * 200 + t0 + c) = q;
            }
        }
        __syncthreads();
    }
}

// ---------------------------------------------------------------------------
// FC: out[b,k,t] = sum_{c,h,w} x[b,c,h,w,t] * Wfc[k,c,h,w]   (float4 over t)
// ---------------------------------------------------------------------------
__global__ __launch_bounds__(64) void fc_kernel(const float* __restrict__ x,
                                                const float* __restrict__ wf,
                                                float* __restrict__ out) {
    const int k = blockIdx.x, b = blockIdx.y, l = threadIdx.x;
    if (l >= 50) return;
    const int t0 = l * 4;
    float4 acc = make_float4(0.f, 0.f, 0.f, 0.f);
    for (int c = 0; c < 64; ++c)
        #pragma unroll
        for (int h = 0; h < 6; ++h)
            #pragma unroll
            for (int w = 0; w < 6; ++w) {
                const float4 v = *reinterpret_cast<const float4*>(
                    x + (((long)(b * 64 + c) * 6 + h) * 6 + w) * 200 + t0);
                const float wv_ = wf[((k * 64 + c) * 6 + h) * 6 + w];
                acc.x = fmaf(wv_, v.x, acc.x);
                acc.y = fmaf(wv_, v.y, acc.y);
                acc.z = fmaf(wv_, v.z, acc.z);
                acc.w = fmaf(wv_, v.w, acc.w);
            }
    *reinterpret_cast<float4*>(out + ((long)b * 10 + k) * 200 + t0) = acc;
}

extern "C" void kernel_launch(void* const* d_in, const int* in_sizes, int n_in,
                              void* d_out, int out_size, void* d_ws, size_t ws_size,
                              hipStream_t stream) {
    const float* x_in = (const float*)d_in[0];  // (4,2,50,50,200)
    const float* W1 = (const float*)d_in[1];    // (16,2,5,5)
    const float* W2 = (const float*)d_in[2];    // (32,16,3,3)
    const float* W3 = (const float*)d_in[3];    // (64,32,3,3)
    const float* W4 = (const float*)d_in[4];    // (64,64,3,3)
    const float* Wfc = (const float*)d_in[5];   // (10,64,6,6)
    float* outp = (float*)d_out;                // (4,10,200)

    float* ws = (float*)d_ws;
    float* hh  = ws;                  // 112
    float* rk  = ws + 112;            // 15 (+1 pad)
    float* wt1 = ws + 128;            // 800
    float* wt2 = wt1 + 800;           // 4608
    float* wt3 = wt2 + 4608;          // 18432
    float* wt4 = wt3 + 18432;         // 36864
    float* A   = wt4 + 36864;         // 7,372,800
    float* B   = A + 7372800;         // 29,491,200
    float* C   = B + 29491200;        // 14,745,600

    hipLaunchKernelGGL(init_tables, dim3(1), dim3(128), 0, stream, hh, rk);
    hipLaunchKernelGGL(transpose_w, dim3(4),   dim3(256), 0, stream, W1, wt1, 16, 50);
    hipLaunchKernelGGL(transpose_w, dim3(18),  dim3(256), 0, stream, W2, wt2, 32, 144);
    hipLaunchKernelGGL(transpose_w, dim3(72),  dim3(256), 0, stream, W3, wt3, 64, 288);
    hipLaunchKernelGGL(transpose_w, dim3(144), dim3(256), 0, stream, W4, wt4, 64, 576);

    // p0 = psp(input): 20000 neurons
    hipLaunchKernelGGL(psp_kernel, dim3(5000), dim3(256), 0, stream, x_in, A, hh, 20000);
    // c1 = conv1(p0): (4,16,48,48,200)
    hipLaunchKernelGGL((conv_kernel<5, 1, 2, 16>), dim3(2304 / 4, 1, 4), dim3(256), 0, stream,
                       A, wt1, B, 16, 50, 50, 48, 48);
    // s1 = spike(c1) in-place: 147456 neurons
    hipLaunchKernelGGL(spike_kernel, dim3(576), dim3(256), 0, stream, B, B, rk, 147456);
    // o1 = pool(psp(s1)): (4,16,24,24,200) = 36864 neurons
    hipLaunchKernelGGL(psppool_kernel, dim3(36864 / 4), dim3(256), 0, stream, B, A, hh, 16, 24, 24);
    // s2 = spike(o1)
    hipLaunchKernelGGL(spike_kernel, dim3(144), dim3(256), 0, stream, A, A, rk, 36864);
    // p2 = psp(s2)
    hipLaunchKernelGGL(psp_kernel, dim3(36864 / 4), dim3(256), 0, stream, A, B, hh, 36864);
    // c2 = conv2(p2): (4,32,24,24,200)
    hipLaunchKernelGGL((conv_kernel<3, 1, 16, 16>), dim3(576 / 4, 2, 4), dim3(256), 0, stream,
                       B, wt2, C, 32, 24, 24, 24, 24);
    // s3 = spike(c2): 73728
    hipLaunchKernelGGL(spike_kernel, dim3(288), dim3(256), 0, stream, C, C, rk, 73728);
    // o2 = pool(psp(s3)): (4,32,12,12,200) = 18432
    hipLaunchKernelGGL(psppool_kernel, dim3(18432 / 4), dim3(256), 0, stream, C, A, hh, 32, 12, 12);
    // s4
    hipLaunchKernelGGL(spike_kernel, dim3(72), dim3(256), 0, stream, A, A, rk, 18432);
    // p4 = psp(s4)
    hipLaunchKernelGGL(psp_kernel, dim3(18432 / 4), dim3(256), 0, stream, A, B, hh, 18432);
    // c3 = conv3(p4): (4,64,12,12,200)
    hipLaunchKernelGGL((conv_kernel<3, 1, 32, 8>), dim3(144 / 4, 8, 4), dim3(256), 0, stream,
                       B, wt3, C, 64, 12, 12, 12, 12);
    // s5: 36864
    hipLaunchKernelGGL(spike_kernel, dim3(144), dim3(256), 0, stream, C, C, rk, 36864);
    // o3 = pool(psp(s5)): (4,64,6,6,200) = 9216
    hipLaunchKernelGGL(psppool_kernel, dim3(9216 / 4), dim3(256), 0, stream, C, A, hh, 64, 6, 6);
    // s6
    hipLaunchKernelGGL(spike_kernel, dim3(36), dim3(256), 0, stream, A, A, rk, 9216);
    // p6 = psp(s6)
    hipLaunchKernelGGL(psp_kernel, dim3(9216 / 4), dim3(256), 0, stream, A, B, hh, 9216);
    // c4 = conv4(p6): (4,64,6,6,200)
    hipLaunchKernelGGL((conv_kernel<3, 1, 64, 8>), dim3(36 / 4, 8, 4), dim3(256), 0, stream,
                       B, wt4, C, 64, 6, 6, 6, 6);
    // s7: 9216
    hipLaunchKernelGGL(spike_kernel, dim3(36), dim3(256), 0, stream, C, C, rk, 9216);
    // p7 = psp(s7)
    hipLaunchKernelGGL(psp_kernel, dim3(9216 / 4), dim3(256), 0, stream, C, B, hh, 9216);
    // fc: (4,10,200)
    hipLaunchKernelGGL(fc_kernel, dim3(10, 4), dim3(64), 0, stream, B, Wfc, A);
    // final spike -> d_out: 40 neurons
    hipLaunchKernelGGL(spike_kernel, dim3(1), dim3(256), 0, stream, A, outp, rk, 40);
    (void)in_sizes; (void)n_in; (void)out_size; (void)ws_size;
}

// Round 4
// 996.410 us; speedup vs baseline: 3.0769x; 1.1101x over previous
//
#include <hip/hip_runtime.h>
#include <math.h>

// ---------------------------------------------------------------------------
// SNN forward: psp (K=100 alpha FIR) -> conv/pool/fc -> spike (refractory scan)
// All arithmetic mirrors the JAX reference's f32 association order.
// Round 4: K=3 convs software-pipelined across ci (zero-filled OOB taps,
// unconditional FMA — bit-exact); conv4 COG=4 for 2x waves; fc t-split;
// prep launches merged.
// ---------------------------------------------------------------------------

#define THETA 10.0f

// hh[q] = h[q-3] for q-3 in [0,99], else 0.  h[k] = (k/10)*exp(1-k/10)
// rk[i] = REF_KERNEL[i+1] = (-40*(i+1))*exp(1-(i+1)),  i=0..14
// wtN = transposed weights: wt[(ci*K*K + tap)*Co + co] = W[co][ci][tap]
__global__ void prep_kernel(const float* __restrict__ W1, const float* __restrict__ W2,
                            const float* __restrict__ W3, const float* __restrict__ W4,
                            float* hh, float* rk,
                            float* wt1, float* wt2, float* wt3, float* wt4) {
    int i = blockIdx.x * 256 + threadIdx.x;
    if (i < 112) {
        int q = i - 3;
        float val = 0.0f;
        if (q >= 0 && q <= 99) {
            float tf = (float)q;
            float x = tf / 10.0f;
            val = x * (float)exp((double)(1.0f - x));
        }
        hh[i] = val;
    } else if (i < 128) {
        int j = i - 112;
        if (j < 15) {
            float t = (float)(j + 1);
            rk[j] = (-40.0f * t) * (float)exp((double)(1.0f - t));
        }
    } else if (i < 928) {            // W1: 16 x 50
        int j = i - 128, co = j / 50, tp = j % 50;
        wt1[tp * 16 + co] = W1[j];
    } else if (i < 5536) {           // W2: 32 x 144
        int j = i - 928, co = j / 144, tp = j % 144;
        wt2[tp * 32 + co] = W2[j];
    } else if (i < 23968) {          // W3: 64 x 288
        int j = i - 5536, co = j / 288, tp = j % 288;
        wt3[tp * 64 + co] = W3[j];
    } else if (i < 60832) {          // W4: 64 x 576
        int j = i - 23968, co = j / 576, tp = j % 576;
        wt4[tp * 64 + co] = W4[j];
    }
}

// ---------------------------------------------------------------------------
// psp: causal FIR along T (T=200).  Block = 4 neurons x 64 lanes.
// ---------------------------------------------------------------------------
__global__ __launch_bounds__(256) void psp_kernel(const float* __restrict__ in,
                                                  float* __restrict__ out,
                                                  const float* __restrict__ hh,
                                                  int n_neurons) {
    __shared__ __align__(16) float xl[4 * 200];
    const int w = threadIdx.x >> 6;
    const int l = threadIdx.x & 63;
    const long base = (long)blockIdx.x * 800;
    for (int i = threadIdx.x; i < 800; i += 256) xl[i] = in[base + i];
    __syncthreads();
    if (l < 50) {
        const int t0 = l * 4;
        const float* xs = &xl[w * 200];
        float a0 = 0.f, a1 = 0.f, a2 = 0.f, a3 = 0.f;
        const int gmax = (l < 25) ? l : 25;
        for (int g = 0; g <= gmax; ++g) {
            const float4 q = *reinterpret_cast<const float4*>(xs + (t0 - 4 * g));
            const int m0 = 4 * g;
            a0 = fmaf(hh[m0 + 0], q.w, a0);
            a1 = fmaf(hh[m0 + 1], q.w, a1);
            a2 = fmaf(hh[m0 + 2], q.w, a2);
            a3 = fmaf(hh[m0 + 3], q.w, a3);
            a0 = fmaf(hh[m0 + 1], q.z, a0);
            a1 = fmaf(hh[m0 + 2], q.z, a1);
            a2 = fmaf(hh[m0 + 3], q.z, a2);
            a3 = fmaf(hh[m0 + 4], q.z, a3);
            a0 = fmaf(hh[m0 + 2], q.y, a0);
            a1 = fmaf(hh[m0 + 3], q.y, a1);
            a2 = fmaf(hh[m0 + 4], q.y, a2);
            a3 = fmaf(hh[m0 + 5], q.y, a3);
            a0 = fmaf(hh[m0 + 3], q.x, a0);
            a1 = fmaf(hh[m0 + 4], q.x, a1);
            a2 = fmaf(hh[m0 + 5], q.x, a2);
            a3 = fmaf(hh[m0 + 6], q.x, a3);
        }
        *reinterpret_cast<float4*>(out + base + (long)w * 200 + t0) =
            make_float4(a0, a1, a2, a3);
    }
}

// ---------------------------------------------------------------------------
// Fused psp -> 2x2 sum-pool (*11).  Bit-identical to unfused.
// ---------------------------------------------------------------------------
__global__ __launch_bounds__(256) void psppool_kernel(const float* __restrict__ in,
                                                      float* __restrict__ out,
                                                      const float* __restrict__ hh,
                                                      int C, int HO, int WO) {
    __shared__ __align__(16) float xl[16 * 200];
    const int w = threadIdx.x >> 6;
    const int l = threadIdx.x & 63;
    const int o0 = blockIdx.x * 4;
    const int H = 2 * HO, W = 2 * WO;
    for (int i = threadIdx.x; i < 3200; i += 256) {
        int px = i / 200, off = i - px * 200;
        int o = o0 + (px >> 2);
        int wi = px & 3;
        int wo = o % WO; int tmp = o / WO;
        int ho = tmp % HO; tmp /= HO;
        int c = tmp % C;  int b = tmp / C;
        int hin = 2 * ho + (wi >> 1), win = 2 * wo + (wi & 1);
        long nin = (((long)(b * C + c) * H + hin) * W + win);
        xl[i] = in[nin * 200 + off];
    }
    __syncthreads();
    if (l < 50) {
        const int t0 = l * 4;
        const float* xs = &xl[(w * 4) * 200];
        float a[4][4];
        #pragma unroll
        for (int i = 0; i < 4; ++i)
            #pragma unroll
            for (int p = 0; p < 4; ++p) a[i][p] = 0.0f;
        const int gmax = (l < 25) ? l : 25;
        for (int g = 0; g <= gmax; ++g) {
            const int m0 = 4 * g;
            #pragma unroll
            for (int p = 0; p < 4; ++p) {
                const float4 q = *reinterpret_cast<const float4*>(xs + p * 200 + (t0 - 4 * g));
                float vv[4] = {q.w, q.z, q.y, q.x};
                #pragma unroll
                for (int d = 0; d < 4; ++d) {
                    #pragma unroll
                    for (int i = 0; i < 4; ++i)
                        a[i][p] = fmaf(hh[m0 + d + i], vv[d], a[i][p]);
                }
            }
        }
        float r[4];
        #pragma unroll
        for (int i = 0; i < 4; ++i) {
            float s = ((a[i][0] + a[i][1]) + a[i][2]) + a[i][3];
            r[i] = s * 11.0f;
        }
        *reinterpret_cast<float4*>(out + (long)(o0 + w) * 200 + t0) =
            make_float4(r[0], r[1], r[2], r[3]);
    }
}

// ---------------------------------------------------------------------------
// conv1 (K=5): original structure — CI=2, 9216 waves, latency OK.
// ---------------------------------------------------------------------------
template <int K, int PAD, int CI, int COG>
__global__ __launch_bounds__(256) void conv_kernel(const float* __restrict__ x,
                                                   const float* __restrict__ wt,
                                                   float* __restrict__ out,
                                                   int Co, int H, int W,
                                                   int HO, int WO) {
    const int l = threadIdx.x & 63;
    const int wv = threadIdx.x >> 6;
    if (l >= 50) return;
    const int p = blockIdx.x * 4 + wv;
    const int wo = p % WO, ho = p / WO;
    const int co0 = blockIdx.y * COG;
    const int b = blockIdx.z;
    const int t0 = l * 4;
    float4 acc[COG];
    #pragma unroll
    for (int c = 0; c < COG; ++c) acc[c] = make_float4(0.f, 0.f, 0.f, 0.f);
    const float* xb = x + ((long)b * CI * H * W) * 200 + t0;
    for (int ci = 0; ci < CI; ++ci) {
        #pragma unroll
        for (int kh = 0; kh < K; ++kh) {
            const int hi = ho + kh - PAD;
            if (hi < 0 || hi >= H) continue;
            #pragma unroll
            for (int kw = 0; kw < K; ++kw) {
                const int wi = wo + kw - PAD;
                if (wi < 0 || wi >= W) continue;
                const float4 v = *reinterpret_cast<const float4*>(
                    xb + ((long)(ci * H + hi) * W + wi) * 200);
                const float* wp = wt + ((ci * K + kh) * K + kw) * Co + co0;
                #pragma unroll
                for (int c = 0; c < COG; ++c) {
                    const float wv_ = wp[c];
                    acc[c].x = fmaf(wv_, v.x, acc[c].x);
                    acc[c].y = fmaf(wv_, v.y, acc[c].y);
                    acc[c].z = fmaf(wv_, v.z, acc[c].z);
                    acc[c].w = fmaf(wv_, v.w, acc[c].w);
                }
            }
        }
    }
    const long hwN = (long)HO * WO;
    const long ob = ((long)(b * Co + co0) * HO + ho) * WO + wo;
    #pragma unroll
    for (int c = 0; c < COG; ++c)
        *reinterpret_cast<float4*>(out + (ob + c * hwN) * 200 + t0) = acc[c];
}

// ---------------------------------------------------------------------------
// K=3 convs: ci-software-pipelined.  All 9 taps of ci+1 load while ci's taps
// FMA.  OOB taps are +0.0 and FMA'd unconditionally: fmaf(w, +/-0, acc)==acc
// bitwise (acc is never -0.0), so results are bit-identical to tap-skipping.
// Per-acc FMA order: ci ascending, (kh,kw) ascending — unchanged.
// ---------------------------------------------------------------------------
template <int CI, int COG>
__global__ __launch_bounds__(256) void conv3_kernel(const float* __restrict__ x,
                                                    const float* __restrict__ wt,
                                                    float* __restrict__ out,
                                                    int Co, int H, int W) {
    const int l = threadIdx.x & 63;
    const int wv = threadIdx.x >> 6;
    if (l >= 50) return;
    const int p = blockIdx.x * 4 + wv;
    const int wo = p % W, ho = p / W;       // HO==H, WO==W for pad=1 K=3
    const int co0 = blockIdx.y * COG;
    const int b = blockIdx.z;
    const int t0 = l * 4;
    float4 acc[COG];
    #pragma unroll
    for (int c = 0; c < COG; ++c) acc[c] = make_float4(0.f, 0.f, 0.f, 0.f);

    bool vm[9];
    #pragma unroll
    for (int i = 0; i < 9; ++i) {
        const int hi = ho + i / 3 - 1, wi = wo + i % 3 - 1;
        vm[i] = (hi >= 0) && (hi < H) && (wi >= 0) && (wi < W);
    }
    const long cis = (long)H * W * 200;
    const float* pb = x + (long)b * CI * cis + ((long)(ho - 1) * W + (wo - 1)) * 200 + t0;

    float4 bufA[9], bufB[9];
    auto ld = [&](int ci, float4 (&B)[9]) {
        const float* pc = pb + ci * cis;
        #pragma unroll
        for (int i = 0; i < 9; ++i) {
            B[i] = vm[i] ? *reinterpret_cast<const float4*>(pc + ((i / 3) * W + (i % 3)) * 200)
                         : make_float4(0.f, 0.f, 0.f, 0.f);
        }
    };
    auto fm = [&](const float4 (&B)[9], int ci) {
        #pragma unroll
        for (int i = 0; i < 9; ++i) {
            const float* wp = wt + (ci * 9 + i) * Co + co0;
            #pragma unroll
            for (int c = 0; c < COG; ++c) {
                const float wv_ = wp[c];
                acc[c].x = fmaf(wv_, B[i].x, acc[c].x);
                acc[c].y = fmaf(wv_, B[i].y, acc[c].y);
                acc[c].z = fmaf(wv_, B[i].z, acc[c].z);
                acc[c].w = fmaf(wv_, B[i].w, acc[c].w);
            }
        }
    };

    ld(0, bufA);
    #pragma unroll 1
    for (int ci = 0; ci < CI; ci += 2) {
        ld(ci + 1, bufB);
        fm(bufA, ci);
        if (ci + 2 < CI) ld(ci + 2, bufA);
        fm(bufB, ci + 1);
    }

    const long hwN = (long)H * W;
    const long ob = ((long)(b * Co + co0) * H + ho) * W + wo;
    #pragma unroll
    for (int c = 0; c < COG; ++c)
        *reinterpret_cast<float4*>(out + (ob + c * hwN) * 200 + t0) = acc[c];
}

// ---------------------------------------------------------------------------
// Refractory spike scan, LDS-staged, coalesced float4 I/O.
// ---------------------------------------------------------------------------
__global__ __launch_bounds__(256) void spike_kernel(const float* __restrict__ v,
                                                    float* __restrict__ s,
                                                    const float* __restrict__ rkt,
                                                    int n) {
    __shared__ __align__(16) float xt[4][16 * 65];
    const int wv = threadIdx.x >> 6;
    const int l = threadIdx.x & 63;
    const int g0 = blockIdx.x * 256 + wv * 64;
    float rk[15];
    #pragma unroll
    for (int i = 0; i < 15; ++i) rk[i] = rkt[i];
    float p[15];
    #pragma unroll
    for (int i = 0; i < 15; ++i) p[i] = 0.0f;
    const int myn = g0 + l;
    float* tile = xt[wv];
    for (int t0 = 0; t0 < 200; t0 += 16) {
        #pragma unroll
        for (int it = 0; it < 4; ++it) {
            const int idx = it * 64 + l;
            const int r = idx >> 2;
            const int c = (idx & 3) * 4;
            const int gn = g0 + r;
            if (gn < n && t0 + c < 200) {
                const float4 q = *reinterpret_cast<const float4*>(v + (long)gn * 200 + t0 + c);
                tile[(c + 0) * 65 + r] = q.x;
                tile[(c + 1) * 65 + r] = q.y;
                tile[(c + 2) * 65 + r] = q.z;
                tile[(c + 3) * 65 + r] = q.w;
            }
        }
        __syncthreads();
        const int tm = (200 - t0 < 16) ? (200 - t0) : 16;
        if (myn < n) {
            for (int tt = 0; tt < tm; ++tt) {
                const float u = tile[tt * 65 + l] + p[0];
                const float sv = (u >= THETA) ? 1.0f : 0.0f;
                tile[tt * 65 + l] = sv;
                #pragma unroll
                for (int i = 0; i < 14; ++i) p[i] = fmaf(sv, rk[i], p[i + 1]);
                p[14] = sv * rk[14];
            }
        }
        __syncthreads();
        #pragma unroll
        for (int it = 0; it < 4; ++it) {
            const int idx = it * 64 + l;
            const int r = idx >> 2;
            const int c = (idx & 3) * 4;
            const int gn = g0 + r;
            if (gn < n && t0 + c < 200) {
                float4 q;
                q.x = tile[(c + 0) * 65 + r];
                q.y = tile[(c + 1) * 65 + r];
                q.z = tile[(c + 2) * 65 + r];
                q.w = tile[(c + 3) * 65 + r];
                *reinterpret_cast<float4*>(s + (long)gn * 200 + t0 + c) = q;
            }
        }
        __syncthreads();
    }
}

// ---------------------------------------------------------------------------
// FC: out[b,k,t] = sum_{c,h,w} x[b,c,h,w,t] * Wfc[k,c,h,w]; grid.z = t-half.
// ---------------------------------------------------------------------------
__global__ __launch_bounds__(64) void fc_kernel(const float* __restrict__ x,
                                                const float* __restrict__ wf,
                                                float* __restrict__ out) {
    const int k = blockIdx.x, b = blockIdx.y, l = threadIdx.x;
    if (l >= 25) return;
    const int t0 = blockIdx.z * 100 + l * 4;
    float4 acc = make_float4(0.f, 0.f, 0.f, 0.f);
    for (int c = 0; c < 64; ++c)
        #pragma unroll
        for (int h = 0; h < 6; ++h)
            #pragma unroll
            for (int w = 0; w < 6; ++w) {
                const float4 v = *reinterpret_cast<const float4*>(
                    x + (((long)(b * 64 + c) * 6 + h) * 6 + w) * 200 + t0);
                const float wv_ = wf[((k * 64 + c) * 6 + h) * 6 + w];
                acc.x = fmaf(wv_, v.x, acc.x);
                acc.y = fmaf(wv_, v.y, acc.y);
                acc.z = fmaf(wv_, v.z, acc.z);
                acc.w = fmaf(wv_, v.w, acc.w);
            }
    *reinterpret_cast<float4*>(out + ((long)b * 10 + k) * 200 + t0) = acc;
}

extern "C" void kernel_launch(void* const* d_in, const int* in_sizes, int n_in,
                              void* d_out, int out_size, void* d_ws, size_t ws_size,
                              hipStream_t stream) {
    const float* x_in = (const float*)d_in[0];  // (4,2,50,50,200)
    const float* W1 = (const float*)d_in[1];    // (16,2,5,5)
    const float* W2 = (const float*)d_in[2];    // (32,16,3,3)
    const float* W3 = (const float*)d_in[3];    // (64,32,3,3)
    const float* W4 = (const float*)d_in[4];    // (64,64,3,3)
    const float* Wfc = (const float*)d_in[5];   // (10,64,6,6)
    float* outp = (float*)d_out;                // (4,10,200)

    float* ws = (float*)d_ws;
    float* hh  = ws;                  // 112
    float* rk  = ws + 112;            // 15 (+1 pad)
    float* wt1 = ws + 128;            // 800
    float* wt2 = wt1 + 800;           // 4608
    float* wt3 = wt2 + 4608;          // 18432
    float* wt4 = wt3 + 18432;         // 36864
    float* A   = wt4 + 36864;         // 7,372,800
    float* B   = A + 7372800;         // 29,491,200
    float* C   = B + 29491200;        // 14,745,600

    hipLaunchKernelGGL(prep_kernel, dim3(238), dim3(256), 0, stream,
                       W1, W2, W3, W4, hh, rk, wt1, wt2, wt3, wt4);

    // p0 = psp(input): 20000 neurons
    hipLaunchKernelGGL(psp_kernel, dim3(5000), dim3(256), 0, stream, x_in, A, hh, 20000);
    // c1 = conv1(p0): (4,16,48,48,200)
    hipLaunchKernelGGL((conv_kernel<5, 1, 2, 16>), dim3(2304 / 4, 1, 4), dim3(256), 0, stream,
                       A, wt1, B, 16, 50, 50, 48, 48);
    // s1 = spike(c1) in-place: 147456 neurons
    hipLaunchKernelGGL(spike_kernel, dim3(576), dim3(256), 0, stream, B, B, rk, 147456);
    // o1 = pool(psp(s1)): (4,16,24,24,200) = 36864 neurons
    hipLaunchKernelGGL(psppool_kernel, dim3(36864 / 4), dim3(256), 0, stream, B, A, hh, 16, 24, 24);
    // s2 = spike(o1)
    hipLaunchKernelGGL(spike_kernel, dim3(144), dim3(256), 0, stream, A, A, rk, 36864);
    // p2 = psp(s2)
    hipLaunchKernelGGL(psp_kernel, dim3(36864 / 4), dim3(256), 0, stream, A, B, hh, 36864);
    // c2 = conv2(p2): (4,32,24,24,200)
    hipLaunchKernelGGL((conv3_kernel<16, 8>), dim3(576 / 4, 4, 4), dim3(256), 0, stream,
                       B, wt2, C, 32, 24, 24);
    // s3 = spike(c2): 73728
    hipLaunchKernelGGL(spike_kernel, dim3(288), dim3(256), 0, stream, C, C, rk, 73728);
    // o2 = pool(psp(s3)): (4,32,12,12,200) = 18432
    hipLaunchKernelGGL(psppool_kernel, dim3(18432 / 4), dim3(256), 0, stream, C, A, hh, 32, 12, 12);
    // s4
    hipLaunchKernelGGL(spike_kernel, dim3(72), dim3(256), 0, stream, A, A, rk, 18432);
    // p4 = psp(s4)
    hipLaunchKernelGGL(psp_kernel, dim3(18432 / 4), dim3(256), 0, stream, A, B, hh, 18432);
    // c3 = conv3(p4): (4,64,12,12,200)
    hipLaunchKernelGGL((conv3_kernel<32, 8>), dim3(144 / 4, 8, 4), dim3(256), 0, stream,
                       B, wt3, C, 64, 12, 12);
    // s5: 36864
    hipLaunchKernelGGL(spike_kernel, dim3(144), dim3(256), 0, stream, C, C, rk, 36864);
    // o3 = pool(psp(s5)): (4,64,6,6,200) = 9216
    hipLaunchKernelGGL(psppool_kernel, dim3(9216 / 4), dim3(256), 0, stream, C, A, hh, 64, 6, 6);
    // s6
    hipLaunchKernelGGL(spike_kernel, dim3(36), dim3(256), 0, stream, A, A, rk, 9216);
    // p6 = psp(s6)
    hipLaunchKernelGGL(psp_kernel, dim3(9216 / 4), dim3(256), 0, stream, A, B, hh, 9216);
    // c4 = conv4(p6): (4,64,6,6,200)
    hipLaunchKernelGGL((conv3_kernel<64, 4>), dim3(36 / 4, 16, 4), dim3(256), 0, stream,
                       B, wt4, C, 64, 6, 6);
    // s7: 9216
    hipLaunchKernelGGL(spike_kernel, dim3(36), dim3(256), 0, stream, C, C, rk, 9216);
    // p7 = psp(s7)
    hipLaunchKernelGGL(psp_kernel, dim3(9216 / 4), dim3(256), 0, stream, C, B, hh, 9216);
    // fc: (4,10,200)
    hipLaunchKernelGGL(fc_kernel, dim3(10, 4, 2), dim3(64), 0, stream, B, Wfc, A);
    // final spike -> d_out: 40 neurons
    hipLaunchKernelGGL(spike_kernel, dim3(1), dim3(256), 0, stream, A, outp, rk, 40);
    (void)in_sizes; (void)n_in; (void)out_size; (void)ws_size;
}

// Round 5
// 909.864 us; speedup vs baseline: 3.3695x; 1.0951x over previous
//
#include <hip/hip_runtime.h>
#include <math.h>

// ---------------------------------------------------------------------------
// SNN forward: psp (K=100 alpha FIR) -> conv/pool/fc -> spike (refractory scan)
// All arithmetic mirrors the JAX reference's f32 association order.
// Round 5: spike fused into the FIR kernels (LDS-resident scan), FIR work
// rebalanced: wave w handles chunks c%4==w for all 64 series -> zero
// divergence, 96% load balance.  FMA order byte-identical to round 1.
// ---------------------------------------------------------------------------

#define THETA 10.0f

// hh[q] = h[q-3] for q-3 in [0,99], else 0.  h[k] = (k/10)*exp(1-k/10)
// rk[i] = REF_KERNEL[i+1] = (-40*(i+1))*exp(1-(i+1)),  i=0..14
// wtN = transposed weights: wt[(ci*K*K + tap)*Co + co] = W[co][ci][tap]
__global__ void prep_kernel(const float* __restrict__ W1, const float* __restrict__ W2,
                            const float* __restrict__ W3, const float* __restrict__ W4,
                            float* hh, float* rk,
                            float* wt1, float* wt2, float* wt3, float* wt4) {
    int i = blockIdx.x * 256 + threadIdx.x;
    if (i < 112) {
        int q = i - 3;
        float val = 0.0f;
        if (q >= 0 && q <= 99) {
            float tf = (float)q;
            float x = tf / 10.0f;
            val = x * (float)exp((double)(1.0f - x));
        }
        hh[i] = val;
    } else if (i < 128) {
        int j = i - 112;
        if (j < 15) {
            float t = (float)(j + 1);
            rk[j] = (-40.0f * t) * (float)exp((double)(1.0f - t));
        }
    } else if (i < 928) {            // W1: 16 x 50
        int j = i - 128, co = j / 50, tp = j % 50;
        wt1[tp * 16 + co] = W1[j];
    } else if (i < 5536) {           // W2: 32 x 144
        int j = i - 928, co = j / 144, tp = j % 144;
        wt2[tp * 32 + co] = W2[j];
    } else if (i < 23968) {          // W3: 64 x 288
        int j = i - 5536, co = j / 288, tp = j % 288;
        wt3[tp * 64 + co] = W3[j];
    } else if (i < 60832) {          // W4: 64 x 576
        int j = i - 23968, co = j / 576, tp = j % 576;
        wt4[tp * 64 + co] = W4[j];
    }
}

// 16-FMA inner step, order identical to round 1 (qw,qz,qy,qx; k ascending
// per accumulator).  h0 = hh[m0..m0+3], h1 = hh[m0+4..m0+7].
#define FIR_STEP(A0, A1, A2, A3, qx, qy, qz, qw, h0, h1)  \
    A0 = fmaf(h0.x, qw, A0);                              \
    A1 = fmaf(h0.y, qw, A1);                              \
    A2 = fmaf(h0.z, qw, A2);                              \
    A3 = fmaf(h0.w, qw, A3);                              \
    A0 = fmaf(h0.y, qz, A0);                              \
    A1 = fmaf(h0.z, qz, A1);                              \
    A2 = fmaf(h0.w, qz, A2);                              \
    A3 = fmaf(h1.x, qz, A3);                              \
    A0 = fmaf(h0.z, qy, A0);                              \
    A1 = fmaf(h0.w, qy, A1);                              \
    A2 = fmaf(h1.x, qy, A2);                              \
    A3 = fmaf(h1.y, qy, A3);                              \
    A0 = fmaf(h0.w, qx, A0);                              \
    A1 = fmaf(h1.x, qx, A1);                              \
    A2 = fmaf(h1.y, qx, A2);                              \
    A3 = fmaf(h1.z, qx, A3);

// ---------------------------------------------------------------------------
// Fused [spike ->] psp.  Block = 64 series.  Stage to LDS tile[t][66]
// (t-major), wave 0 runs the refractory scan in-LDS (identical math),
// then wave w computes FIR chunks c%4==w for all 64 series (lane=series).
// ---------------------------------------------------------------------------
template <bool SCAN>
__global__ __launch_bounds__(256) void spikepsp_kernel(const float* __restrict__ in,
                                                       float* __restrict__ out,
                                                       const float* __restrict__ hh,
                                                       const float* __restrict__ rkt,
                                                       int n) {
    __shared__ float tile[200 * 66];
    const int l = threadIdx.x & 63;
    const int w = threadIdx.x >> 6;
    const int s0 = blockIdx.x * 64;
    // stage: i = slot*50 + q  (float4 over t, coalesced)
    for (int i = threadIdx.x; i < 3200; i += 256) {
        const int slot = i / 50, q = i - slot * 50;
        const int ser = s0 + slot;
        float4 v = make_float4(0.f, 0.f, 0.f, 0.f);
        if (ser < n) v = *reinterpret_cast<const float4*>(in + (long)ser * 200 + 4 * q);
        tile[(4 * q + 0) * 66 + slot] = v.x;
        tile[(4 * q + 1) * 66 + slot] = v.y;
        tile[(4 * q + 2) * 66 + slot] = v.z;
        tile[(4 * q + 3) * 66 + slot] = v.w;
    }
    __syncthreads();
    if (SCAN) {
        if (w == 0) {
            float rk[15];
            #pragma unroll
            for (int i = 0; i < 15; ++i) rk[i] = rkt[i];
            float p[15];
            #pragma unroll
            for (int i = 0; i < 15; ++i) p[i] = 0.0f;
            float* col = tile + l;
            for (int t = 0; t < 200; ++t) {
                const float u = col[t * 66] + p[0];
                const float sv = (u >= THETA) ? 1.0f : 0.0f;
                col[t * 66] = sv;
                #pragma unroll
                for (int i = 0; i < 14; ++i) p[i] = fmaf(sv, rk[i], p[i + 1]);
                p[14] = sv * rk[14];
            }
        }
        __syncthreads();
    }
    // FIR: wave w -> chunks c = w, w+4, ...  (wave-uniform g bound)
    const bool valid = (s0 + l) < n;
    for (int c = w; c < 50; c += 4) {
        const int t0 = 4 * c;
        float a0 = 0.f, a1 = 0.f, a2 = 0.f, a3 = 0.f;
        const int gmax = (c < 25) ? c : 25;
        float4 h0 = *reinterpret_cast<const float4*>(hh);
        const float* bp = &tile[t0 * 66 + l];
        for (int g = 0; g <= gmax; ++g) {
            const float4 h1 = *reinterpret_cast<const float4*>(hh + 4 * g + 4);
            const float qx = bp[0], qy = bp[66], qz = bp[132], qw = bp[198];
            FIR_STEP(a0, a1, a2, a3, qx, qy, qz, qw, h0, h1)
            h0 = h1;
            bp -= 4 * 66;
        }
        if (valid)
            *reinterpret_cast<float4*>(out + (long)(s0 + l) * 200 + t0) =
                make_float4(a0, a1, a2, a3);
    }
}

// ---------------------------------------------------------------------------
// Fused spike -> psp -> 2x2 sum-pool (*11).  Block = 16 output neurons =
// 64 input series (lane = slot = 4*oi + pixel).  Scan as above; FIR per lane
// runs one pixel chain; pool combine = in-order quad shuffle sum
// ((p0+p1)+p2)+p3 then *11 — bit-identical to the unfused version.
// ---------------------------------------------------------------------------
__global__ __launch_bounds__(256) void spikepsppool_kernel(const float* __restrict__ in,
                                                           float* __restrict__ out,
                                                           const float* __restrict__ hh,
                                                           const float* __restrict__ rkt,
                                                           int C, int HO, int WO) {
    __shared__ float tile[200 * 66];
    __shared__ int sbase[64];
    const int l = threadIdx.x & 63;
    const int w = threadIdx.x >> 6;
    const int o0 = blockIdx.x * 16;
    const int H = 2 * HO, W = 2 * WO;
    if (threadIdx.x < 64) {
        const int oi = threadIdx.x >> 2, p = threadIdx.x & 3;
        const int o = o0 + oi;
        const int wo = o % WO; int tmp = o / WO;
        const int ho = tmp % HO; tmp /= HO;
        const int c = tmp % C; const int b = tmp / C;
        sbase[threadIdx.x] = ((b * C + c) * H + 2 * ho + (p >> 1)) * W + 2 * wo + (p & 1);
    }
    __syncthreads();
    for (int i = threadIdx.x; i < 3200; i += 256) {
        const int slot = i / 50, q = i - slot * 50;
        const float4 v = *reinterpret_cast<const float4*>(in + (long)sbase[slot] * 200 + 4 * q);
        tile[(4 * q + 0) * 66 + slot] = v.x;
        tile[(4 * q + 1) * 66 + slot] = v.y;
        tile[(4 * q + 2) * 66 + slot] = v.z;
        tile[(4 * q + 3) * 66 + slot] = v.w;
    }
    __syncthreads();
    if (w == 0) {
        float rk[15];
        #pragma unroll
        for (int i = 0; i < 15; ++i) rk[i] = rkt[i];
        float p[15];
        #pragma unroll
        for (int i = 0; i < 15; ++i) p[i] = 0.0f;
        float* col = tile + l;
        for (int t = 0; t < 200; ++t) {
            const float u = col[t * 66] + p[0];
            const float sv = (u >= THETA) ? 1.0f : 0.0f;
            col[t * 66] = sv;
            #pragma unroll
            for (int i = 0; i < 14; ++i) p[i] = fmaf(sv, rk[i], p[i + 1]);
            p[14] = sv * rk[14];
        }
    }
    __syncthreads();
    const int qb = l & ~3;
    for (int c = w; c < 50; c += 4) {
        const int t0 = 4 * c;
        float a0 = 0.f, a1 = 0.f, a2 = 0.f, a3 = 0.f;
        const int gmax = (c < 25) ? c : 25;
        float4 h0 = *reinterpret_cast<const float4*>(hh);
        const float* bp = &tile[t0 * 66 + l];
        for (int g = 0; g <= gmax; ++g) {
            const float4 h1 = *reinterpret_cast<const float4*>(hh + 4 * g + 4);
            const float qx = bp[0], qy = bp[66], qz = bp[132], qw = bp[198];
            FIR_STEP(a0, a1, a2, a3, qx, qy, qz, qw, h0, h1)
            h0 = h1;
            bp -= 4 * 66;
        }
        float r[4];
        float av[4] = {a0, a1, a2, a3};
        #pragma unroll
        for (int i = 0; i < 4; ++i) {
            const float v0 = __shfl(av[i], qb + 0);
            const float v1 = __shfl(av[i], qb + 1);
            const float v2 = __shfl(av[i], qb + 2);
            const float v3 = __shfl(av[i], qb + 3);
            r[i] = (((v0 + v1) + v2) + v3) * 11.0f;
        }
        if ((l & 3) == 0)
            *reinterpret_cast<float4*>(out + (long)(o0 + (l >> 2)) * 200 + t0) =
                make_float4(r[0], r[1], r[2], r[3]);
    }
}

// ---------------------------------------------------------------------------
// conv1 (K=5): float4-of-t, transposed weights, 16 co accumulators.
// ---------------------------------------------------------------------------
template <int K, int PAD, int CI, int COG>
__global__ __launch_bounds__(256) void conv_kernel(const float* __restrict__ x,
                                                   const float* __restrict__ wt,
                                                   float* __restrict__ out,
                                                   int Co, int H, int W,
                                                   int HO, int WO) {
    const int l = threadIdx.x & 63;
    const int wv = threadIdx.x >> 6;
    if (l >= 50) return;
    const int p = blockIdx.x * 4 + wv;
    const int wo = p % WO, ho = p / WO;
    const int co0 = blockIdx.y * COG;
    const int b = blockIdx.z;
    const int t0 = l * 4;
    float4 acc[COG];
    #pragma unroll
    for (int c = 0; c < COG; ++c) acc[c] = make_float4(0.f, 0.f, 0.f, 0.f);
    const float* xb = x + ((long)b * CI * H * W) * 200 + t0;
    for (int ci = 0; ci < CI; ++ci) {
        #pragma unroll
        for (int kh = 0; kh < K; ++kh) {
            const int hi = ho + kh - PAD;
            if (hi < 0 || hi >= H) continue;
            #pragma unroll
            for (int kw = 0; kw < K; ++kw) {
                const int wi = wo + kw - PAD;
                if (wi < 0 || wi >= W) continue;
                const float4 v = *reinterpret_cast<const float4*>(
                    xb + ((long)(ci * H + hi) * W + wi) * 200);
                const float* wp = wt + ((ci * K + kh) * K + kw) * Co + co0;
                #pragma unroll
                for (int c = 0; c < COG; ++c) {
                    const float wv_ = wp[c];
                    acc[c].x = fmaf(wv_, v.x, acc[c].x);
                    acc[c].y = fmaf(wv_, v.y, acc[c].y);
                    acc[c].z = fmaf(wv_, v.z, acc[c].z);
                    acc[c].w = fmaf(wv_, v.w, acc[c].w);
                }
            }
        }
    }
    const long hwN = (long)HO * WO;
    const long ob = ((long)(b * Co + co0) * HO + ho) * WO + wo;
    #pragma unroll
    for (int c = 0; c < COG; ++c)
        *reinterpret_cast<float4*>(out + (ob + c * hwN) * 200 + t0) = acc[c];
}

// ---------------------------------------------------------------------------
// K=3 convs: ci-software-pipelined, zero-filled OOB taps (bit-exact).
// ---------------------------------------------------------------------------
template <int CI, int COG>
__global__ __launch_bounds__(256) void conv3_kernel(const float* __restrict__ x,
                                                    const float* __restrict__ wt,
                                                    float* __restrict__ out,
                                                    int Co, int H, int W) {
    const int l = threadIdx.x & 63;
    const int wv = threadIdx.x >> 6;
    if (l >= 50) return;
    const int p = blockIdx.x * 4 + wv;
    const int wo = p % W, ho = p / W;
    const int co0 = blockIdx.y * COG;
    const int b = blockIdx.z;
    const int t0 = l * 4;
    float4 acc[COG];
    #pragma unroll
    for (int c = 0; c < COG; ++c) acc[c] = make_float4(0.f, 0.f, 0.f, 0.f);

    bool vm[9];
    #pragma unroll
    for (int i = 0; i < 9; ++i) {
        const int hi = ho + i / 3 - 1, wi = wo + i % 3 - 1;
        vm[i] = (hi >= 0) && (hi < H) && (wi >= 0) && (wi < W);
    }
    const long cis = (long)H * W * 200;
    const float* pb = x + (long)b * CI * cis + ((long)(ho - 1) * W + (wo - 1)) * 200 + t0;

    float4 bufA[9], bufB[9];
    auto ld = [&](int ci, float4 (&B)[9]) {
        const float* pc = pb + ci * cis;
        #pragma unroll
        for (int i = 0; i < 9; ++i) {
            B[i] = vm[i] ? *reinterpret_cast<const float4*>(pc + ((i / 3) * W + (i % 3)) * 200)
                         : make_float4(0.f, 0.f, 0.f, 0.f);
        }
    };
    auto fm = [&](const float4 (&B)[9], int ci) {
        #pragma unroll
        for (int i = 0; i < 9; ++i) {
            const float* wp = wt + (ci * 9 + i) * Co + co0;
            #pragma unroll
            for (int c = 0; c < COG; ++c) {
                const float wv_ = wp[c];
                acc[c].x = fmaf(wv_, B[i].x, acc[c].x);
                acc[c].y = fmaf(wv_, B[i].y, acc[c].y);
                acc[c].z = fmaf(wv_, B[i].z, acc[c].z);
                acc[c].w = fmaf(wv_, B[i].w, acc[c].w);
            }
        }
    };

    ld(0, bufA);
    #pragma unroll 1
    for (int ci = 0; ci < CI; ci += 2) {
        ld(ci + 1, bufB);
        fm(bufA, ci);
        if (ci + 2 < CI) ld(ci + 2, bufA);
        fm(bufB, ci + 1);
    }

    const long hwN = (long)H * W;
    const long ob = ((long)(b * Co + co0) * H + ho) * W + wo;
    #pragma unroll
    for (int c = 0; c < COG; ++c)
        *reinterpret_cast<float4*>(out + (ob + c * hwN) * 200 + t0) = acc[c];
}

// ---------------------------------------------------------------------------
// Standalone spike scan (only the tiny final fc->spike uses this now).
// ---------------------------------------------------------------------------
__global__ __launch_bounds__(256) void spike_kernel(const float* __restrict__ v,
                                                    float* __restrict__ s,
                                                    const float* __restrict__ rkt,
                                                    int n) {
    const int nid = blockIdx.x * 256 + threadIdx.x;
    if (nid >= n) return;
    float rk[15];
    #pragma unroll
    for (int i = 0; i < 15; ++i) rk[i] = rkt[i];
    float p[15];
    #pragma unroll
    for (int i = 0; i < 15; ++i) p[i] = 0.0f;
    const float* vp = v + (long)nid * 200;
    float* sp = s + (long)nid * 200;
    for (int t = 0; t < 200; ++t) {
        const float u = vp[t] + p[0];
        const float sv = (u >= THETA) ? 1.0f : 0.0f;
        sp[t] = sv;
        #pragma unroll
        for (int i = 0; i < 14; ++i) p[i] = fmaf(sv, rk[i], p[i + 1]);
        p[14] = sv * rk[14];
    }
}

// ---------------------------------------------------------------------------
// FC: out[b,k,t] = sum_{c,h,w} x[b,c,h,w,t] * Wfc[k,c,h,w]; grid.z = t-half.
// ---------------------------------------------------------------------------
__global__ __launch_bounds__(64) void fc_kernel(const float* __restrict__ x,
                                                const float* __restrict__ wf,
                                                float* __restrict__ out) {
    const int k = blockIdx.x, b = blockIdx.y, l = threadIdx.x;
    if (l >= 25) return;
    const int t0 = blockIdx.z * 100 + l * 4;
    float4 acc = make_float4(0.f, 0.f, 0.f, 0.f);
    for (int c = 0; c < 64; ++c)
        #pragma unroll
        for (int h = 0; h < 6; ++h)
            #pragma unroll
            for (int w = 0; w < 6; ++w) {
                const float4 v = *reinterpret_cast<const float4*>(
                    x + (((long)(b * 64 + c) * 6 + h) * 6 + w) * 200 + t0);
                const float wv_ = wf[((k * 64 + c) * 6 + h) * 6 + w];
                acc.x = fmaf(wv_, v.x, acc.x);
                acc.y = fmaf(wv_, v.y, acc.y);
                acc.z = fmaf(wv_, v.z, acc.z);
                acc.w = fmaf(wv_, v.w, acc.w);
            }
    *reinterpret_cast<float4*>(out + ((long)b * 10 + k) * 200 + t0) = acc;
}

extern "C" void kernel_launch(void* const* d_in, const int* in_sizes, int n_in,
                              void* d_out, int out_size, void* d_ws, size_t ws_size,
                              hipStream_t stream) {
    const float* x_in = (const float*)d_in[0];  // (4,2,50,50,200)
    const float* W1 = (const float*)d_in[1];    // (16,2,5,5)
    const float* W2 = (const float*)d_in[2];    // (32,16,3,3)
    const float* W3 = (const float*)d_in[3];    // (64,32,3,3)
    const float* W4 = (const float*)d_in[4];    // (64,64,3,3)
    const float* Wfc = (const float*)d_in[5];   // (10,64,6,6)
    float* outp = (float*)d_out;                // (4,10,200)

    float* ws = (float*)d_ws;
    float* hh  = ws;                  // 112
    float* rk  = ws + 112;            // 15 (+1 pad)
    float* wt1 = ws + 128;            // 800
    float* wt2 = wt1 + 800;           // 4608
    float* wt3 = wt2 + 4608;          // 18432
    float* wt4 = wt3 + 18432;         // 36864
    float* A   = wt4 + 36864;         // 7,372,800
    float* B   = A + 7372800;         // 29,491,200
    float* C   = B + 29491200;        // 14,745,600

    hipLaunchKernelGGL(prep_kernel, dim3(238), dim3(256), 0, stream,
                       W1, W2, W3, W4, hh, rk, wt1, wt2, wt3, wt4);

    // p0 = psp(input): 20000 series (no scan)
    hipLaunchKernelGGL((spikepsp_kernel<false>), dim3(313), dim3(256), 0, stream,
                       x_in, A, hh, rk, 20000);
    // c1 = conv1(p0): (4,16,48,48,200)
    hipLaunchKernelGGL((conv_kernel<5, 1, 2, 16>), dim3(2304 / 4, 1, 4), dim3(256), 0, stream,
                       A, wt1, B, 16, 50, 50, 48, 48);
    // o1 = pool(psp(spike(c1))): 36864 outputs
    hipLaunchKernelGGL(spikepsppool_kernel, dim3(36864 / 16), dim3(256), 0, stream,
                       B, A, hh, rk, 16, 24, 24);
    // p2 = psp(spike(o1)): 36864 series
    hipLaunchKernelGGL((spikepsp_kernel<true>), dim3(36864 / 64), dim3(256), 0, stream,
                       A, B, hh, rk, 36864);
    // c2 = conv2(p2): (4,32,24,24,200)
    hipLaunchKernelGGL((conv3_kernel<16, 8>), dim3(576 / 4, 4, 4), dim3(256), 0, stream,
                       B, wt2, C, 32, 24, 24);
    // o2 = pool(psp(spike(c2))): 18432 outputs
    hipLaunchKernelGGL(spikepsppool_kernel, dim3(18432 / 16), dim3(256), 0, stream,
                       C, A, hh, rk, 32, 12, 12);
    // p4 = psp(spike(o2)): 18432 series
    hipLaunchKernelGGL((spikepsp_kernel<true>), dim3(18432 / 64), dim3(256), 0, stream,
                       A, B, hh, rk, 18432);
    // c3 = conv3(p4): (4,64,12,12,200)
    hipLaunchKernelGGL((conv3_kernel<32, 8>), dim3(144 / 4, 8, 4), dim3(256), 0, stream,
                       B, wt3, C, 64, 12, 12);
    // o3 = pool(psp(spike(c3))): 9216 outputs
    hipLaunchKernelGGL(spikepsppool_kernel, dim3(9216 / 16), dim3(256), 0, stream,
                       C, A, hh, rk, 64, 6, 6);
    // p6 = psp(spike(o3)): 9216 series
    hipLaunchKernelGGL((spikepsp_kernel<true>), dim3(9216 / 64), dim3(256), 0, stream,
                       A, B, hh, rk, 9216);
    // c4 = conv4(p6): (4,64,6,6,200)
    hipLaunchKernelGGL((conv3_kernel<64, 4>), dim3(36 / 4, 16, 4), dim3(256), 0, stream,
                       B, wt4, C, 64, 6, 6);
    // p7 = psp(spike(c4)): 9216 series
    hipLaunchKernelGGL((spikepsp_kernel<true>), dim3(9216 / 64), dim3(256), 0, stream,
                       C, B, hh, rk, 9216);
    // fc: (4,10,200)
    hipLaunchKernelGGL(fc_kernel, dim3(10, 4, 2), dim3(64), 0, stream, B, Wfc, A);
    // final spike -> d_out: 40 series
    hipLaunchKernelGGL(spike_kernel, dim3(1), dim3(256), 0, stream, A, outp, rk, 40);
    (void)in_sizes; (void)n_in; (void)out_size; (void)ws_size;
}

// Round 6
// 891.243 us; speedup vs baseline: 3.4399x; 1.0209x over previous
//
#include <hip/hip_runtime.h>
#include <math.h>

// ---------------------------------------------------------------------------
// SNN forward: psp (K=100 alpha FIR) -> conv/pool/fc -> spike (refractory scan)
// All arithmetic mirrors the JAX reference's f32 association order.
// Round 6: fused FIR kernels switched to row-major LDS tile [series][204]
// (gcd(204,32)=4 -> b128 accesses hit all 32 banks uniformly).  Staging,
// scan, and FIR are all single ds_*_b128 ops — kills the 5.4M bank
// conflicts of round 5.  Math order unchanged (bit-exact).
// ---------------------------------------------------------------------------

#define THETA 10.0f
#define RSTRIDE 204   // words per series row: 200 + pad4; 16B aligned, gcd(.,32)=4

// hh[q] = h[q-3] for q-3 in [0,99], else 0.  h[k] = (k/10)*exp(1-k/10)
// rk[i] = REF_KERNEL[i+1] = (-40*(i+1))*exp(1-(i+1)),  i=0..14
// wtN = transposed weights: wt[(ci*K*K + tap)*Co + co] = W[co][ci][tap]
__global__ void prep_kernel(const float* __restrict__ W1, const float* __restrict__ W2,
                            const float* __restrict__ W3, const float* __restrict__ W4,
                            float* hh, float* rk,
                            float* wt1, float* wt2, float* wt3, float* wt4) {
    int i = blockIdx.x * 256 + threadIdx.x;
    if (i < 112) {
        int q = i - 3;
        float val = 0.0f;
        if (q >= 0 && q <= 99) {
            float tf = (float)q;
            float x = tf / 10.0f;
            val = x * (float)exp((double)(1.0f - x));
        }
        hh[i] = val;
    } else if (i < 128) {
        int j = i - 112;
        if (j < 15) {
            float t = (float)(j + 1);
            rk[j] = (-40.0f * t) * (float)exp((double)(1.0f - t));
        }
    } else if (i < 928) {            // W1: 16 x 50
        int j = i - 128, co = j / 50, tp = j % 50;
        wt1[tp * 16 + co] = W1[j];
    } else if (i < 5536) {           // W2: 32 x 144
        int j = i - 928, co = j / 144, tp = j % 144;
        wt2[tp * 32 + co] = W2[j];
    } else if (i < 23968) {          // W3: 64 x 288
        int j = i - 5536, co = j / 288, tp = j % 288;
        wt3[tp * 64 + co] = W3[j];
    } else if (i < 60832) {          // W4: 64 x 576
        int j = i - 23968, co = j / 576, tp = j % 576;
        wt4[tp * 64 + co] = W4[j];
    }
}

// 16-FMA inner step, order identical to round 1 (qw,qz,qy,qx; k ascending
// per accumulator).  h0 = hh[m0..m0+3], h1 = hh[m0+4..m0+7].
#define FIR_STEP(A0, A1, A2, A3, qx, qy, qz, qw, h0, h1)  \
    A0 = fmaf(h0.x, qw, A0);                              \
    A1 = fmaf(h0.y, qw, A1);                              \
    A2 = fmaf(h0.z, qw, A2);                              \
    A3 = fmaf(h0.w, qw, A3);                              \
    A0 = fmaf(h0.y, qz, A0);                              \
    A1 = fmaf(h0.z, qz, A1);                              \
    A2 = fmaf(h0.w, qz, A2);                              \
    A3 = fmaf(h1.x, qz, A3);                              \
    A0 = fmaf(h0.z, qy, A0);                              \
    A1 = fmaf(h0.w, qy, A1);                              \
    A2 = fmaf(h1.x, qy, A2);                              \
    A3 = fmaf(h1.y, qy, A3);                              \
    A0 = fmaf(h0.w, qx, A0);                              \
    A1 = fmaf(h1.x, qx, A1);                              \
    A2 = fmaf(h1.y, qx, A2);                              \
    A3 = fmaf(h1.z, qx, A3);

// 4 sequential scan steps on a float4 (ascending t), identical math.
#define SCAN4(XV, p, rk)                                          \
    {                                                             \
        float u_, sv_;                                            \
        u_ = XV.x + p[0]; sv_ = (u_ >= THETA) ? 1.0f : 0.0f;      \
        XV.x = sv_;                                               \
        _Pragma("unroll")                                         \
        for (int i_ = 0; i_ < 14; ++i_) p[i_] = fmaf(sv_, rk[i_], p[i_ + 1]); \
        p[14] = sv_ * rk[14];                                     \
        u_ = XV.y + p[0]; sv_ = (u_ >= THETA) ? 1.0f : 0.0f;      \
        XV.y = sv_;                                               \
        _Pragma("unroll")                                         \
        for (int i_ = 0; i_ < 14; ++i_) p[i_] = fmaf(sv_, rk[i_], p[i_ + 1]); \
        p[14] = sv_ * rk[14];                                     \
        u_ = XV.z + p[0]; sv_ = (u_ >= THETA) ? 1.0f : 0.0f;      \
        XV.z = sv_;                                               \
        _Pragma("unroll")                                         \
        for (int i_ = 0; i_ < 14; ++i_) p[i_] = fmaf(sv_, rk[i_], p[i_ + 1]); \
        p[14] = sv_ * rk[14];                                     \
        u_ = XV.w + p[0]; sv_ = (u_ >= THETA) ? 1.0f : 0.0f;      \
        XV.w = sv_;                                               \
        _Pragma("unroll")                                         \
        for (int i_ = 0; i_ < 14; ++i_) p[i_] = fmaf(sv_, rk[i_], p[i_ + 1]); \
        p[14] = sv_ * rk[14];                                     \
    }

// ---------------------------------------------------------------------------
// Fused [spike ->] psp.  Block = 64 series, LDS tile row-major [64][204].
// Stage (b128 write) -> wave-0 in-LDS scan (b128 r/w, 4 reg steps) ->
// FIR: wave w does chunks c%4==w for all 64 series (lane = series),
// one b128 read + 16 FMA per g.
// ---------------------------------------------------------------------------
template <bool SCAN>
__global__ __launch_bounds__(256) void spikepsp_kernel(const float* __restrict__ in,
                                                       float* __restrict__ out,
                                                       const float* __restrict__ hh,
                                                       const float* __restrict__ rkt,
                                                       int n) {
    __shared__ __align__(16) float tile[64 * RSTRIDE];
    const int l = threadIdx.x & 63;
    const int w = threadIdx.x >> 6;
    const int s0 = blockIdx.x * 64;
    for (int i = threadIdx.x; i < 3200; i += 256) {
        const int slot = i / 50, q = i - slot * 50;
        const int ser = s0 + slot;
        float4 v = make_float4(0.f, 0.f, 0.f, 0.f);
        if (ser < n) v = *reinterpret_cast<const float4*>(in + (long)ser * 200 + 4 * q);
        *reinterpret_cast<float4*>(&tile[slot * RSTRIDE + 4 * q]) = v;
    }
    __syncthreads();
    if (SCAN) {
        if (w == 0) {
            float rk[15];
            #pragma unroll
            for (int i = 0; i < 15; ++i) rk[i] = rkt[i];
            float p[15];
            #pragma unroll
            for (int i = 0; i < 15; ++i) p[i] = 0.0f;
            float* row = tile + l * RSTRIDE;
            for (int tq = 0; tq < 50; ++tq) {
                float4 xv = *reinterpret_cast<const float4*>(&row[4 * tq]);
                SCAN4(xv, p, rk)
                *reinterpret_cast<float4*>(&row[4 * tq]) = xv;
            }
        }
        __syncthreads();
    }
    const bool valid = (s0 + l) < n;
    const float* row = tile + l * RSTRIDE;
    for (int c = w; c < 50; c += 4) {
        const int t0 = 4 * c;
        float a0 = 0.f, a1 = 0.f, a2 = 0.f, a3 = 0.f;
        const int gmax = (c < 25) ? c : 25;
        float4 h0 = *reinterpret_cast<const float4*>(hh);
        const float* bp = row + t0;
        for (int g = 0; g <= gmax; ++g) {
            const float4 h1 = *reinterpret_cast<const float4*>(hh + 4 * g + 4);
            const float4 qv = *reinterpret_cast<const float4*>(bp);
            FIR_STEP(a0, a1, a2, a3, qv.x, qv.y, qv.z, qv.w, h0, h1)
            h0 = h1;
            bp -= 4;
        }
        if (valid)
            *reinterpret_cast<float4*>(out + (long)(s0 + l) * 200 + t0) =
                make_float4(a0, a1, a2, a3);
    }
}

// ---------------------------------------------------------------------------
// Fused spike -> psp -> 2x2 sum-pool (*11).  Block = 16 outputs = 64 input
// series (slot = 4*oi + pixel).  Same tile layout; pool combine = in-order
// quad shuffle sum ((p0+p1)+p2)+p3 then *11 — bit-identical to unfused.
// ---------------------------------------------------------------------------
__global__ __launch_bounds__(256) void spikepsppool_kernel(const float* __restrict__ in,
                                                           float* __restrict__ out,
                                                           const float* __restrict__ hh,
                                                           const float* __restrict__ rkt,
                                                           int C, int HO, int WO) {
    __shared__ __align__(16) float tile[64 * RSTRIDE];
    __shared__ int sbase[64];
    const int l = threadIdx.x & 63;
    const int w = threadIdx.x >> 6;
    const int o0 = blockIdx.x * 16;
    const int H = 2 * HO, W = 2 * WO;
    if (threadIdx.x < 64) {
        const int oi = threadIdx.x >> 2, p = threadIdx.x & 3;
        const int o = o0 + oi;
        const int wo = o % WO; int tmp = o / WO;
        const int ho = tmp % HO; tmp /= HO;
        const int c = tmp % C; const int b = tmp / C;
        sbase[threadIdx.x] = ((b * C + c) * H + 2 * ho + (p >> 1)) * W + 2 * wo + (p & 1);
    }
    __syncthreads();
    for (int i = threadIdx.x; i < 3200; i += 256) {
        const int slot = i / 50, q = i - slot * 50;
        const float4 v = *reinterpret_cast<const float4*>(in + (long)sbase[slot] * 200 + 4 * q);
        *reinterpret_cast<float4*>(&tile[slot * RSTRIDE + 4 * q]) = v;
    }
    __syncthreads();
    if (w == 0) {
        float rk[15];
        #pragma unroll
        for (int i = 0; i < 15; ++i) rk[i] = rkt[i];
        float p[15];
        #pragma unroll
        for (int i = 0; i < 15; ++i) p[i] = 0.0f;
        float* row = tile + l * RSTRIDE;
        for (int tq = 0; tq < 50; ++tq) {
            float4 xv = *reinterpret_cast<const float4*>(&row[4 * tq]);
            SCAN4(xv, p, rk)
            *reinterpret_cast<float4*>(&row[4 * tq]) = xv;
        }
    }
    __syncthreads();
    const int qb = l & ~3;
    const float* row = tile + l * RSTRIDE;
    for (int c = w; c < 50; c += 4) {
        const int t0 = 4 * c;
        float a0 = 0.f, a1 = 0.f, a2 = 0.f, a3 = 0.f;
        const int gmax = (c < 25) ? c : 25;
        float4 h0 = *reinterpret_cast<const float4*>(hh);
        const float* bp = row + t0;
        for (int g = 0; g <= gmax; ++g) {
            const float4 h1 = *reinterpret_cast<const float4*>(hh + 4 * g + 4);
            const float4 qv = *reinterpret_cast<const float4*>(bp);
            FIR_STEP(a0, a1, a2, a3, qv.x, qv.y, qv.z, qv.w, h0, h1)
            h0 = h1;
            bp -= 4;
        }
        float r[4];
        float av[4] = {a0, a1, a2, a3};
        #pragma unroll
        for (int i = 0; i < 4; ++i) {
            const float v0 = __shfl(av[i], qb + 0);
            const float v1 = __shfl(av[i], qb + 1);
            const float v2 = __shfl(av[i], qb + 2);
            const float v3 = __shfl(av[i], qb + 3);
            r[i] = (((v0 + v1) + v2) + v3) * 11.0f;
        }
        if ((l & 3) == 0)
            *reinterpret_cast<float4*>(out + (long)(o0 + (l >> 2)) * 200 + t0) =
                make_float4(r[0], r[1], r[2], r[3]);
    }
}

// ---------------------------------------------------------------------------
// conv1 (K=5): float4-of-t, transposed weights, 16 co accumulators.
// ---------------------------------------------------------------------------
template <int K, int PAD, int CI, int COG>
__global__ __launch_bounds__(256) void conv_kernel(const float* __restrict__ x,
                                                   const float* __restrict__ wt,
                                                   float* __restrict__ out,
                                                   int Co, int H, int W,
                                                   int HO, int WO) {
    const int l = threadIdx.x & 63;
    const int wv = threadIdx.x >> 6;
    if (l >= 50) return;
    const int p = blockIdx.x * 4 + wv;
    const int wo = p % WO, ho = p / WO;
    const int co0 = blockIdx.y * COG;
    const int b = blockIdx.z;
    const int t0 = l * 4;
    float4 acc[COG];
    #pragma unroll
    for (int c = 0; c < COG; ++c) acc[c] = make_float4(0.f, 0.f, 0.f, 0.f);
    const float* xb = x + ((long)b * CI * H * W) * 200 + t0;
    for (int ci = 0; ci < CI; ++ci) {
        #pragma unroll
        for (int kh = 0; kh < K; ++kh) {
            const int hi = ho + kh - PAD;
            if (hi < 0 || hi >= H) continue;
            #pragma unroll
            for (int kw = 0; kw < K; ++kw) {
                const int wi = wo + kw - PAD;
                if (wi < 0 || wi >= W) continue;
                const float4 v = *reinterpret_cast<const float4*>(
                    xb + ((long)(ci * H + hi) * W + wi) * 200);
                const float* wp = wt + ((ci * K + kh) * K + kw) * Co + co0;
                #pragma unroll
                for (int c = 0; c < COG; ++c) {
                    const float wv_ = wp[c];
                    acc[c].x = fmaf(wv_, v.x, acc[c].x);
                    acc[c].y = fmaf(wv_, v.y, acc[c].y);
                    acc[c].z = fmaf(wv_, v.z, acc[c].z);
                    acc[c].w = fmaf(wv_, v.w, acc[c].w);
                }
            }
        }
    }
    const long hwN = (long)HO * WO;
    const long ob = ((long)(b * Co + co0) * HO + ho) * WO + wo;
    #pragma unroll
    for (int c = 0; c < COG; ++c)
        *reinterpret_cast<float4*>(out + (ob + c * hwN) * 200 + t0) = acc[c];
}

// ---------------------------------------------------------------------------
// K=3 convs: ci-software-pipelined, zero-filled OOB taps (bit-exact).
// ---------------------------------------------------------------------------
template <int CI, int COG>
__global__ __launch_bounds__(256) void conv3_kernel(const float* __restrict__ x,
                                                    const float* __restrict__ wt,
                                                    float* __restrict__ out,
                                                    int Co, int H, int W) {
    const int l = threadIdx.x & 63;
    const int wv = threadIdx.x >> 6;
    if (l >= 50) return;
    const int p = blockIdx.x * 4 + wv;
    const int wo = p % W, ho = p / W;
    const int co0 = blockIdx.y * COG;
    const int b = blockIdx.z;
    const int t0 = l * 4;
    float4 acc[COG];
    #pragma unroll
    for (int c = 0; c < COG; ++c) acc[c] = make_float4(0.f, 0.f, 0.f, 0.f);

    bool vm[9];
    #pragma unroll
    for (int i = 0; i < 9; ++i) {
        const int hi = ho + i / 3 - 1, wi = wo + i % 3 - 1;
        vm[i] = (hi >= 0) && (hi < H) && (wi >= 0) && (wi < W);
    }
    const long cis = (long)H * W * 200;
    const float* pb = x + (long)b * CI * cis + ((long)(ho - 1) * W + (wo - 1)) * 200 + t0;

    float4 bufA[9], bufB[9];
    auto ld = [&](int ci, float4 (&B)[9]) {
        const float* pc = pb + ci * cis;
        #pragma unroll
        for (int i = 0; i < 9; ++i) {
            B[i] = vm[i] ? *reinterpret_cast<const float4*>(pc + ((i / 3) * W + (i % 3)) * 200)
                         : make_float4(0.f, 0.f, 0.f, 0.f);
        }
    };
    auto fm = [&](const float4 (&B)[9], int ci) {
        #pragma unroll
        for (int i = 0; i < 9; ++i) {
            const float* wp = wt + (ci * 9 + i) * Co + co0;
            #pragma unroll
            for (int c = 0; c < COG; ++c) {
                const float wv_ = wp[c];
                acc[c].x = fmaf(wv_, B[i].x, acc[c].x);
                acc[c].y = fmaf(wv_, B[i].y, acc[c].y);
                acc[c].z = fmaf(wv_, B[i].z, acc[c].z);
                acc[c].w = fmaf(wv_, B[i].w, acc[c].w);
            }
        }
    };

    ld(0, bufA);
    #pragma unroll 1
    for (int ci = 0; ci < CI; ci += 2) {
        ld(ci + 1, bufB);
        fm(bufA, ci);
        if (ci + 2 < CI) ld(ci + 2, bufA);
        fm(bufB, ci + 1);
    }

    const long hwN = (long)H * W;
    const long ob = ((long)(b * Co + co0) * H + ho) * W + wo;
    #pragma unroll
    for (int c = 0; c < COG; ++c)
        *reinterpret_cast<float4*>(out + (ob + c * hwN) * 200 + t0) = acc[c];
}

// ---------------------------------------------------------------------------
// Standalone spike scan (only the tiny final fc->spike uses this now).
// ---------------------------------------------------------------------------
__global__ __launch_bounds__(256) void spike_kernel(const float* __restrict__ v,
                                                    float* __restrict__ s,
                                                    const float* __restrict__ rkt,
                                                    int n) {
    const int nid = blockIdx.x * 256 + threadIdx.x;
    if (nid >= n) return;
    float rk[15];
    #pragma unroll
    for (int i = 0; i < 15; ++i) rk[i] = rkt[i];
    float p[15];
    #pragma unroll
    for (int i = 0; i < 15; ++i) p[i] = 0.0f;
    const float* vp = v + (long)nid * 200;
    float* sp = s + (long)nid * 200;
    for (int t = 0; t < 200; ++t) {
        const float u = vp[t] + p[0];
        const float sv = (u >= THETA) ? 1.0f : 0.0f;
        sp[t] = sv;
        #pragma unroll
        for (int i = 0; i < 14; ++i) p[i] = fmaf(sv, rk[i], p[i + 1]);
        p[14] = sv * rk[14];
    }
}

// ---------------------------------------------------------------------------
// FC: out[b,k,t] = sum_{c,h,w} x[b,c,h,w,t] * Wfc[k,c,h,w]; grid.z = t-half.
// ---------------------------------------------------------------------------
__global__ __launch_bounds__(64) void fc_kernel(const float* __restrict__ x,
                                                const float* __restrict__ wf,
                                                float* __restrict__ out) {
    const int k = blockIdx.x, b = blockIdx.y, l = threadIdx.x;
    if (l >= 25) return;
    const int t0 = blockIdx.z * 100 + l * 4;
    float4 acc = make_float4(0.f, 0.f, 0.f, 0.f);
    for (int c = 0; c < 64; ++c)
        #pragma unroll
        for (int h = 0; h < 6; ++h)
            #pragma unroll
            for (int w = 0; w < 6; ++w) {
                const float4 v = *reinterpret_cast<const float4*>(
                    x + (((long)(b * 64 + c) * 6 + h) * 6 + w) * 200 + t0);
                const float wv_ = wf[((k * 64 + c) * 6 + h) * 6 + w];
                acc.x = fmaf(wv_, v.x, acc.x);
                acc.y = fmaf(wv_, v.y, acc.y);
                acc.z = fmaf(wv_, v.z, acc.z);
                acc.w = fmaf(wv_, v.w, acc.w);
            }
    *reinterpret_cast<float4*>(out + ((long)b * 10 + k) * 200 + t0) = acc;
}

extern "C" void kernel_launch(void* const* d_in, const int* in_sizes, int n_in,
                              void* d_out, int out_size, void* d_ws, size_t ws_size,
                              hipStream_t stream) {
    const float* x_in = (const float*)d_in[0];  // (4,2,50,50,200)
    const float* W1 = (const float*)d_in[1];    // (16,2,5,5)
    const float* W2 = (const float*)d_in[2];    // (32,16,3,3)
    const float* W3 = (const float*)d_in[3];    // (64,32,3,3)
    const float* W4 = (const float*)d_in[4];    // (64,64,3,3)
    const float* Wfc = (const float*)d_in[5];   // (10,64,6,6)
    float* outp = (float*)d_out;                // (4,10,200)

    float* ws = (float*)d_ws;
    float* hh  = ws;                  // 112
    float* rk  = ws + 112;            // 15 (+1 pad)
    float* wt1 = ws + 128;            // 800
    float* wt2 = wt1 + 800;           // 4608
    float* wt3 = wt2 + 4608;          // 18432
    float* wt4 = wt3 + 18432;         // 36864
    float* A   = wt4 + 36864;         // 7,372,800
    float* B   = A + 7372800;         // 29,491,200
    float* C   = B + 29491200;        // 14,745,600

    hipLaunchKernelGGL(prep_kernel, dim3(238), dim3(256), 0, stream,
                       W1, W2, W3, W4, hh, rk, wt1, wt2, wt3, wt4);

    // p0 = psp(input): 20000 series (no scan)
    hipLaunchKernelGGL((spikepsp_kernel<false>), dim3(313), dim3(256), 0, stream,
                       x_in, A, hh, rk, 20000);
    // c1 = conv1(p0): (4,16,48,48,200)
    hipLaunchKernelGGL((conv_kernel<5, 1, 2, 16>), dim3(2304 / 4, 1, 4), dim3(256), 0, stream,
                       A, wt1, B, 16, 50, 50, 48, 48);
    // o1 = pool(psp(spike(c1))): 36864 outputs
    hipLaunchKernelGGL(spikepsppool_kernel, dim3(36864 / 16), dim3(256), 0, stream,
                       B, A, hh, rk, 16, 24, 24);
    // p2 = psp(spike(o1)): 36864 series
    hipLaunchKernelGGL((spikepsp_kernel<true>), dim3(36864 / 64), dim3(256), 0, stream,
                       A, B, hh, rk, 36864);
    // c2 = conv2(p2): (4,32,24,24,200)
    hipLaunchKernelGGL((conv3_kernel<16, 8>), dim3(576 / 4, 4, 4), dim3(256), 0, stream,
                       B, wt2, C, 32, 24, 24);
    // o2 = pool(psp(spike(c2))): 18432 outputs
    hipLaunchKernelGGL(spikepsppool_kernel, dim3(18432 / 16), dim3(256), 0, stream,
                       C, A, hh, rk, 32, 12, 12);
    // p4 = psp(spike(o2)): 18432 series
    hipLaunchKernelGGL((spikepsp_kernel<true>), dim3(18432 / 64), dim3(256), 0, stream,
                       A, B, hh, rk, 18432);
    // c3 = conv3(p4): (4,64,12,12,200)
    hipLaunchKernelGGL((conv3_kernel<32, 8>), dim3(144 / 4, 8, 4), dim3(256), 0, stream,
                       B, wt3, C, 64, 12, 12);
    // o3 = pool(psp(spike(c3))): 9216 outputs
    hipLaunchKernelGGL(spikepsppool_kernel, dim3(9216 / 16), dim3(256), 0, stream,
                       C, A, hh, rk, 64, 6, 6);
    // p6 = psp(spike(o3)): 9216 series
    hipLaunchKernelGGL((spikepsp_kernel<true>), dim3(9216 / 64), dim3(256), 0, stream,
                       A, B, hh, rk, 9216);
    // c4 = conv4(p6): (4,64,6,6,200)
    hipLaunchKernelGGL((conv3_kernel<64, 4>), dim3(36 / 4, 16, 4), dim3(256), 0, stream,
                       B, wt4, C, 64, 6, 6);
    // p7 = psp(spike(c4)): 9216 series
    hipLaunchKernelGGL((spikepsp_kernel<true>), dim3(9216 / 64), dim3(256), 0, stream,
                       C, B, hh, rk, 9216);
    // fc: (4,10,200)
    hipLaunchKernelGGL(fc_kernel, dim3(10, 4, 2), dim3(64), 0, stream, B, Wfc, A);
    // final spike -> d_out: 40 series
    hipLaunchKernelGGL(spike_kernel, dim3(1), dim3(256), 0, stream, A, outp, rk, 40);
    (void)in_sizes; (void)n_in; (void)out_size; (void)ws_size;
}

// Round 7
// 804.813 us; speedup vs baseline: 3.8094x; 1.1074x over previous
//
#include <hip/hip_runtime.h>
#include <math.h>

// ---------------------------------------------------------------------------
// SNN forward: psp (K=100 alpha FIR) -> conv/pool/fc -> spike (refractory scan)
// All arithmetic mirrors the JAX reference's f32 association order.
// Round 7: FIR kernels widened to 512 threads / 8 waves per 64-series block
// (wave w takes chunks c%8==w).  Same 52KB LDS tile -> 3 blocks/CU but now
// 24 waves/CU (75% occupancy) instead of 12.  Math unchanged (bit-exact).
// ---------------------------------------------------------------------------

#define THETA 10.0f
#define RSTRIDE 204   // words per series row: 200 + pad4; 16B aligned

// hh[q] = h[q-3] for q-3 in [0,99], else 0.  h[k] = (k/10)*exp(1-k/10)
// rk[i] = REF_KERNEL[i+1] = (-40*(i+1))*exp(1-(i+1)),  i=0..14
// wtN = transposed weights: wt[(ci*K*K + tap)*Co + co] = W[co][ci][tap]
__global__ void prep_kernel(const float* __restrict__ W1, const float* __restrict__ W2,
                            const float* __restrict__ W3, const float* __restrict__ W4,
                            float* hh, float* rk,
                            float* wt1, float* wt2, float* wt3, float* wt4) {
    int i = blockIdx.x * 256 + threadIdx.x;
    if (i < 112) {
        int q = i - 3;
        float val = 0.0f;
        if (q >= 0 && q <= 99) {
            float tf = (float)q;
            float x = tf / 10.0f;
            val = x * (float)exp((double)(1.0f - x));
        }
        hh[i] = val;
    } else if (i < 128) {
        int j = i - 112;
        if (j < 15) {
            float t = (float)(j + 1);
            rk[j] = (-40.0f * t) * (float)exp((double)(1.0f - t));
        }
    } else if (i < 928) {            // W1: 16 x 50
        int j = i - 128, co = j / 50, tp = j % 50;
        wt1[tp * 16 + co] = W1[j];
    } else if (i < 5536) {           // W2: 32 x 144
        int j = i - 928, co = j / 144, tp = j % 144;
        wt2[tp * 32 + co] = W2[j];
    } else if (i < 23968) {          // W3: 64 x 288
        int j = i - 5536, co = j / 288, tp = j % 288;
        wt3[tp * 64 + co] = W3[j];
    } else if (i < 60832) {          // W4: 64 x 576
        int j = i - 23968, co = j / 576, tp = j % 576;
        wt4[tp * 64 + co] = W4[j];
    }
}

// 16-FMA inner step, order identical to round 1 (qw,qz,qy,qx; k ascending
// per accumulator).  h0 = hh[m0..m0+3], h1 = hh[m0+4..m0+7].
#define FIR_STEP(A0, A1, A2, A3, qx, qy, qz, qw, h0, h1)  \
    A0 = fmaf(h0.x, qw, A0);                              \
    A1 = fmaf(h0.y, qw, A1);                              \
    A2 = fmaf(h0.z, qw, A2);                              \
    A3 = fmaf(h0.w, qw, A3);                              \
    A0 = fmaf(h0.y, qz, A0);                              \
    A1 = fmaf(h0.z, qz, A1);                              \
    A2 = fmaf(h0.w, qz, A2);                              \
    A3 = fmaf(h1.x, qz, A3);                              \
    A0 = fmaf(h0.z, qy, A0);                              \
    A1 = fmaf(h0.w, qy, A1);                              \
    A2 = fmaf(h1.x, qy, A2);                              \
    A3 = fmaf(h1.y, qy, A3);                              \
    A0 = fmaf(h0.w, qx, A0);                              \
    A1 = fmaf(h1.x, qx, A1);                              \
    A2 = fmaf(h1.y, qx, A2);                              \
    A3 = fmaf(h1.z, qx, A3);

// 4 sequential scan steps on a float4 (ascending t), identical math.
#define SCAN4(XV, p, rk)                                          \
    {                                                             \
        float u_, sv_;                                            \
        u_ = XV.x + p[0]; sv_ = (u_ >= THETA) ? 1.0f : 0.0f;      \
        XV.x = sv_;                                               \
        _Pragma("unroll")                                         \
        for (int i_ = 0; i_ < 14; ++i_) p[i_] = fmaf(sv_, rk[i_], p[i_ + 1]); \
        p[14] = sv_ * rk[14];                                     \
        u_ = XV.y + p[0]; sv_ = (u_ >= THETA) ? 1.0f : 0.0f;      \
        XV.y = sv_;                                               \
        _Pragma("unroll")                                         \
        for (int i_ = 0; i_ < 14; ++i_) p[i_] = fmaf(sv_, rk[i_], p[i_ + 1]); \
        p[14] = sv_ * rk[14];                                     \
        u_ = XV.z + p[0]; sv_ = (u_ >= THETA) ? 1.0f : 0.0f;      \
        XV.z = sv_;                                               \
        _Pragma("unroll")                                         \
        for (int i_ = 0; i_ < 14; ++i_) p[i_] = fmaf(sv_, rk[i_], p[i_ + 1]); \
        p[14] = sv_ * rk[14];                                     \
        u_ = XV.w + p[0]; sv_ = (u_ >= THETA) ? 1.0f : 0.0f;      \
        XV.w = sv_;                                               \
        _Pragma("unroll")                                         \
        for (int i_ = 0; i_ < 14; ++i_) p[i_] = fmaf(sv_, rk[i_], p[i_ + 1]); \
        p[14] = sv_ * rk[14];                                     \
    }

// ---------------------------------------------------------------------------
// Fused [spike ->] psp.  Block = 64 series x 8 waves, LDS tile [64][204].
// Stage (b128) -> wave-0 in-LDS scan -> FIR: wave w does chunks c%8==w for
// all 64 series (lane = series), one b128 read + 16 FMA per g.
// ---------------------------------------------------------------------------
template <bool SCAN>
__global__ __launch_bounds__(512) void spikepsp_kernel(const float* __restrict__ in,
                                                       float* __restrict__ out,
                                                       const float* __restrict__ hh,
                                                       const float* __restrict__ rkt,
                                                       int n) {
    __shared__ __align__(16) float tile[64 * RSTRIDE];
    const int l = threadIdx.x & 63;
    const int w = threadIdx.x >> 6;
    const int s0 = blockIdx.x * 64;
    for (int i = threadIdx.x; i < 3200; i += 512) {
        const int slot = i / 50, q = i - slot * 50;
        const int ser = s0 + slot;
        float4 v = make_float4(0.f, 0.f, 0.f, 0.f);
        if (ser < n) v = *reinterpret_cast<const float4*>(in + (long)ser * 200 + 4 * q);
        *reinterpret_cast<float4*>(&tile[slot * RSTRIDE + 4 * q]) = v;
    }
    __syncthreads();
    if (SCAN) {
        if (w == 0) {
            float rk[15];
            #pragma unroll
            for (int i = 0; i < 15; ++i) rk[i] = rkt[i];
            float p[15];
            #pragma unroll
            for (int i = 0; i < 15; ++i) p[i] = 0.0f;
            float* row = tile + l * RSTRIDE;
            for (int tq = 0; tq < 50; ++tq) {
                float4 xv = *reinterpret_cast<const float4*>(&row[4 * tq]);
                SCAN4(xv, p, rk)
                *reinterpret_cast<float4*>(&row[4 * tq]) = xv;
            }
        }
        __syncthreads();
    }
    const bool valid = (s0 + l) < n;
    const float* row = tile + l * RSTRIDE;
    for (int c = w; c < 50; c += 8) {
        const int t0 = 4 * c;
        float a0 = 0.f, a1 = 0.f, a2 = 0.f, a3 = 0.f;
        const int gmax = (c < 25) ? c : 25;
        float4 h0 = *reinterpret_cast<const float4*>(hh);
        const float* bp = row + t0;
        for (int g = 0; g <= gmax; ++g) {
            const float4 h1 = *reinterpret_cast<const float4*>(hh + 4 * g + 4);
            const float4 qv = *reinterpret_cast<const float4*>(bp);
            FIR_STEP(a0, a1, a2, a3, qv.x, qv.y, qv.z, qv.w, h0, h1)
            h0 = h1;
            bp -= 4;
        }
        if (valid)
            *reinterpret_cast<float4*>(out + (long)(s0 + l) * 200 + t0) =
                make_float4(a0, a1, a2, a3);
    }
}

// ---------------------------------------------------------------------------
// Fused spike -> psp -> 2x2 sum-pool (*11).  Block = 16 outputs = 64 input
// series (slot = 4*oi + pixel), 8 waves.  Pool combine = in-order quad
// shuffle sum ((p0+p1)+p2)+p3 then *11 — bit-identical to unfused.
// ---------------------------------------------------------------------------
__global__ __launch_bounds__(512) void spikepsppool_kernel(const float* __restrict__ in,
                                                           float* __restrict__ out,
                                                           const float* __restrict__ hh,
                                                           const float* __restrict__ rkt,
                                                           int C, int HO, int WO) {
    __shared__ __align__(16) float tile[64 * RSTRIDE];
    __shared__ int sbase[64];
    const int l = threadIdx.x & 63;
    const int w = threadIdx.x >> 6;
    const int o0 = blockIdx.x * 16;
    const int H = 2 * HO, W = 2 * WO;
    if (threadIdx.x < 64) {
        const int oi = threadIdx.x >> 2, p = threadIdx.x & 3;
        const int o = o0 + oi;
        const int wo = o % WO; int tmp = o / WO;
        const int ho = tmp % HO; tmp /= HO;
        const int c = tmp % C; const int b = tmp / C;
        sbase[threadIdx.x] = ((b * C + c) * H + 2 * ho + (p >> 1)) * W + 2 * wo + (p & 1);
    }
    __syncthreads();
    for (int i = threadIdx.x; i < 3200; i += 512) {
        const int slot = i / 50, q = i - slot * 50;
        const float4 v = *reinterpret_cast<const float4*>(in + (long)sbase[slot] * 200 + 4 * q);
        *reinterpret_cast<float4*>(&tile[slot * RSTRIDE + 4 * q]) = v;
    }
    __syncthreads();
    if (w == 0) {
        float rk[15];
        #pragma unroll
        for (int i = 0; i < 15; ++i) rk[i] = rkt[i];
        float p[15];
        #pragma unroll
        for (int i = 0; i < 15; ++i) p[i] = 0.0f;
        float* row = tile + l * RSTRIDE;
        for (int tq = 0; tq < 50; ++tq) {
            float4 xv = *reinterpret_cast<const float4*>(&row[4 * tq]);
            SCAN4(xv, p, rk)
            *reinterpret_cast<float4*>(&row[4 * tq]) = xv;
        }
    }
    __syncthreads();
    const int qb = l & ~3;
    const float* row = tile + l * RSTRIDE;
    for (int c = w; c < 50; c += 8) {
        const int t0 = 4 * c;
        float a0 = 0.f, a1 = 0.f, a2 = 0.f, a3 = 0.f;
        const int gmax = (c < 25) ? c : 25;
        float4 h0 = *reinterpret_cast<const float4*>(hh);
        const float* bp = row + t0;
        for (int g = 0; g <= gmax; ++g) {
            const float4 h1 = *reinterpret_cast<const float4*>(hh + 4 * g + 4);
            const float4 qv = *reinterpret_cast<const float4*>(bp);
            FIR_STEP(a0, a1, a2, a3, qv.x, qv.y, qv.z, qv.w, h0, h1)
            h0 = h1;
            bp -= 4;
        }
        float r[4];
        float av[4] = {a0, a1, a2, a3};
        #pragma unroll
        for (int i = 0; i < 4; ++i) {
            const float v0 = __shfl(av[i], qb + 0);
            const float v1 = __shfl(av[i], qb + 1);
            const float v2 = __shfl(av[i], qb + 2);
            const float v3 = __shfl(av[i], qb + 3);
            r[i] = (((v0 + v1) + v2) + v3) * 11.0f;
        }
        if ((l & 3) == 0)
            *reinterpret_cast<float4*>(out + (long)(o0 + (l >> 2)) * 200 + t0) =
                make_float4(r[0], r[1], r[2], r[3]);
    }
}

// ---------------------------------------------------------------------------
// conv1 (K=5): float4-of-t, transposed weights, 16 co accumulators.
// ---------------------------------------------------------------------------
template <int K, int PAD, int CI, int COG>
__global__ __launch_bounds__(256) void conv_kernel(const float* __restrict__ x,
                                                   const float* __restrict__ wt,
                                                   float* __restrict__ out,
                                                   int Co, int H, int W,
                                                   int HO, int WO) {
    const int l = threadIdx.x & 63;
    const int wv = threadIdx.x >> 6;
    if (l >= 50) return;
    const int p = blockIdx.x * 4 + wv;
    const int wo = p % WO, ho = p / WO;
    const int co0 = blockIdx.y * COG;
    const int b = blockIdx.z;
    const int t0 = l * 4;
    float4 acc[COG];
    #pragma unroll
    for (int c = 0; c < COG; ++c) acc[c] = make_float4(0.f, 0.f, 0.f, 0.f);
    const float* xb = x + ((long)b * CI * H * W) * 200 + t0;
    for (int ci = 0; ci < CI; ++ci) {
        #pragma unroll
        for (int kh = 0; kh < K; ++kh) {
            const int hi = ho + kh - PAD;
            if (hi < 0 || hi >= H) continue;
            #pragma unroll
            for (int kw = 0; kw < K; ++kw) {
                const int wi = wo + kw - PAD;
                if (wi < 0 || wi >= W) continue;
                const float4 v = *reinterpret_cast<const float4*>(
                    xb + ((long)(ci * H + hi) * W + wi) * 200);
                const float* wp = wt + ((ci * K + kh) * K + kw) * Co + co0;
                #pragma unroll
                for (int c = 0; c < COG; ++c) {
                    const float wv_ = wp[c];
                    acc[c].x = fmaf(wv_, v.x, acc[c].x);
                    acc[c].y = fmaf(wv_, v.y, acc[c].y);
                    acc[c].z = fmaf(wv_, v.z, acc[c].z);
                    acc[c].w = fmaf(wv_, v.w, acc[c].w);
                }
            }
        }
    }
    const long hwN = (long)HO * WO;
    const long ob = ((long)(b * Co + co0) * HO + ho) * WO + wo;
    #pragma unroll
    for (int c = 0; c < COG; ++c)
        *reinterpret_cast<float4*>(out + (ob + c * hwN) * 200 + t0) = acc[c];
}

// ---------------------------------------------------------------------------
// K=3 convs: ci-software-pipelined, zero-filled OOB taps (bit-exact).
// ---------------------------------------------------------------------------
template <int CI, int COG>
__global__ __launch_bounds__(256) void conv3_kernel(const float* __restrict__ x,
                                                    const float* __restrict__ wt,
                                                    float* __restrict__ out,
                                                    int Co, int H, int W) {
    const int l = threadIdx.x & 63;
    const int wv = threadIdx.x >> 6;
    if (l >= 50) return;
    const int p = blockIdx.x * 4 + wv;
    const int wo = p % W, ho = p / W;
    const int co0 = blockIdx.y * COG;
    const int b = blockIdx.z;
    const int t0 = l * 4;
    float4 acc[COG];
    #pragma unroll
    for (int c = 0; c < COG; ++c) acc[c] = make_float4(0.f, 0.f, 0.f, 0.f);

    bool vm[9];
    #pragma unroll
    for (int i = 0; i < 9; ++i) {
        const int hi = ho + i / 3 - 1, wi = wo + i % 3 - 1;
        vm[i] = (hi >= 0) && (hi < H) && (wi >= 0) && (wi < W);
    }
    const long cis = (long)H * W * 200;
    const float* pb = x + (long)b * CI * cis + ((long)(ho - 1) * W + (wo - 1)) * 200 + t0;

    float4 bufA[9], bufB[9];
    auto ld = [&](int ci, float4 (&B)[9]) {
        const float* pc = pb + ci * cis;
        #pragma unroll
        for (int i = 0; i < 9; ++i) {
            B[i] = vm[i] ? *reinterpret_cast<const float4*>(pc + ((i / 3) * W + (i % 3)) * 200)
                         : make_float4(0.f, 0.f, 0.f, 0.f);
        }
    };
    auto fm = [&](const float4 (&B)[9], int ci) {
        #pragma unroll
        for (int i = 0; i < 9; ++i) {
            const float* wp = wt + (ci * 9 + i) * Co + co0;
            #pragma unroll
            for (int c = 0; c < COG; ++c) {
                const float wv_ = wp[c];
                acc[c].x = fmaf(wv_, B[i].x, acc[c].x);
                acc[c].y = fmaf(wv_, B[i].y, acc[c].y);
                acc[c].z = fmaf(wv_, B[i].z, acc[c].z);
                acc[c].w = fmaf(wv_, B[i].w, acc[c].w);
            }
        }
    };

    ld(0, bufA);
    #pragma unroll 1
    for (int ci = 0; ci < CI; ci += 2) {
        ld(ci + 1, bufB);
        fm(bufA, ci);
        if (ci + 2 < CI) ld(ci + 2, bufA);
        fm(bufB, ci + 1);
    }

    const long hwN = (long)H * W;
    const long ob = ((long)(b * Co + co0) * H + ho) * W + wo;
    #pragma unroll
    for (int c = 0; c < COG; ++c)
        *reinterpret_cast<float4*>(out + (ob + c * hwN) * 200 + t0) = acc[c];
}

// ---------------------------------------------------------------------------
// Standalone spike scan (only the tiny final fc->spike uses this now).
// ---------------------------------------------------------------------------
__global__ __launch_bounds__(256) void spike_kernel(const float* __restrict__ v,
                                                    float* __restrict__ s,
                                                    const float* __restrict__ rkt,
                                                    int n) {
    const int nid = blockIdx.x * 256 + threadIdx.x;
    if (nid >= n) return;
    float rk[15];
    #pragma unroll
    for (int i = 0; i < 15; ++i) rk[i] = rkt[i];
    float p[15];
    #pragma unroll
    for (int i = 0; i < 15; ++i) p[i] = 0.0f;
    const float* vp = v + (long)nid * 200;
    float* sp = s + (long)nid * 200;
    for (int t = 0; t < 200; ++t) {
        const float u = vp[t] + p[0];
        const float sv = (u >= THETA) ? 1.0f : 0.0f;
        sp[t] = sv;
        #pragma unroll
        for (int i = 0; i < 14; ++i) p[i] = fmaf(sv, rk[i], p[i + 1]);
        p[14] = sv * rk[14];
    }
}

// ---------------------------------------------------------------------------
// FC: out[b,k,t] = sum_{c,h,w} x[b,c,h,w,t] * Wfc[k,c,h,w]; grid.z = t-half.
// ---------------------------------------------------------------------------
__global__ __launch_bounds__(64) void fc_kernel(const float* __restrict__ x,
                                                const float* __restrict__ wf,
                                                float* __restrict__ out) {
    const int k = blockIdx.x, b = blockIdx.y, l = threadIdx.x;
    if (l >= 25) return;
    const int t0 = blockIdx.z * 100 + l * 4;
    float4 acc = make_float4(0.f, 0.f, 0.f, 0.f);
    for (int c = 0; c < 64; ++c)
        #pragma unroll
        for (int h = 0; h < 6; ++h)
            #pragma unroll
            for (int w = 0; w < 6; ++w) {
                const float4 v = *reinterpret_cast<const float4*>(
                    x + (((long)(b * 64 + c) * 6 + h) * 6 + w) * 200 + t0);
                const float wv_ = wf[((k * 64 + c) * 6 + h) * 6 + w];
                acc.x = fmaf(wv_, v.x, acc.x);
                acc.y = fmaf(wv_, v.y, acc.y);
                acc.z = fmaf(wv_, v.z, acc.z);
                acc.w = fmaf(wv_, v.w, acc.w);
            }
    *reinterpret_cast<float4*>(out + ((long)b * 10 + k) * 200 + t0) = acc;
}

extern "C" void kernel_launch(void* const* d_in, const int* in_sizes, int n_in,
                              void* d_out, int out_size, void* d_ws, size_t ws_size,
                              hipStream_t stream) {
    const float* x_in = (const float*)d_in[0];  // (4,2,50,50,200)
    const float* W1 = (const float*)d_in[1];    // (16,2,5,5)
    const float* W2 = (const float*)d_in[2];    // (32,16,3,3)
    const float* W3 = (const float*)d_in[3];    // (64,32,3,3)
    const float* W4 = (const float*)d_in[4];    // (64,64,3,3)
    const float* Wfc = (const float*)d_in[5];   // (10,64,6,6)
    float* outp = (float*)d_out;                // (4,10,200)

    float* ws = (float*)d_ws;
    float* hh  = ws;                  // 112
    float* rk  = ws + 112;            // 15 (+1 pad)
    float* wt1 = ws + 128;            // 800
    float* wt2 = wt1 + 800;           // 4608
    float* wt3 = wt2 + 4608;          // 18432
    float* wt4 = wt3 + 18432;         // 36864
    float* A   = wt4 + 36864;         // 7,372,800
    float* B   = A + 7372800;         // 29,491,200
    float* C   = B + 29491200;        // 14,745,600

    hipLaunchKernelGGL(prep_kernel, dim3(238), dim3(256), 0, stream,
                       W1, W2, W3, W4, hh, rk, wt1, wt2, wt3, wt4);

    // p0 = psp(input): 20000 series (no scan)
    hipLaunchKernelGGL((spikepsp_kernel<false>), dim3(313), dim3(512), 0, stream,
                       x_in, A, hh, rk, 20000);
    // c1 = conv1(p0): (4,16,48,48,200)
    hipLaunchKernelGGL((conv_kernel<5, 1, 2, 16>), dim3(2304 / 4, 1, 4), dim3(256), 0, stream,
                       A, wt1, B, 16, 50, 50, 48, 48);
    // o1 = pool(psp(spike(c1))): 36864 outputs
    hipLaunchKernelGGL(spikepsppool_kernel, dim3(36864 / 16), dim3(512), 0, stream,
                       B, A, hh, rk, 16, 24, 24);
    // p2 = psp(spike(o1)): 36864 series
    hipLaunchKernelGGL((spikepsp_kernel<true>), dim3(36864 / 64), dim3(512), 0, stream,
                       A, B, hh, rk, 36864);
    // c2 = conv2(p2): (4,32,24,24,200)
    hipLaunchKernelGGL((conv3_kernel<16, 8>), dim3(576 / 4, 4, 4), dim3(256), 0, stream,
                       B, wt2, C, 32, 24, 24);
    // o2 = pool(psp(spike(c2))): 18432 outputs
    hipLaunchKernelGGL(spikepsppool_kernel, dim3(18432 / 16), dim3(512), 0, stream,
                       C, A, hh, rk, 32, 12, 12);
    // p4 = psp(spike(o2)): 18432 series
    hipLaunchKernelGGL((spikepsp_kernel<true>), dim3(18432 / 64), dim3(512), 0, stream,
                       A, B, hh, rk, 18432);
    // c3 = conv3(p4): (4,64,12,12,200)
    hipLaunchKernelGGL((conv3_kernel<32, 8>), dim3(144 / 4, 8, 4), dim3(256), 0, stream,
                       B, wt3, C, 64, 12, 12);
    // o3 = pool(psp(spike(c3))): 9216 outputs
    hipLaunchKernelGGL(spikepsppool_kernel, dim3(9216 / 16), dim3(512), 0, stream,
                       C, A, hh, rk, 64, 6, 6);
    // p6 = psp(spike(o3)): 9216 series
    hipLaunchKernelGGL((spikepsp_kernel<true>), dim3(9216 / 64), dim3(512), 0, stream,
                       A, B, hh, rk, 9216);
    // c4 = conv4(p6): (4,64,6,6,200)
    hipLaunchKernelGGL((conv3_kernel<64, 4>), dim3(36 / 4, 16, 4), dim3(256), 0, stream,
                       B, wt4, C, 64, 6, 6);
    // p7 = psp(spike(c4)): 9216 series
    hipLaunchKernelGGL((spikepsp_kernel<true>), dim3(9216 / 64), dim3(512), 0, stream,
                       C, B, hh, rk, 9216);
    // fc: (4,10,200)
    hipLaunchKernelGGL(fc_kernel, dim3(10, 4, 2), dim3(64), 0, stream, B, Wfc, A);
    // final spike -> d_out: 40 series
    hipLaunchKernelGGL(spike_kernel, dim3(1), dim3(256), 0, stream, A, outp, rk, 40);
    (void)in_sizes; (void)n_in; (void)out_size; (void)ws_size;
}

// Round 8
// 730.941 us; speedup vs baseline: 4.1943x; 1.1011x over previous
//
#include <hip/hip_runtime.h>
#include <math.h>

// ---------------------------------------------------------------------------
// SNN forward: psp (K=100 alpha FIR) -> conv/pool/fc -> spike (refractory scan)
// All arithmetic mirrors the JAX reference's f32 association order.
// Round 8: FIR restructured to 16 outputs/lane/item (4 sub-chunks share each
// ds_read_b128 -> 64 FMA per 16B LDS read, 4x arithmetic intensity; was
// LDS-BW-bound at 128 B/cyc demand vs 85 B/cyc ceiling).  Zero-padded
// coefficient table HQ makes out-of-range taps exact no-ops — bit-exact,
// branch-free.  Math order per accumulator unchanged.
// ---------------------------------------------------------------------------

#define THETA 10.0f
#define RSTRIDE 204   // words per series row: 200 + pad4; 16B aligned

// HQ[i] = h[i-15] for 15<=i<=114 (h[k] = (k/10)*exp(1-k/10)), else 0. 144 entries.
// rk[i] = REF_KERNEL[i+1] = (-40*(i+1))*exp(1-(i+1)),  i=0..14
// wtN = transposed weights: wt[(ci*K*K + tap)*Co + co] = W[co][ci][tap]
__global__ void prep_kernel(const float* __restrict__ W1, const float* __restrict__ W2,
                            const float* __restrict__ W3, const float* __restrict__ W4,
                            float* HQ, float* rk,
                            float* wt1, float* wt2, float* wt3, float* wt4) {
    int i = blockIdx.x * 256 + threadIdx.x;
    if (i < 144) {
        int k = i - 15;
        float val = 0.0f;
        if (k >= 0 && k <= 99) {
            float tf = (float)k;
            float x = tf / 10.0f;
            val = x * (float)exp((double)(1.0f - x));   // same expr as prior rounds
        }
        HQ[i] = val;
    } else if (i < 160) {
        int j = i - 144;
        if (j < 15) {
            float t = (float)(j + 1);
            rk[j] = (-40.0f * t) * (float)exp((double)(1.0f - t));
        }
    } else if (i < 960) {            // W1: 16 x 50
        int j = i - 160, co = j / 50, tp = j % 50;
        wt1[tp * 16 + co] = W1[j];
    } else if (i < 5568) {           // W2: 32 x 144
        int j = i - 960, co = j / 144, tp = j % 144;
        wt2[tp * 32 + co] = W2[j];
    } else if (i < 24000) {          // W3: 64 x 288
        int j = i - 5568, co = j / 288, tp = j % 288;
        wt3[tp * 64 + co] = W3[j];
    } else if (i < 60864) {          // W4: 64 x 576
        int j = i - 24000, co = j / 576, tp = j % 576;
        wt4[tp * 64 + co] = W4[j];
    }
}

// 16-FMA inner step, order identical to round 1 (qw,qz,qy,qx; k ascending
// per accumulator).  hA = coeff base vector, hB = next vector.
#define FIR_STEP(A0, A1, A2, A3, qx, qy, qz, qw, hA, hB)  \
    A0 = fmaf(hA.x, qw, A0);                              \
    A1 = fmaf(hA.y, qw, A1);                              \
    A2 = fmaf(hA.z, qw, A2);                              \
    A3 = fmaf(hA.w, qw, A3);                              \
    A0 = fmaf(hA.y, qz, A0);                              \
    A1 = fmaf(hA.z, qz, A1);                              \
    A2 = fmaf(hA.w, qz, A2);                              \
    A3 = fmaf(hB.x, qz, A3);                              \
    A0 = fmaf(hA.z, qy, A0);                              \
    A1 = fmaf(hA.w, qy, A1);                              \
    A2 = fmaf(hB.x, qy, A2);                              \
    A3 = fmaf(hB.y, qy, A3);                              \
    A0 = fmaf(hA.w, qx, A0);                              \
    A1 = fmaf(hB.x, qx, A1);                              \
    A2 = fmaf(hB.y, qx, A2);                              \
    A3 = fmaf(hB.z, qx, A3);

// 4 sequential scan steps on a float4 (ascending t), identical math.
#define SCAN4(XV, p, rk)                                          \
    {                                                             \
        float u_, sv_;                                            \
        u_ = XV.x + p[0]; sv_ = (u_ >= THETA) ? 1.0f : 0.0f;      \
        XV.x = sv_;                                               \
        _Pragma("unroll")                                         \
        for (int i_ = 0; i_ < 14; ++i_) p[i_] = fmaf(sv_, rk[i_], p[i_ + 1]); \
        p[14] = sv_ * rk[14];                                     \
        u_ = XV.y + p[0]; sv_ = (u_ >= THETA) ? 1.0f : 0.0f;      \
        XV.y = sv_;                                               \
        _Pragma("unroll")                                         \
        for (int i_ = 0; i_ < 14; ++i_) p[i_] = fmaf(sv_, rk[i_], p[i_ + 1]); \
        p[14] = sv_ * rk[14];                                     \
        u_ = XV.z + p[0]; sv_ = (u_ >= THETA) ? 1.0f : 0.0f;      \
        XV.z = sv_;                                               \
        _Pragma("unroll")                                         \
        for (int i_ = 0; i_ < 14; ++i_) p[i_] = fmaf(sv_, rk[i_], p[i_ + 1]); \
        p[14] = sv_ * rk[14];                                     \
        u_ = XV.w + p[0]; sv_ = (u_ >= THETA) ? 1.0f : 0.0f;      \
        XV.w = sv_;                                               \
        _Pragma("unroll")                                         \
        for (int i_ = 0; i_ < 14; ++i_) p[i_] = fmaf(sv_, rk[i_], p[i_ + 1]); \
        p[14] = sv_ * rk[14];                                     \
    }

// ---------------------------------------------------------------------------
// FIR run over NSUB sub-chunks (4*NSUB outputs starting at t0).
// One b128 tile read + 16*NSUB FMAs per j.  Rolling 5-vector HQ window:
// H[m] = HQ[4j+4m]; sub-chunk d uses (H[d+4-NSUB], H[d+5-NSUB]).
// Out-of-range taps hit HQ zeros -> exact no-ops (operands >= +0).
// ---------------------------------------------------------------------------
template <int NSUB>
__device__ __forceinline__ void fir_run(const float* __restrict__ row,
                                        const float4* __restrict__ HQ4,
                                        int t0, int jend, float4 (&acc)[NSUB]) {
    float4 H[5];
    #pragma unroll
    for (int m = 0; m < 5; ++m) H[m] = HQ4[m];
    const float* bp = row + t0 + 4 * (NSUB - 1);
    for (int j = 0; j <= jend; ++j) {
        const float4 qv = *reinterpret_cast<const float4*>(bp);
        const float4 Hn = HQ4[j + 5];
        #pragma unroll
        for (int d = 0; d < NSUB; ++d) {
            const float4 hA = H[d + 4 - NSUB];
            const float4 hB = H[d + 5 - NSUB];
            FIR_STEP(acc[d].x, acc[d].y, acc[d].z, acc[d].w,
                     qv.x, qv.y, qv.z, qv.w, hA, hB)
        }
        #pragma unroll
        for (int m = 0; m < 4; ++m) H[m] = H[m + 1];
        H[4] = Hn;
        bp -= 4;
    }
}

// ---------------------------------------------------------------------------
// Fused [spike ->] psp.  Block = 64 series x 8 waves, LDS tile [64][204].
// Items: 12 superchunks (16 outputs) + 1 tail pair (8 outputs), round-robin
// over waves (item = w, w+8).
// ---------------------------------------------------------------------------
template <bool SCAN>
__global__ __launch_bounds__(512) void spikepsp_kernel(const float* __restrict__ in,
                                                       float* __restrict__ out,
                                                       const float* __restrict__ HQ,
                                                       const float* __restrict__ rkt,
                                                       int n) {
    __shared__ __align__(16) float tile[64 * RSTRIDE];
    const int l = threadIdx.x & 63;
    const int w = threadIdx.x >> 6;
    const int s0 = blockIdx.x * 64;
    for (int i = threadIdx.x; i < 3200; i += 512) {
        const int slot = i / 50, q = i - slot * 50;
        const int ser = s0 + slot;
        float4 v = make_float4(0.f, 0.f, 0.f, 0.f);
        if (ser < n) v = *reinterpret_cast<const float4*>(in + (long)ser * 200 + 4 * q);
        *reinterpret_cast<float4*>(&tile[slot * RSTRIDE + 4 * q]) = v;
    }
    __syncthreads();
    if (SCAN) {
        if (w == 0) {
            float rk[15];
            #pragma unroll
            for (int i = 0; i < 15; ++i) rk[i] = rkt[i];
            float p[15];
            #pragma unroll
            for (int i = 0; i < 15; ++i) p[i] = 0.0f;
            float* row = tile + l * RSTRIDE;
            for (int tq = 0; tq < 50; ++tq) {
                float4 xv = *reinterpret_cast<const float4*>(&row[4 * tq]);
                SCAN4(xv, p, rk)
                *reinterpret_cast<float4*>(&row[4 * tq]) = xv;
            }
        }
        __syncthreads();
    }
    const bool valid = (s0 + l) < n;
    const float* row = tile + l * RSTRIDE;
    const float4* HQ4 = reinterpret_cast<const float4*>(HQ);
    float* op = out + (long)(s0 + l) * 200;
    for (int item = w; item < 13; item += 8) {
        if (item < 12) {
            const int t0 = 16 * item;
            const int gm = (4 * item < 25) ? 4 * item : 25;
            float4 acc[4];
            #pragma unroll
            for (int d = 0; d < 4; ++d) acc[d] = make_float4(0.f, 0.f, 0.f, 0.f);
            fir_run<4>(row, HQ4, t0, gm + 3, acc);
            if (valid) {
                #pragma unroll
                for (int d = 0; d < 4; ++d)
                    *reinterpret_cast<float4*>(op + t0 + 4 * d) = acc[d];
            }
        } else {
            float4 acc[2];
            #pragma unroll
            for (int d = 0; d < 2; ++d) acc[d] = make_float4(0.f, 0.f, 0.f, 0.f);
            fir_run<2>(row, HQ4, 192, 26, acc);
            if (valid) {
                #pragma unroll
                for (int d = 0; d < 2; ++d)
                    *reinterpret_cast<float4*>(op + 192 + 4 * d) = acc[d];
            }
        }
    }
}

// ---------------------------------------------------------------------------
// Fused spike -> psp -> 2x2 sum-pool (*11).  Block = 16 outputs = 64 input
// series (slot = 4*oi + pixel), 8 waves.  Pool combine = in-order quad
// shuffle sum ((p0+p1)+p2)+p3 then *11 — bit-identical to unfused.
// ---------------------------------------------------------------------------
__global__ __launch_bounds__(512) void spikepsppool_kernel(const float* __restrict__ in,
                                                           float* __restrict__ out,
                                                           const float* __restrict__ HQ,
                                                           const float* __restrict__ rkt,
                                                           int C, int HO, int WO) {
    __shared__ __align__(16) float tile[64 * RSTRIDE];
    __shared__ int sbase[64];
    const int l = threadIdx.x & 63;
    const int w = threadIdx.x >> 6;
    const int o0 = blockIdx.x * 16;
    const int H = 2 * HO, W = 2 * WO;
    if (threadIdx.x < 64) {
        const int oi = threadIdx.x >> 2, p = threadIdx.x & 3;
        const int o = o0 + oi;
        const int wo = o % WO; int tmp = o / WO;
        const int ho = tmp % HO; tmp /= HO;
        const int c = tmp % C; const int b = tmp / C;
        sbase[threadIdx.x] = ((b * C + c) * H + 2 * ho + (p >> 1)) * W + 2 * wo + (p & 1);
    }
    __syncthreads();
    for (int i = threadIdx.x; i < 3200; i += 512) {
        const int slot = i / 50, q = i - slot * 50;
        const float4 v = *reinterpret_cast<const float4*>(in + (long)sbase[slot] * 200 + 4 * q);
        *reinterpret_cast<float4*>(&tile[slot * RSTRIDE + 4 * q]) = v;
    }
    __syncthreads();
    if (w == 0) {
        float rk[15];
        #pragma unroll
        for (int i = 0; i < 15; ++i) rk[i] = rkt[i];
        float p[15];
        #pragma unroll
        for (int i = 0; i < 15; ++i) p[i] = 0.0f;
        float* row = tile + l * RSTRIDE;
        for (int tq = 0; tq < 50; ++tq) {
            float4 xv = *reinterpret_cast<const float4*>(&row[4 * tq]);
            SCAN4(xv, p, rk)
            *reinterpret_cast<float4*>(&row[4 * tq]) = xv;
        }
    }
    __syncthreads();
    const int qb = l & ~3;
    const float* row = tile + l * RSTRIDE;
    const float4* HQ4 = reinterpret_cast<const float4*>(HQ);
    float* op = out + (long)(o0 + (l >> 2)) * 200;
    auto qsum = [&](float v) -> float {
        const float v0 = __shfl(v, qb + 0);
        const float v1 = __shfl(v, qb + 1);
        const float v2 = __shfl(v, qb + 2);
        const float v3 = __shfl(v, qb + 3);
        return (((v0 + v1) + v2) + v3) * 11.0f;
    };
    for (int item = w; item < 13; item += 8) {
        if (item < 12) {
            const int t0 = 16 * item;
            const int gm = (4 * item < 25) ? 4 * item : 25;
            float4 acc[4];
            #pragma unroll
            for (int d = 0; d < 4; ++d) acc[d] = make_float4(0.f, 0.f, 0.f, 0.f);
            fir_run<4>(row, HQ4, t0, gm + 3, acc);
            #pragma unroll
            for (int d = 0; d < 4; ++d) {
                float4 r;
                r.x = qsum(acc[d].x); r.y = qsum(acc[d].y);
                r.z = qsum(acc[d].z); r.w = qsum(acc[d].w);
                if ((l & 3) == 0)
                    *reinterpret_cast<float4*>(op + t0 + 4 * d) = r;
            }
        } else {
            float4 acc[2];
            #pragma unroll
            for (int d = 0; d < 2; ++d) acc[d] = make_float4(0.f, 0.f, 0.f, 0.f);
            fir_run<2>(row, HQ4, 192, 26, acc);
            #pragma unroll
            for (int d = 0; d < 2; ++d) {
                float4 r;
                r.x = qsum(acc[d].x); r.y = qsum(acc[d].y);
                r.z = qsum(acc[d].z); r.w = qsum(acc[d].w);
                if ((l & 3) == 0)
                    *reinterpret_cast<float4*>(op + 192 + 4 * d) = r;
            }
        }
    }
}

// ---------------------------------------------------------------------------
// conv1 (K=5): float4-of-t, transposed weights, 16 co accumulators.
// ---------------------------------------------------------------------------
template <int K, int PAD, int CI, int COG>
__global__ __launch_bounds__(256) void conv_kernel(const float* __restrict__ x,
                                                   const float* __restrict__ wt,
                                                   float* __restrict__ out,
                                                   int Co, int H, int W,
                                                   int HO, int WO) {
    const int l = threadIdx.x & 63;
    const int wv = threadIdx.x >> 6;
    if (l >= 50) return;
    const int p = blockIdx.x * 4 + wv;
    const int wo = p % WO, ho = p / WO;
    const int co0 = blockIdx.y * COG;
    const int b = blockIdx.z;
    const int t0 = l * 4;
    float4 acc[COG];
    #pragma unroll
    for (int c = 0; c < COG; ++c) acc[c] = make_float4(0.f, 0.f, 0.f, 0.f);
    const float* xb = x + ((long)b * CI * H * W) * 200 + t0;
    for (int ci = 0; ci < CI; ++ci) {
        #pragma unroll
        for (int kh = 0; kh < K; ++kh) {
            const int hi = ho + kh - PAD;
            if (hi < 0 || hi >= H) continue;
            #pragma unroll
            for (int kw = 0; kw < K; ++kw) {
                const int wi = wo + kw - PAD;
                if (wi < 0 || wi >= W) continue;
                const float4 v = *reinterpret_cast<const float4*>(
                    xb + ((long)(ci * H + hi) * W + wi) * 200);
                const float* wp = wt + ((ci * K + kh) * K + kw) * Co + co0;
                #pragma unroll
                for (int c = 0; c < COG; ++c) {
                    const float wv_ = wp[c];
                    acc[c].x = fmaf(wv_, v.x, acc[c].x);
                    acc[c].y = fmaf(wv_, v.y, acc[c].y);
                    acc[c].z = fmaf(wv_, v.z, acc[c].z);
                    acc[c].w = fmaf(wv_, v.w, acc[c].w);
                }
            }
        }
    }
    const long hwN = (long)HO * WO;
    const long ob = ((long)(b * Co + co0) * HO + ho) * WO + wo;
    #pragma unroll
    for (int c = 0; c < COG; ++c)
        *reinterpret_cast<float4*>(out + (ob + c * hwN) * 200 + t0) = acc[c];
}

// ---------------------------------------------------------------------------
// K=3 convs: ci-software-pipelined, zero-filled OOB taps (bit-exact).
// ---------------------------------------------------------------------------
template <int CI, int COG>
__global__ __launch_bounds__(256) void conv3_kernel(const float* __restrict__ x,
                                                    const float* __restrict__ wt,
                                                    float* __restrict__ out,
                                                    int Co, int H, int W) {
    const int l = threadIdx.x & 63;
    const int wv = threadIdx.x >> 6;
    if (l >= 50) return;
    const int p = blockIdx.x * 4 + wv;
    const int wo = p % W, ho = p / W;
    const int co0 = blockIdx.y * COG;
    const int b = blockIdx.z;
    const int t0 = l * 4;
    float4 acc[COG];
    #pragma unroll
    for (int c = 0; c < COG; ++c) acc[c] = make_float4(0.f, 0.f, 0.f, 0.f);

    bool vm[9];
    #pragma unroll
    for (int i = 0; i < 9; ++i) {
        const int hi = ho + i / 3 - 1, wi = wo + i % 3 - 1;
        vm[i] = (hi >= 0) && (hi < H) && (wi >= 0) && (wi < W);
    }
    const long cis = (long)H * W * 200;
    const float* pb = x + (long)b * CI * cis + ((long)(ho - 1) * W + (wo - 1)) * 200 + t0;

    float4 bufA[9], bufB[9];
    auto ld = [&](int ci, float4 (&B)[9]) {
        const float* pc = pb + ci * cis;
        #pragma unroll
        for (int i = 0; i < 9; ++i) {
            B[i] = vm[i] ? *reinterpret_cast<const float4*>(pc + ((i / 3) * W + (i % 3)) * 200)
                         : make_float4(0.f, 0.f, 0.f, 0.f);
        }
    };
    auto fm = [&](const float4 (&B)[9], int ci) {
        #pragma unroll
        for (int i = 0; i < 9; ++i) {
            const float* wp = wt + (ci * 9 + i) * Co + co0;
            #pragma unroll
            for (int c = 0; c < COG; ++c) {
                const float wv_ = wp[c];
                acc[c].x = fmaf(wv_, B[i].x, acc[c].x);
                acc[c].y = fmaf(wv_, B[i].y, acc[c].y);
                acc[c].z = fmaf(wv_, B[i].z, acc[c].z);
                acc[c].w = fmaf(wv_, B[i].w, acc[c].w);
            }
        }
    };

    ld(0, bufA);
    #pragma unroll 1
    for (int ci = 0; ci < CI; ci += 2) {
        ld(ci + 1, bufB);
        fm(bufA, ci);
        if (ci + 2 < CI) ld(ci + 2, bufA);
        fm(bufB, ci + 1);
    }

    const long hwN = (long)H * W;
    const long ob = ((long)(b * Co + co0) * H + ho) * W + wo;
    #pragma unroll
    for (int c = 0; c < COG; ++c)
        *reinterpret_cast<float4*>(out + (ob + c * hwN) * 200 + t0) = acc[c];
}

// ---------------------------------------------------------------------------
// Standalone spike scan (only the tiny final fc->spike uses this now).
// ---------------------------------------------------------------------------
__global__ __launch_bounds__(256) void spike_kernel(const float* __restrict__ v,
                                                    float* __restrict__ s,
                                                    const float* __restrict__ rkt,
                                                    int n) {
    const int nid = blockIdx.x * 256 + threadIdx.x;
    if (nid >= n) return;
    float rk[15];
    #pragma unroll
    for (int i = 0; i < 15; ++i) rk[i] = rkt[i];
    float p[15];
    #pragma unroll
    for (int i = 0; i < 15; ++i) p[i] = 0.0f;
    const float* vp = v + (long)nid * 200;
    float* sp = s + (long)nid * 200;
    for (int t = 0; t < 200; ++t) {
        const float u = vp[t] + p[0];
        const float sv = (u >= THETA) ? 1.0f : 0.0f;
        sp[t] = sv;
        #pragma unroll
        for (int i = 0; i < 14; ++i) p[i] = fmaf(sv, rk[i], p[i + 1]);
        p[14] = sv * rk[14];
    }
}

// ---------------------------------------------------------------------------
// FC: out[b,k,t] = sum_{c,h,w} x[b,c,h,w,t] * Wfc[k,c,h,w]; grid.z = t-half.
// ---------------------------------------------------------------------------
__global__ __launch_bounds__(64) void fc_kernel(const float* __restrict__ x,
                                                const float* __restrict__ wf,
                                                float* __restrict__ out) {
    const int k = blockIdx.x, b = blockIdx.y, l = threadIdx.x;
    if (l >= 25) return;
    const int t0 = blockIdx.z * 100 + l * 4;
    float4 acc = make_float4(0.f, 0.f, 0.f, 0.f);
    for (int c = 0; c < 64; ++c)
        #pragma unroll
        for (int h = 0; h < 6; ++h)
            #pragma unroll
            for (int w = 0; w < 6; ++w) {
                const float4 v = *reinterpret_cast<const float4*>(
                    x + (((long)(b * 64 + c) * 6 + h) * 6 + w) * 200 + t0);
                const float wv_ = wf[((k * 64 + c) * 6 + h) * 6 + w];
                acc.x = fmaf(wv_, v.x, acc.x);
                acc.y = fmaf(wv_, v.y, acc.y);
                acc.z = fmaf(wv_, v.z, acc.z);
                acc.w = fmaf(wv_, v.w, acc.w);
            }
    *reinterpret_cast<float4*>(out + ((long)b * 10 + k) * 200 + t0) = acc;
}

extern "C" void kernel_launch(void* const* d_in, const int* in_sizes, int n_in,
                              void* d_out, int out_size, void* d_ws, size_t ws_size,
                              hipStream_t stream) {
    const float* x_in = (const float*)d_in[0];  // (4,2,50,50,200)
    const float* W1 = (const float*)d_in[1];    // (16,2,5,5)
    const float* W2 = (const float*)d_in[2];    // (32,16,3,3)
    const float* W3 = (const float*)d_in[3];    // (64,32,3,3)
    const float* W4 = (const float*)d_in[4];    // (64,64,3,3)
    const float* Wfc = (const float*)d_in[5];   // (10,64,6,6)
    float* outp = (float*)d_out;                // (4,10,200)

    float* ws = (float*)d_ws;
    float* HQ  = ws;                  // 144 (16B aligned)
    float* rk  = ws + 144;            // 15 (+1 pad)
    float* wt1 = ws + 160;            // 800
    float* wt2 = wt1 + 800;           // 4608
    float* wt3 = wt2 + 4608;          // 18432
    float* wt4 = wt3 + 18432;         // 36864
    float* A   = wt4 + 36864;         // 7,372,800
    float* B   = A + 7372800;         // 29,491,200
    float* C   = B + 29491200;        // 14,745,600

    hipLaunchKernelGGL(prep_kernel, dim3(238), dim3(256), 0, stream,
                       W1, W2, W3, W4, HQ, rk, wt1, wt2, wt3, wt4);

    // p0 = psp(input): 20000 series (no scan)
    hipLaunchKernelGGL((spikepsp_kernel<false>), dim3(313), dim3(512), 0, stream,
                       x_in, A, HQ, rk, 20000);
    // c1 = conv1(p0): (4,16,48,48,200)
    hipLaunchKernelGGL((conv_kernel<5, 1, 2, 16>), dim3(2304 / 4, 1, 4), dim3(256), 0, stream,
                       A, wt1, B, 16, 50, 50, 48, 48);
    // o1 = pool(psp(spike(c1))): 36864 outputs
    hipLaunchKernelGGL(spikepsppool_kernel, dim3(36864 / 16), dim3(512), 0, stream,
                       B, A, HQ, rk, 16, 24, 24);
    // p2 = psp(spike(o1)): 36864 series
    hipLaunchKernelGGL((spikepsp_kernel<true>), dim3(36864 / 64), dim3(512), 0, stream,
                       A, B, HQ, rk, 36864);
    // c2 = conv2(p2): (4,32,24,24,200)
    hipLaunchKernelGGL((conv3_kernel<16, 8>), dim3(576 / 4, 4, 4), dim3(256), 0, stream,
                       B, wt2, C, 32, 24, 24);
    // o2 = pool(psp(spike(c2))): 18432 outputs
    hipLaunchKernelGGL(spikepsppool_kernel, dim3(18432 / 16), dim3(512), 0, stream,
                       C, A, HQ, rk, 32, 12, 12);
    // p4 = psp(spike(o2)): 18432 series
    hipLaunchKernelGGL((spikepsp_kernel<true>), dim3(18432 / 64), dim3(512), 0, stream,
                       A, B, HQ, rk, 18432);
    // c3 = conv3(p4): (4,64,12,12,200)
    hipLaunchKernelGGL((conv3_kernel<32, 8>), dim3(144 / 4, 8, 4), dim3(256), 0, stream,
                       B, wt3, C, 64, 12, 12);
    // o3 = pool(psp(spike(c3))): 9216 outputs
    hipLaunchKernelGGL(spikepsppool_kernel, dim3(9216 / 16), dim3(512), 0, stream,
                       C, A, HQ, rk, 64, 6, 6);
    // p6 = psp(spike(o3)): 9216 series
    hipLaunchKernelGGL((spikepsp_kernel<true>), dim3(9216 / 64), dim3(512), 0, stream,
                       A, B, HQ, rk, 9216);
    // c4 = conv4(p6): (4,64,6,6,200)
    hipLaunchKernelGGL((conv3_kernel<64, 4>), dim3(36 / 4, 16, 4), dim3(256), 0, stream,
                       B, wt4, C, 64, 6, 6);
    // p7 = psp(spike(c4)): 9216 series
    hipLaunchKernelGGL((spikepsp_kernel<true>), dim3(9216 / 64), dim3(512), 0, stream,
                       C, B, HQ, rk, 9216);
    // fc: (4,10,200)
    hipLaunchKernelGGL(fc_kernel, dim3(10, 4, 2), dim3(64), 0, stream, B, Wfc, A);
    // final spike -> d_out: 40 series
    hipLaunchKernelGGL(spike_kernel, dim3(1), dim3(256), 0, stream, A, outp, rk, 40);
    (void)in_sizes; (void)n_in; (void)out_size; (void)ws_size;
}

// Round 9
// 705.574 us; speedup vs baseline: 4.3451x; 1.0360x over previous
//
#include <hip/hip_runtime.h>
#include <math.h>

// ---------------------------------------------------------------------------
// SNN forward: psp (K=100 alpha FIR) -> conv/pool/fc -> spike (refractory scan)
// All arithmetic mirrors the JAX reference's f32 association order.
// Round 9: fc rewritten — block per (b, 8-t chunk) stages x into LDS once
// (72 KB, coalesced), 20 lanes run the 10 k-chains x 2 t-quads from LDS
// broadcast reads.  x read from HBM exactly once (was 4x scattered re-read,
// 93.6 us at 0.7% VALU).  Reduction order (c,h,w ascending fmaf) unchanged
// -> bit-exact.  All other kernels unchanged from round 8.
// ---------------------------------------------------------------------------

#define THETA 10.0f
#define RSTRIDE 204   // words per series row: 200 + pad4; 16B aligned

// HQ[i] = h[i-15] for 15<=i<=114 (h[k] = (k/10)*exp(1-k/10)), else 0. 144 entries.
// rk[i] = REF_KERNEL[i+1] = (-40*(i+1))*exp(1-(i+1)),  i=0..14
// wtN = transposed weights: wt[(ci*K*K + tap)*Co + co] = W[co][ci][tap]
__global__ void prep_kernel(const float* __restrict__ W1, const float* __restrict__ W2,
                            const float* __restrict__ W3, const float* __restrict__ W4,
                            float* HQ, float* rk,
                            float* wt1, float* wt2, float* wt3, float* wt4) {
    int i = blockIdx.x * 256 + threadIdx.x;
    if (i < 144) {
        int k = i - 15;
        float val = 0.0f;
        if (k >= 0 && k <= 99) {
            float tf = (float)k;
            float x = tf / 10.0f;
            val = x * (float)exp((double)(1.0f - x));   // same expr as prior rounds
        }
        HQ[i] = val;
    } else if (i < 160) {
        int j = i - 144;
        if (j < 15) {
            float t = (float)(j + 1);
            rk[j] = (-40.0f * t) * (float)exp((double)(1.0f - t));
        }
    } else if (i < 960) {            // W1: 16 x 50
        int j = i - 160, co = j / 50, tp = j % 50;
        wt1[tp * 16 + co] = W1[j];
    } else if (i < 5568) {           // W2: 32 x 144
        int j = i - 960, co = j / 144, tp = j % 144;
        wt2[tp * 32 + co] = W2[j];
    } else if (i < 24000) {          // W3: 64 x 288
        int j = i - 5568, co = j / 288, tp = j % 288;
        wt3[tp * 64 + co] = W3[j];
    } else if (i < 60864) {          // W4: 64 x 576
        int j = i - 24000, co = j / 576, tp = j % 576;
        wt4[tp * 64 + co] = W4[j];
    }
}

// 16-FMA inner step, order identical to round 1 (qw,qz,qy,qx; k ascending
// per accumulator).  hA = coeff base vector, hB = next vector.
#define FIR_STEP(A0, A1, A2, A3, qx, qy, qz, qw, hA, hB)  \
    A0 = fmaf(hA.x, qw, A0);                              \
    A1 = fmaf(hA.y, qw, A1);                              \
    A2 = fmaf(hA.z, qw, A2);                              \
    A3 = fmaf(hA.w, qw, A3);                              \
    A0 = fmaf(hA.y, qz, A0);                              \
    A1 = fmaf(hA.z, qz, A1);                              \
    A2 = fmaf(hA.w, qz, A2);                              \
    A3 = fmaf(hB.x, qz, A3);                              \
    A0 = fmaf(hA.z, qy, A0);                              \
    A1 = fmaf(hA.w, qy, A1);                              \
    A2 = fmaf(hB.x, qy, A2);                              \
    A3 = fmaf(hB.y, qy, A3);                              \
    A0 = fmaf(hA.w, qx, A0);                              \
    A1 = fmaf(hB.x, qx, A1);                              \
    A2 = fmaf(hB.y, qx, A2);                              \
    A3 = fmaf(hB.z, qx, A3);

// 4 sequential scan steps on a float4 (ascending t), identical math.
#define SCAN4(XV, p, rk)                                          \
    {                                                             \
        float u_, sv_;                                            \
        u_ = XV.x + p[0]; sv_ = (u_ >= THETA) ? 1.0f : 0.0f;      \
        XV.x = sv_;                                               \
        _Pragma("unroll")                                         \
        for (int i_ = 0; i_ < 14; ++i_) p[i_] = fmaf(sv_, rk[i_], p[i_ + 1]); \
        p[14] = sv_ * rk[14];                                     \
        u_ = XV.y + p[0]; sv_ = (u_ >= THETA) ? 1.0f : 0.0f;      \
        XV.y = sv_;                                               \
        _Pragma("unroll")                                         \
        for (int i_ = 0; i_ < 14; ++i_) p[i_] = fmaf(sv_, rk[i_], p[i_ + 1]); \
        p[14] = sv_ * rk[14];                                     \
        u_ = XV.z + p[0]; sv_ = (u_ >= THETA) ? 1.0f : 0.0f;      \
        XV.z = sv_;                                               \
        _Pragma("unroll")                                         \
        for (int i_ = 0; i_ < 14; ++i_) p[i_] = fmaf(sv_, rk[i_], p[i_ + 1]); \
        p[14] = sv_ * rk[14];                                     \
        u_ = XV.w + p[0]; sv_ = (u_ >= THETA) ? 1.0f : 0.0f;      \
        XV.w = sv_;                                               \
        _Pragma("unroll")                                         \
        for (int i_ = 0; i_ < 14; ++i_) p[i_] = fmaf(sv_, rk[i_], p[i_ + 1]); \
        p[14] = sv_ * rk[14];                                     \
    }

// ---------------------------------------------------------------------------
// FIR run over NSUB sub-chunks (4*NSUB outputs starting at t0).
// One b128 tile read + 16*NSUB FMAs per j.  Rolling 5-vector HQ window:
// H[m] = HQ[4j+4m]; sub-chunk d uses (H[d+4-NSUB], H[d+5-NSUB]).
// Out-of-range taps hit HQ zeros -> exact no-ops (operands >= +0).
// ---------------------------------------------------------------------------
template <int NSUB>
__device__ __forceinline__ void fir_run(const float* __restrict__ row,
                                        const float4* __restrict__ HQ4,
                                        int t0, int jend, float4 (&acc)[NSUB]) {
    float4 H[5];
    #pragma unroll
    for (int m = 0; m < 5; ++m) H[m] = HQ4[m];
    const float* bp = row + t0 + 4 * (NSUB - 1);
    for (int j = 0; j <= jend; ++j) {
        const float4 qv = *reinterpret_cast<const float4*>(bp);
        const float4 Hn = HQ4[j + 5];
        #pragma unroll
        for (int d = 0; d < NSUB; ++d) {
            const float4 hA = H[d + 4 - NSUB];
            const float4 hB = H[d + 5 - NSUB];
            FIR_STEP(acc[d].x, acc[d].y, acc[d].z, acc[d].w,
                     qv.x, qv.y, qv.z, qv.w, hA, hB)
        }
        #pragma unroll
        for (int m = 0; m < 4; ++m) H[m] = H[m + 1];
        H[4] = Hn;
        bp -= 4;
    }
}

// ---------------------------------------------------------------------------
// Fused [spike ->] psp.  Block = 64 series x 8 waves, LDS tile [64][204].
// Items: 12 superchunks (16 outputs) + 1 tail pair (8 outputs), round-robin
// over waves (item = w, w+8).
// ---------------------------------------------------------------------------
template <bool SCAN>
__global__ __launch_bounds__(512) void spikepsp_kernel(const float* __restrict__ in,
                                                       float* __restrict__ out,
                                                       const float* __restrict__ HQ,
                                                       const float* __restrict__ rkt,
                                                       int n) {
    __shared__ __align__(16) float tile[64 * RSTRIDE];
    const int l = threadIdx.x & 63;
    const int w = threadIdx.x >> 6;
    const int s0 = blockIdx.x * 64;
    for (int i = threadIdx.x; i < 3200; i += 512) {
        const int slot = i / 50, q = i - slot * 50;
        const int ser = s0 + slot;
        float4 v = make_float4(0.f, 0.f, 0.f, 0.f);
        if (ser < n) v = *reinterpret_cast<const float4*>(in + (long)ser * 200 + 4 * q);
        *reinterpret_cast<float4*>(&tile[slot * RSTRIDE + 4 * q]) = v;
    }
    __syncthreads();
    if (SCAN) {
        if (w == 0) {
            float rk[15];
            #pragma unroll
            for (int i = 0; i < 15; ++i) rk[i] = rkt[i];
            float p[15];
            #pragma unroll
            for (int i = 0; i < 15; ++i) p[i] = 0.0f;
            float* row = tile + l * RSTRIDE;
            for (int tq = 0; tq < 50; ++tq) {
                float4 xv = *reinterpret_cast<const float4*>(&row[4 * tq]);
                SCAN4(xv, p, rk)
                *reinterpret_cast<float4*>(&row[4 * tq]) = xv;
            }
        }
        __syncthreads();
    }
    const bool valid = (s0 + l) < n;
    const float* row = tile + l * RSTRIDE;
    const float4* HQ4 = reinterpret_cast<const float4*>(HQ);
    float* op = out + (long)(s0 + l) * 200;
    for (int item = w; item < 13; item += 8) {
        if (item < 12) {
            const int t0 = 16 * item;
            const int gm = (4 * item < 25) ? 4 * item : 25;
            float4 acc[4];
            #pragma unroll
            for (int d = 0; d < 4; ++d) acc[d] = make_float4(0.f, 0.f, 0.f, 0.f);
            fir_run<4>(row, HQ4, t0, gm + 3, acc);
            if (valid) {
                #pragma unroll
                for (int d = 0; d < 4; ++d)
                    *reinterpret_cast<float4*>(op + t0 + 4 * d) = acc[d];
            }
        } else {
            float4 acc[2];
            #pragma unroll
            for (int d = 0; d < 2; ++d) acc[d] = make_float4(0.f, 0.f, 0.f, 0.f);
            fir_run<2>(row, HQ4, 192, 26, acc);
            if (valid) {
                #pragma unroll
                for (int d = 0; d < 2; ++d)
                    *reinterpret_cast<float4*>(op + 192 + 4 * d) = acc[d];
            }
        }
    }
}

// ---------------------------------------------------------------------------
// Fused spike -> psp -> 2x2 sum-pool (*11).  Block = 16 outputs = 64 input
// series (slot = 4*oi + pixel), 8 waves.  Pool combine = in-order quad
// shuffle sum ((p0+p1)+p2)+p3 then *11 — bit-identical to unfused.
// ---------------------------------------------------------------------------
__global__ __launch_bounds__(512) void spikepsppool_kernel(const float* __restrict__ in,
                                                           float* __restrict__ out,
                                                           const float* __restrict__ HQ,
                                                           const float* __restrict__ rkt,
                                                           int C, int HO, int WO) {
    __shared__ __align__(16) float tile[64 * RSTRIDE];
    __shared__ int sbase[64];
    const int l = threadIdx.x & 63;
    const int w = threadIdx.x >> 6;
    const int o0 = blockIdx.x * 16;
    const int H = 2 * HO, W = 2 * WO;
    if (threadIdx.x < 64) {
        const int oi = threadIdx.x >> 2, p = threadIdx.x & 3;
        const int o = o0 + oi;
        const int wo = o % WO; int tmp = o / WO;
        const int ho = tmp % HO; tmp /= HO;
        const int c = tmp % C; const int b = tmp / C;
        sbase[threadIdx.x] = ((b * C + c) * H + 2 * ho + (p >> 1)) * W + 2 * wo + (p & 1);
    }
    __syncthreads();
    for (int i = threadIdx.x; i < 3200; i += 512) {
        const int slot = i / 50, q = i - slot * 50;
        const float4 v = *reinterpret_cast<const float4*>(in + (long)sbase[slot] * 200 + 4 * q);
        *reinterpret_cast<float4*>(&tile[slot * RSTRIDE + 4 * q]) = v;
    }
    __syncthreads();
    if (w == 0) {
        float rk[15];
        #pragma unroll
        for (int i = 0; i < 15; ++i) rk[i] = rkt[i];
        float p[15];
        #pragma unroll
        for (int i = 0; i < 15; ++i) p[i] = 0.0f;
        float* row = tile + l * RSTRIDE;
        for (int tq = 0; tq < 50; ++tq) {
            float4 xv = *reinterpret_cast<const float4*>(&row[4 * tq]);
            SCAN4(xv, p, rk)
            *reinterpret_cast<float4*>(&row[4 * tq]) = xv;
        }
    }
    __syncthreads();
    const int qb = l & ~3;
    const float* row = tile + l * RSTRIDE;
    const float4* HQ4 = reinterpret_cast<const float4*>(HQ);
    float* op = out + (long)(o0 + (l >> 2)) * 200;
    auto qsum = [&](float v) -> float {
        const float v0 = __shfl(v, qb + 0);
        const float v1 = __shfl(v, qb + 1);
        const float v2 = __shfl(v, qb + 2);
        const float v3 = __shfl(v, qb + 3);
        return (((v0 + v1) + v2) + v3) * 11.0f;
    };
    for (int item = w; item < 13; item += 8) {
        if (item < 12) {
            const int t0 = 16 * item;
            const int gm = (4 * item < 25) ? 4 * item : 25;
            float4 acc[4];
            #pragma unroll
            for (int d = 0; d < 4; ++d) acc[d] = make_float4(0.f, 0.f, 0.f, 0.f);
            fir_run<4>(row, HQ4, t0, gm + 3, acc);
            #pragma unroll
            for (int d = 0; d < 4; ++d) {
                float4 r;
                r.x = qsum(acc[d].x); r.y = qsum(acc[d].y);
                r.z = qsum(acc[d].z); r.w = qsum(acc[d].w);
                if ((l & 3) == 0)
                    *reinterpret_cast<float4*>(op + t0 + 4 * d) = r;
            }
        } else {
            float4 acc[2];
            #pragma unroll
            for (int d = 0; d < 2; ++d) acc[d] = make_float4(0.f, 0.f, 0.f, 0.f);
            fir_run<2>(row, HQ4, 192, 26, acc);
            #pragma unroll
            for (int d = 0; d < 2; ++d) {
                float4 r;
                r.x = qsum(acc[d].x); r.y = qsum(acc[d].y);
                r.z = qsum(acc[d].z); r.w = qsum(acc[d].w);
                if ((l & 3) == 0)
                    *reinterpret_cast<float4*>(op + 192 + 4 * d) = r;
            }
        }
    }
}

// ---------------------------------------------------------------------------
// conv1 (K=5): float4-of-t, transposed weights, 16 co accumulators.
// ---------------------------------------------------------------------------
template <int K, int PAD, int CI, int COG>
__global__ __launch_bounds__(256) void conv_kernel(const float* __restrict__ x,
                                                   const float* __restrict__ wt,
                                                   float* __restrict__ out,
                                                   int Co, int H, int W,
                                                   int HO, int WO) {
    const int l = threadIdx.x & 63;
    const int wv = threadIdx.x >> 6;
    if (l >= 50) return;
    const int p = blockIdx.x * 4 + wv;
    const int wo = p % WO, ho = p / WO;
    const int co0 = blockIdx.y * COG;
    const int b = blockIdx.z;
    const int t0 = l * 4;
    float4 acc[COG];
    #pragma unroll
    for (int c = 0; c < COG; ++c) acc[c] = make_float4(0.f, 0.f, 0.f, 0.f);
    const float* xb = x + ((long)b * CI * H * W) * 200 + t0;
    for (int ci = 0; ci < CI; ++ci) {
        #pragma unroll
        for (int kh = 0; kh < K; ++kh) {
            const int hi = ho + kh - PAD;
            if (hi < 0 || hi >= H) continue;
            #pragma unroll
            for (int kw = 0; kw < K; ++kw) {
                const int wi = wo + kw - PAD;
                if (wi < 0 || wi >= W) continue;
                const float4 v = *reinterpret_cast<const float4*>(
                    xb + ((long)(ci * H + hi) * W + wi) * 200);
                const float* wp = wt + ((ci * K + kh) * K + kw) * Co + co0;
                #pragma unroll
                for (int c = 0; c < COG; ++c) {
                    const float wv_ = wp[c];
                    acc[c].x = fmaf(wv_, v.x, acc[c].x);
                    acc[c].y = fmaf(wv_, v.y, acc[c].y);
                    acc[c].z = fmaf(wv_, v.z, acc[c].z);
                    acc[c].w = fmaf(wv_, v.w, acc[c].w);
                }
            }
        }
    }
    const long hwN = (long)HO * WO;
    const long ob = ((long)(b * Co + co0) * HO + ho) * WO + wo;
    #pragma unroll
    for (int c = 0; c < COG; ++c)
        *reinterpret_cast<float4*>(out + (ob + c * hwN) * 200 + t0) = acc[c];
}

// ---------------------------------------------------------------------------
// K=3 convs: ci-software-pipelined, zero-filled OOB taps (bit-exact).
// ---------------------------------------------------------------------------
template <int CI, int COG>
__global__ __launch_bounds__(256) void conv3_kernel(const float* __restrict__ x,
                                                    const float* __restrict__ wt,
                                                    float* __restrict__ out,
                                                    int Co, int H, int W) {
    const int l = threadIdx.x & 63;
    const int wv = threadIdx.x >> 6;
    if (l >= 50) return;
    const int p = blockIdx.x * 4 + wv;
    const int wo = p % W, ho = p / W;
    const int co0 = blockIdx.y * COG;
    const int b = blockIdx.z;
    const int t0 = l * 4;
    float4 acc[COG];
    #pragma unroll
    for (int c = 0; c < COG; ++c) acc[c] = make_float4(0.f, 0.f, 0.f, 0.f);

    bool vm[9];
    #pragma unroll
    for (int i = 0; i < 9; ++i) {
        const int hi = ho + i / 3 - 1, wi = wo + i % 3 - 1;
        vm[i] = (hi >= 0) && (hi < H) && (wi >= 0) && (wi < W);
    }
    const long cis = (long)H * W * 200;
    const float* pb = x + (long)b * CI * cis + ((long)(ho - 1) * W + (wo - 1)) * 200 + t0;

    float4 bufA[9], bufB[9];
    auto ld = [&](int ci, float4 (&B)[9]) {
        const float* pc = pb + ci * cis;
        #pragma unroll
        for (int i = 0; i < 9; ++i) {
            B[i] = vm[i] ? *reinterpret_cast<const float4*>(pc + ((i / 3) * W + (i % 3)) * 200)
                         : make_float4(0.f, 0.f, 0.f, 0.f);
        }
    };
    auto fm = [&](const float4 (&B)[9], int ci) {
        #pragma unroll
        for (int i = 0; i < 9; ++i) {
            const float* wp = wt + (ci * 9 + i) * Co + co0;
            #pragma unroll
            for (int c = 0; c < COG; ++c) {
                const float wv_ = wp[c];
                acc[c].x = fmaf(wv_, B[i].x, acc[c].x);
                acc[c].y = fmaf(wv_, B[i].y, acc[c].y);
                acc[c].z = fmaf(wv_, B[i].z, acc[c].z);
                acc[c].w = fmaf(wv_, B[i].w, acc[c].w);
            }
        }
    };

    ld(0, bufA);
    #pragma unroll 1
    for (int ci = 0; ci < CI; ci += 2) {
        ld(ci + 1, bufB);
        fm(bufA, ci);
        if (ci + 2 < CI) ld(ci + 2, bufA);
        fm(bufB, ci + 1);
    }

    const long hwN = (long)H * W;
    const long ob = ((long)(b * Co + co0) * H + ho) * W + wo;
    #pragma unroll
    for (int c = 0; c < COG; ++c)
        *reinterpret_cast<float4*>(out + (ob + c * hwN) * 200 + t0) = acc[c];
}

// ---------------------------------------------------------------------------
// Standalone spike scan (only the tiny final fc->spike uses this now).
// ---------------------------------------------------------------------------
__global__ __launch_bounds__(256) void spike_kernel(const float* __restrict__ v,
                                                    float* __restrict__ s,
                                                    const float* __restrict__ rkt,
                                                    int n) {
    const int nid = blockIdx.x * 256 + threadIdx.x;
    if (nid >= n) return;
    float rk[15];
    #pragma unroll
    for (int i = 0; i < 15; ++i) rk[i] = rkt[i];
    float p[15];
    #pragma unroll
    for (int i = 0; i < 15; ++i) p[i] = 0.0f;
    const float* vp = v + (long)nid * 200;
    float* sp = s + (long)nid * 200;
    for (int t = 0; t < 200; ++t) {
        const float u = vp[t] + p[0];
        const float sv = (u >= THETA) ? 1.0f : 0.0f;
        sp[t] = sv;
        #pragma unroll
        for (int i = 0; i < 14; ++i) p[i] = fmaf(sv, rk[i], p[i + 1]);
        p[14] = sv * rk[14];
    }
}

// ---------------------------------------------------------------------------
// FC: out[b,k,t] = sum_m x[b,m,t] * Wfc[k,m], m = (c,h,w) ascending (2304).
// Block = (b, 8-t chunk).  Stage x[b,:,t0..t0+8) into LDS (72 KB) with
// coalesced float4 loads; lanes (k,q) in 10x2 run the m-ascending fmaf
// chain from LDS broadcast reads.  Order identical to prior fc -> bit-exact.
// x is read from HBM exactly once across the whole fc.
// ---------------------------------------------------------------------------
__global__ __launch_bounds__(64) void fc_kernel(const float* __restrict__ x,
                                                const float* __restrict__ wf,
                                                float* __restrict__ out) {
    __shared__ __align__(16) float xs[2304 * 8];
    const int b = blockIdx.x;          // 4
    const int t0 = blockIdx.y * 8;     // 25 chunks
    const int l = threadIdx.x;
    const float* xb = x + (long)b * 2304 * 200 + t0;
    for (int i = l; i < 4608; i += 64) {
        const int m = i >> 1, q = i & 1;
        const float4 v = *reinterpret_cast<const float4*>(xb + (long)m * 200 + 4 * q);
        *reinterpret_cast<float4*>(&xs[m * 8 + 4 * q]) = v;
    }
    __syncthreads();
    if (l < 20) {
        const int k = l >> 1, q = l & 1;
        float4 acc = make_float4(0.f, 0.f, 0.f, 0.f);
        const float* wp = wf + k * 2304;
        const float* xp = xs + 4 * q;
        for (int m = 0; m < 2304; ++m) {
            const float4 v = *reinterpret_cast<const float4*>(xp + m * 8);
            const float wv_ = wp[m];
            acc.x = fmaf(wv_, v.x, acc.x);
            acc.y = fmaf(wv_, v.y, acc.y);
            acc.z = fmaf(wv_, v.z, acc.z);
            acc.w = fmaf(wv_, v.w, acc.w);
        }
        *reinterpret_cast<float4*>(out + ((long)b * 10 + k) * 200 + t0 + 4 * q) = acc;
    }
}

extern "C" void kernel_launch(void* const* d_in, const int* in_sizes, int n_in,
                              void* d_out, int out_size, void* d_ws, size_t ws_size,
                              hipStream_t stream) {
    const float* x_in = (const float*)d_in[0];  // (4,2,50,50,200)
    const float* W1 = (const float*)d_in[1];    // (16,2,5,5)
    const float* W2 = (const float*)d_in[2];    // (32,16,3,3)
    const float* W3 = (const float*)d_in[3];    // (64,32,3,3)
    const float* W4 = (const float*)d_in[4];    // (64,64,3,3)
    const float* Wfc = (const float*)d_in[5];   // (10,64,6,6)
    float* outp = (float*)d_out;                // (4,10,200)

    float* ws = (float*)d_ws;
    float* HQ  = ws;                  // 144 (16B aligned)
    float* rk  = ws + 144;            // 15 (+1 pad)
    float* wt1 = ws + 160;            // 800
    float* wt2 = wt1 + 800;           // 4608
    float* wt3 = wt2 + 4608;          // 18432
    float* wt4 = wt3 + 18432;         // 36864
    float* A   = wt4 + 36864;         // 7,372,800
    float* B   = A + 7372800;         // 29,491,200
    float* C   = B + 29491200;        // 14,745,600

    hipLaunchKernelGGL(prep_kernel, dim3(238), dim3(256), 0, stream,
                       W1, W2, W3, W4, HQ, rk, wt1, wt2, wt3, wt4);

    // p0 = psp(input): 20000 series (no scan)
    hipLaunchKernelGGL((spikepsp_kernel<false>), dim3(313), dim3(512), 0, stream,
                       x_in, A, HQ, rk, 20000);
    // c1 = conv1(p0): (4,16,48,48,200)
    hipLaunchKernelGGL((conv_kernel<5, 1, 2, 16>), dim3(2304 / 4, 1, 4), dim3(256), 0, stream,
                       A, wt1, B, 16, 50, 50, 48, 48);
    // o1 = pool(psp(spike(c1))): 36864 outputs
    hipLaunchKernelGGL(spikepsppool_kernel, dim3(36864 / 16), dim3(512), 0, stream,
                       B, A, HQ, rk, 16, 24, 24);
    // p2 = psp(spike(o1)): 36864 series
    hipLaunchKernelGGL((spikepsp_kernel<true>), dim3(36864 / 64), dim3(512), 0, stream,
                       A, B, HQ, rk, 36864);
    // c2 = conv2(p2): (4,32,24,24,200)
    hipLaunchKernelGGL((conv3_kernel<16, 8>), dim3(576 / 4, 4, 4), dim3(256), 0, stream,
                       B, wt2, C, 32, 24, 24);
    // o2 = pool(psp(spike(c2))): 18432 outputs
    hipLaunchKernelGGL(spikepsppool_kernel, dim3(18432 / 16), dim3(512), 0, stream,
                       C, A, HQ, rk, 32, 12, 12);
    // p4 = psp(spike(o2)): 18432 series
    hipLaunchKernelGGL((spikepsp_kernel<true>), dim3(18432 / 64), dim3(512), 0, stream,
                       A, B, HQ, rk, 18432);
    // c3 = conv3(p4): (4,64,12,12,200)
    hipLaunchKernelGGL((conv3_kernel<32, 8>), dim3(144 / 4, 8, 4), dim3(256), 0, stream,
                       B, wt3, C, 64, 12, 12);
    // o3 = pool(psp(spike(c3))): 9216 outputs
    hipLaunchKernelGGL(spikepsppool_kernel, dim3(9216 / 16), dim3(512), 0, stream,
                       C, A, HQ, rk, 64, 6, 6);
    // p6 = psp(spike(o3)): 9216 series
    hipLaunchKernelGGL((spikepsp_kernel<true>), dim3(9216 / 64), dim3(512), 0, stream,
                       A, B, HQ, rk, 9216);
    // c4 = conv4(p6): (4,64,6,6,200)
    hipLaunchKernelGGL((conv3_kernel<64, 4>), dim3(36 / 4, 16, 4), dim3(256), 0, stream,
                       B, wt4, C, 64, 6, 6);
    // p7 = psp(spike(c4)): 9216 series
    hipLaunchKernelGGL((spikepsp_kernel<true>), dim3(9216 / 64), dim3(512), 0, stream,
                       C, B, HQ, rk, 9216);
    // fc: (4,10,200) — block per (b, 8-t chunk)
    hipLaunchKernelGGL(fc_kernel, dim3(4, 25), dim3(64), 0, stream, B, Wfc, A);
    // final spike -> d_out: 40 series
    hipLaunchKernelGGL(spike_kernel, dim3(1), dim3(256), 0, stream, A, outp, rk, 40);
    (void)in_sizes; (void)n_in; (void)out_size; (void)ws_size;
}

// Round 10
// 674.827 us; speedup vs baseline: 4.5431x; 1.0456x over previous
//
#include <hip/hip_runtime.h>
#include <math.h>

// ---------------------------------------------------------------------------
// SNN forward: psp (K=100 alpha FIR) -> conv/pool/fc -> spike (refractory scan)
// All arithmetic mirrors the JAX reference's f32 association order.
// Round 10: FIR re-grained to 8-output items (NSUB=2, 25 items) with a
// hand-balanced static wave->item table (max/avg 1.12 vs 1.35) and 6.5%
// less zero-pad waste.  fc LDS flipped t-major so the m-chain uses b128
// reads (576 vs 2304 LDS issues).  All math orders unchanged (bit-exact).
// ---------------------------------------------------------------------------

#define THETA 10.0f
#define RSTRIDE 204   // words per series row: 200 + pad4; 16B aligned

// HQ[i] = h[i-15] for 15<=i<=114 (h[k] = (k/10)*exp(1-k/10)), else 0. 144 entries.
// rk[i] = REF_KERNEL[i+1] = (-40*(i+1))*exp(1-(i+1)),  i=0..14
// wtN = transposed weights: wt[(ci*K*K + tap)*Co + co] = W[co][ci][tap]
__global__ void prep_kernel(const float* __restrict__ W1, const float* __restrict__ W2,
                            const float* __restrict__ W3, const float* __restrict__ W4,
                            float* HQ, float* rk,
                            float* wt1, float* wt2, float* wt3, float* wt4) {
    int i = blockIdx.x * 256 + threadIdx.x;
    if (i < 144) {
        int k = i - 15;
        float val = 0.0f;
        if (k >= 0 && k <= 99) {
            float tf = (float)k;
            float x = tf / 10.0f;
            val = x * (float)exp((double)(1.0f - x));   // same expr as prior rounds
        }
        HQ[i] = val;
    } else if (i < 160) {
        int j = i - 144;
        if (j < 15) {
            float t = (float)(j + 1);
            rk[j] = (-40.0f * t) * (float)exp((double)(1.0f - t));
        }
    } else if (i < 960) {            // W1: 16 x 50
        int j = i - 160, co = j / 50, tp = j % 50;
        wt1[tp * 16 + co] = W1[j];
    } else if (i < 5568) {           // W2: 32 x 144
        int j = i - 960, co = j / 144, tp = j % 144;
        wt2[tp * 32 + co] = W2[j];
    } else if (i < 24000) {          // W3: 64 x 288
        int j = i - 5568, co = j / 288, tp = j % 288;
        wt3[tp * 64 + co] = W3[j];
    } else if (i < 60864) {          // W4: 64 x 576
        int j = i - 24000, co = j / 576, tp = j % 576;
        wt4[tp * 64 + co] = W4[j];
    }
}

// 16-FMA inner step, order identical to round 1 (qw,qz,qy,qx; k ascending
// per accumulator).  hA = coeff base vector, hB = next vector.
#define FIR_STEP(A0, A1, A2, A3, qx, qy, qz, qw, hA, hB)  \
    A0 = fmaf(hA.x, qw, A0);                              \
    A1 = fmaf(hA.y, qw, A1);                              \
    A2 = fmaf(hA.z, qw, A2);                              \
    A3 = fmaf(hA.w, qw, A3);                              \
    A0 = fmaf(hA.y, qz, A0);                              \
    A1 = fmaf(hA.z, qz, A1);                              \
    A2 = fmaf(hA.w, qz, A2);                              \
    A3 = fmaf(hB.x, qz, A3);                              \
    A0 = fmaf(hA.z, qy, A0);                              \
    A1 = fmaf(hA.w, qy, A1);                              \
    A2 = fmaf(hB.x, qy, A2);                              \
    A3 = fmaf(hB.y, qy, A3);                              \
    A0 = fmaf(hA.w, qx, A0);                              \
    A1 = fmaf(hB.x, qx, A1);                              \
    A2 = fmaf(hB.y, qx, A2);                              \
    A3 = fmaf(hB.z, qx, A3);

// 4 sequential scan steps on a float4 (ascending t), identical math.
#define SCAN4(XV, p, rk)                                          \
    {                                                             \
        float u_, sv_;                                            \
        u_ = XV.x + p[0]; sv_ = (u_ >= THETA) ? 1.0f : 0.0f;      \
        XV.x = sv_;                                               \
        _Pragma("unroll")                                         \
        for (int i_ = 0; i_ < 14; ++i_) p[i_] = fmaf(sv_, rk[i_], p[i_ + 1]); \
        p[14] = sv_ * rk[14];                                     \
        u_ = XV.y + p[0]; sv_ = (u_ >= THETA) ? 1.0f : 0.0f;      \
        XV.y = sv_;                                               \
        _Pragma("unroll")                                         \
        for (int i_ = 0; i_ < 14; ++i_) p[i_] = fmaf(sv_, rk[i_], p[i_ + 1]); \
        p[14] = sv_ * rk[14];                                     \
        u_ = XV.z + p[0]; sv_ = (u_ >= THETA) ? 1.0f : 0.0f;      \
        XV.z = sv_;                                               \
        _Pragma("unroll")                                         \
        for (int i_ = 0; i_ < 14; ++i_) p[i_] = fmaf(sv_, rk[i_], p[i_ + 1]); \
        p[14] = sv_ * rk[14];                                     \
        u_ = XV.w + p[0]; sv_ = (u_ >= THETA) ? 1.0f : 0.0f;      \
        XV.w = sv_;                                               \
        _Pragma("unroll")                                         \
        for (int i_ = 0; i_ < 14; ++i_) p[i_] = fmaf(sv_, rk[i_], p[i_ + 1]); \
        p[14] = sv_ * rk[14];                                     \
    }

// ---------------------------------------------------------------------------
// FIR item (8 outputs at t0=8*id): per j one b128 tile read + 32 FMA.
// Window: A=HQ4[j+2], B=HQ4[j+3], C=HQ4[j+4]; d=0 uses (A,B), d=1 uses (B,C).
// Out-of-range taps hit HQ zeros -> exact no-ops (all operands >= +0).
// jend = min(2*id,25)+1 covers both chunks exactly.
// ---------------------------------------------------------------------------
__device__ __forceinline__ void fir_run2(const float* __restrict__ row,
                                         const float4* __restrict__ HQ4,
                                         int t0, int jend, float4 (&acc)[2]) {
    float4 A = HQ4[2], B = HQ4[3], C = HQ4[4];
    const float* bp = row + t0 + 4;
    for (int j = 0; j <= jend; ++j) {
        const float4 qv = *reinterpret_cast<const float4*>(bp);
        const float4 N = HQ4[j + 5];
        FIR_STEP(acc[0].x, acc[0].y, acc[0].z, acc[0].w,
                 qv.x, qv.y, qv.z, qv.w, A, B)
        FIR_STEP(acc[1].x, acc[1].y, acc[1].z, acc[1].w,
                 qv.x, qv.y, qv.z, qv.w, B, C)
        A = B; B = C; C = N;
        bp -= 4;
    }
}

// Balanced wave->item table (item id i has min(2i,25)+2 j-iters; wave sums
// 60..71 vs avg 63.3).  -1 = no item.
__device__ static const signed char FIR_ITEMS[8][4] = {
    {24, 12, 8, -1}, {22, 21, 4, -1}, {20, 19, 3, -1}, {18, 17, 2, -1},
    {16, 15, 1, 0},  {13, 11, 5, -1}, {14, 10, 6, -1}, {23, 9, 7, -1}};

// ---------------------------------------------------------------------------
// Fused [spike ->] psp.  Block = 64 series x 8 waves, LDS tile [64][204].
// ---------------------------------------------------------------------------
template <bool SCAN>
__global__ __launch_bounds__(512) void spikepsp_kernel(const float* __restrict__ in,
                                                       float* __restrict__ out,
                                                       const float* __restrict__ HQ,
                                                       const float* __restrict__ rkt,
                                                       int n) {
    __shared__ __align__(16) float tile[64 * RSTRIDE];
    const int l = threadIdx.x & 63;
    const int w = threadIdx.x >> 6;
    const int s0 = blockIdx.x * 64;
    for (int i = threadIdx.x; i < 3200; i += 512) {
        const int slot = i / 50, q = i - slot * 50;
        const int ser = s0 + slot;
        float4 v = make_float4(0.f, 0.f, 0.f, 0.f);
        if (ser < n) v = *reinterpret_cast<const float4*>(in + (long)ser * 200 + 4 * q);
        *reinterpret_cast<float4*>(&tile[slot * RSTRIDE + 4 * q]) = v;
    }
    __syncthreads();
    if (SCAN) {
        if (w == 0) {
            float rk[15];
            #pragma unroll
            for (int i = 0; i < 15; ++i) rk[i] = rkt[i];
            float p[15];
            #pragma unroll
            for (int i = 0; i < 15; ++i) p[i] = 0.0f;
            float* row = tile + l * RSTRIDE;
            for (int tq = 0; tq < 50; ++tq) {
                float4 xv = *reinterpret_cast<const float4*>(&row[4 * tq]);
                SCAN4(xv, p, rk)
                *reinterpret_cast<float4*>(&row[4 * tq]) = xv;
            }
        }
        __syncthreads();
    }
    const bool valid = (s0 + l) < n;
    const float* row = tile + l * RSTRIDE;
    const float4* HQ4 = reinterpret_cast<const float4*>(HQ);
    float* op = out + (long)(s0 + l) * 200;
    #pragma unroll
    for (int k = 0; k < 4; ++k) {
        const int id = FIR_ITEMS[w][k];
        if (id < 0) break;
        const int t0 = 8 * id;
        const int jend = ((2 * id < 25) ? 2 * id : 25) + 1;
        float4 acc[2];
        acc[0] = make_float4(0.f, 0.f, 0.f, 0.f);
        acc[1] = make_float4(0.f, 0.f, 0.f, 0.f);
        fir_run2(row, HQ4, t0, jend, acc);
        if (valid) {
            *reinterpret_cast<float4*>(op + t0) = acc[0];
            *reinterpret_cast<float4*>(op + t0 + 4) = acc[1];
        }
    }
}

// ---------------------------------------------------------------------------
// Fused spike -> psp -> 2x2 sum-pool (*11).  Block = 16 outputs = 64 input
// series (slot = 4*oi + pixel), 8 waves.  Pool combine = in-order quad
// shuffle sum ((p0+p1)+p2)+p3 then *11 — bit-identical to unfused.
// ---------------------------------------------------------------------------
__global__ __launch_bounds__(512) void spikepsppool_kernel(const float* __restrict__ in,
                                                           float* __restrict__ out,
                                                           const float* __restrict__ HQ,
                                                           const float* __restrict__ rkt,
                                                           int C, int HO, int WO) {
    __shared__ __align__(16) float tile[64 * RSTRIDE];
    __shared__ int sbase[64];
    const int l = threadIdx.x & 63;
    const int w = threadIdx.x >> 6;
    const int o0 = blockIdx.x * 16;
    const int H = 2 * HO, W = 2 * WO;
    if (threadIdx.x < 64) {
        const int oi = threadIdx.x >> 2, p = threadIdx.x & 3;
        const int o = o0 + oi;
        const int wo = o % WO; int tmp = o / WO;
        const int ho = tmp % HO; tmp /= HO;
        const int c = tmp % C; const int b = tmp / C;
        sbase[threadIdx.x] = ((b * C + c) * H + 2 * ho + (p >> 1)) * W + 2 * wo + (p & 1);
    }
    __syncthreads();
    for (int i = threadIdx.x; i < 3200; i += 512) {
        const int slot = i / 50, q = i - slot * 50;
        const float4 v = *reinterpret_cast<const float4*>(in + (long)sbase[slot] * 200 + 4 * q);
        *reinterpret_cast<float4*>(&tile[slot * RSTRIDE + 4 * q]) = v;
    }
    __syncthreads();
    if (w == 0) {
        float rk[15];
        #pragma unroll
        for (int i = 0; i < 15; ++i) rk[i] = rkt[i];
        float p[15];
        #pragma unroll
        for (int i = 0; i < 15; ++i) p[i] = 0.0f;
        float* row = tile + l * RSTRIDE;
        for (int tq = 0; tq < 50; ++tq) {
            float4 xv = *reinterpret_cast<const float4*>(&row[4 * tq]);
            SCAN4(xv, p, rk)
            *reinterpret_cast<float4*>(&row[4 * tq]) = xv;
        }
    }
    __syncthreads();
    const int qb = l & ~3;
    const float* row = tile + l * RSTRIDE;
    const float4* HQ4 = reinterpret_cast<const float4*>(HQ);
    float* op = out + (long)(o0 + (l >> 2)) * 200;
    auto qsum = [&](float v) -> float {
        const float v0 = __shfl(v, qb + 0);
        const float v1 = __shfl(v, qb + 1);
        const float v2 = __shfl(v, qb + 2);
        const float v3 = __shfl(v, qb + 3);
        return (((v0 + v1) + v2) + v3) * 11.0f;
    };
    #pragma unroll
    for (int k = 0; k < 4; ++k) {
        const int id = FIR_ITEMS[w][k];
        if (id < 0) break;
        const int t0 = 8 * id;
        const int jend = ((2 * id < 25) ? 2 * id : 25) + 1;
        float4 acc[2];
        acc[0] = make_float4(0.f, 0.f, 0.f, 0.f);
        acc[1] = make_float4(0.f, 0.f, 0.f, 0.f);
        fir_run2(row, HQ4, t0, jend, acc);
        #pragma unroll
        for (int d = 0; d < 2; ++d) {
            float4 r;
            r.x = qsum(acc[d].x); r.y = qsum(acc[d].y);
            r.z = qsum(acc[d].z); r.w = qsum(acc[d].w);
            if ((l & 3) == 0)
                *reinterpret_cast<float4*>(op + t0 + 4 * d) = r;
        }
    }
}

// ---------------------------------------------------------------------------
// conv1 (K=5): float4-of-t, transposed weights, 16 co accumulators.
// ---------------------------------------------------------------------------
template <int K, int PAD, int CI, int COG>
__global__ __launch_bounds__(256) void conv_kernel(const float* __restrict__ x,
                                                   const float* __restrict__ wt,
                                                   float* __restrict__ out,
                                                   int Co, int H, int W,
                                                   int HO, int WO) {
    const int l = threadIdx.x & 63;
    const int wv = threadIdx.x >> 6;
    if (l >= 50) return;
    const int p = blockIdx.x * 4 + wv;
    const int wo = p % WO, ho = p / WO;
    const int co0 = blockIdx.y * COG;
    const int b = blockIdx.z;
    const int t0 = l * 4;
    float4 acc[COG];
    #pragma unroll
    for (int c = 0; c < COG; ++c) acc[c] = make_float4(0.f, 0.f, 0.f, 0.f);
    const float* xb = x + ((long)b * CI * H * W) * 200 + t0;
    for (int ci = 0; ci < CI; ++ci) {
        #pragma unroll
        for (int kh = 0; kh < K; ++kh) {
            const int hi = ho + kh - PAD;
            if (hi < 0 || hi >= H) continue;
            #pragma unroll
            for (int kw = 0; kw < K; ++kw) {
                const int wi = wo + kw - PAD;
                if (wi < 0 || wi >= W) continue;
                const float4 v = *reinterpret_cast<const float4*>(
                    xb + ((long)(ci * H + hi) * W + wi) * 200);
                const float* wp = wt + ((ci * K + kh) * K + kw) * Co + co0;
                #pragma unroll
                for (int c = 0; c < COG; ++c) {
                    const float wv_ = wp[c];
                    acc[c].x = fmaf(wv_, v.x, acc[c].x);
                    acc[c].y = fmaf(wv_, v.y, acc[c].y);
                    acc[c].z = fmaf(wv_, v.z, acc[c].z);
                    acc[c].w = fmaf(wv_, v.w, acc[c].w);
                }
            }
        }
    }
    const long hwN = (long)HO * WO;
    const long ob = ((long)(b * Co + co0) * HO + ho) * WO + wo;
    #pragma unroll
    for (int c = 0; c < COG; ++c)
        *reinterpret_cast<float4*>(out + (ob + c * hwN) * 200 + t0) = acc[c];
}

// ---------------------------------------------------------------------------
// K=3 convs: ci-software-pipelined, zero-filled OOB taps (bit-exact).
// ---------------------------------------------------------------------------
template <int CI, int COG>
__global__ __launch_bounds__(256) void conv3_kernel(const float* __restrict__ x,
                                                    const float* __restrict__ wt,
                                                    float* __restrict__ out,
                                                    int Co, int H, int W) {
    const int l = threadIdx.x & 63;
    const int wv = threadIdx.x >> 6;
    if (l >= 50) return;
    const int p = blockIdx.x * 4 + wv;
    const int wo = p % W, ho = p / W;
    const int co0 = blockIdx.y * COG;
    const int b = blockIdx.z;
    const int t0 = l * 4;
    float4 acc[COG];
    #pragma unroll
    for (int c = 0; c < COG; ++c) acc[c] = make_float4(0.f, 0.f, 0.f, 0.f);

    bool vm[9];
    #pragma unroll
    for (int i = 0; i < 9; ++i) {
        const int hi = ho + i / 3 - 1, wi = wo + i % 3 - 1;
        vm[i] = (hi >= 0) && (hi < H) && (wi >= 0) && (wi < W);
    }
    const long cis = (long)H * W * 200;
    const float* pb = x + (long)b * CI * cis + ((long)(ho - 1) * W + (wo - 1)) * 200 + t0;

    float4 bufA[9], bufB[9];
    auto ld = [&](int ci, float4 (&B)[9]) {
        const float* pc = pb + ci * cis;
        #pragma unroll
        for (int i = 0; i < 9; ++i) {
            B[i] = vm[i] ? *reinterpret_cast<const float4*>(pc + ((i / 3) * W + (i % 3)) * 200)
                         : make_float4(0.f, 0.f, 0.f, 0.f);
        }
    };
    auto fm = [&](const float4 (&B)[9], int ci) {
        #pragma unroll
        for (int i = 0; i < 9; ++i) {
            const float* wp = wt + (ci * 9 + i) * Co + co0;
            #pragma unroll
            for (int c = 0; c < COG; ++c) {
                const float wv_ = wp[c];
                acc[c].x = fmaf(wv_, B[i].x, acc[c].x);
                acc[c].y = fmaf(wv_, B[i].y, acc[c].y);
                acc[c].z = fmaf(wv_, B[i].z, acc[c].z);
                acc[c].w = fmaf(wv_, B[i].w, acc[c].w);
            }
        }
    };

    ld(0, bufA);
    #pragma unroll 1
    for (int ci = 0; ci < CI; ci += 2) {
        ld(ci + 1, bufB);
        fm(bufA, ci);
        if (ci + 2 < CI) ld(ci + 2, bufA);
        fm(bufB, ci + 1);
    }

    const long hwN = (long)H * W;
    const long ob = ((long)(b * Co + co0) * H + ho) * W + wo;
    #pragma unroll
    for (int c = 0; c < COG; ++c)
        *reinterpret_cast<float4*>(out + (ob + c * hwN) * 200 + t0) = acc[c];
}

// ---------------------------------------------------------------------------
// Standalone spike scan (only the tiny final fc->spike uses this now).
// ---------------------------------------------------------------------------
__global__ __launch_bounds__(256) void spike_kernel(const float* __restrict__ v,
                                                    float* __restrict__ s,
                                                    const float* __restrict__ rkt,
                                                    int n) {
    const int nid = blockIdx.x * 256 + threadIdx.x;
    if (nid >= n) return;
    float rk[15];
    #pragma unroll
    for (int i = 0; i < 15; ++i) rk[i] = rkt[i];
    float p[15];
    #pragma unroll
    for (int i = 0; i < 15; ++i) p[i] = 0.0f;
    const float* vp = v + (long)nid * 200;
    float* sp = s + (long)nid * 200;
    for (int t = 0; t < 200; ++t) {
        const float u = vp[t] + p[0];
        const float sv = (u >= THETA) ? 1.0f : 0.0f;
        sp[t] = sv;
        #pragma unroll
        for (int i = 0; i < 14; ++i) p[i] = fmaf(sv, rk[i], p[i + 1]);
        p[14] = sv * rk[14];
    }
}

// ---------------------------------------------------------------------------
// FC: out[b,k,t] = sum_m x[b,m,t] * Wfc[k,m], m ascending (2304) — chain
// order unchanged (bit-exact).  LDS t-major xs[q][2308]: lane (k,q) reads
// 4 m's per ds_read_b128 (576 LDS issues vs 2304).  80 active lanes/block.
// ---------------------------------------------------------------------------
__global__ __launch_bounds__(128) void fc_kernel(const float* __restrict__ x,
                                                 const float* __restrict__ wf,
                                                 float* __restrict__ out) {
    __shared__ __align__(16) float xs[8 * 2308];
    const int b = blockIdx.x;          // 4
    const int t0 = blockIdx.y * 8;     // 25 chunks
    const int tid = threadIdx.x;
    const float* xb = x + (long)b * 2304 * 200 + t0;
    for (int i = tid; i < 4608; i += 128) {
        const int m = i >> 1, qh = (i & 1) * 4;
        const float4 v = *reinterpret_cast<const float4*>(xb + (long)m * 200 + qh);
        xs[(qh + 0) * 2308 + m] = v.x;
        xs[(qh + 1) * 2308 + m] = v.y;
        xs[(qh + 2) * 2308 + m] = v.z;
        xs[(qh + 3) * 2308 + m] = v.w;
    }
    __syncthreads();
    if (tid < 80) {
        const int k = tid >> 3, q = tid & 7;
        float a = 0.0f;
        const float* wp = wf + k * 2304;
        const float* xp = xs + q * 2308;
        for (int m4 = 0; m4 < 2304; m4 += 4) {
            const float4 xv = *reinterpret_cast<const float4*>(xp + m4);
            const float4 wv = *reinterpret_cast<const float4*>(wp + m4);
            a = fmaf(wv.x, xv.x, a);
            a = fmaf(wv.y, xv.y, a);
            a = fmaf(wv.z, xv.z, a);
            a = fmaf(wv.w, xv.w, a);
        }
        out[((long)b * 10 + k) * 200 + t0 + q] = a;
    }
}

extern "C" void kernel_launch(void* const* d_in, const int* in_sizes, int n_in,
                              void* d_out, int out_size, void* d_ws, size_t ws_size,
                              hipStream_t stream) {
    const float* x_in = (const float*)d_in[0];  // (4,2,50,50,200)
    const float* W1 = (const float*)d_in[1];    // (16,2,5,5)
    const float* W2 = (const float*)d_in[2];    // (32,16,3,3)
    const float* W3 = (const float*)d_in[3];    // (64,32,3,3)
    const float* W4 = (const float*)d_in[4];    // (64,64,3,3)
    const float* Wfc = (const float*)d_in[5];   // (10,64,6,6)
    float* outp = (float*)d_out;                // (4,10,200)

    float* ws = (float*)d_ws;
    float* HQ  = ws;                  // 144 (16B aligned)
    float* rk  = ws + 144;            // 15 (+1 pad)
    float* wt1 = ws + 160;            // 800
    float* wt2 = wt1 + 800;           // 4608
    float* wt3 = wt2 + 4608;          // 18432
    float* wt4 = wt3 + 18432;         // 36864
    float* A   = wt4 + 36864;         // 7,372,800
    float* B   = A + 7372800;         // 29,491,200
    float* C   = B + 29491200;        // 14,745,600

    hipLaunchKernelGGL(prep_kernel, dim3(238), dim3(256), 0, stream,
                       W1, W2, W3, W4, HQ, rk, wt1, wt2, wt3, wt4);

    // p0 = psp(input): 20000 series (no scan)
    hipLaunchKernelGGL((spikepsp_kernel<false>), dim3(313), dim3(512), 0, stream,
                       x_in, A, HQ, rk, 20000);
    // c1 = conv1(p0): (4,16,48,48,200)
    hipLaunchKernelGGL((conv_kernel<5, 1, 2, 16>), dim3(2304 / 4, 1, 4), dim3(256), 0, stream,
                       A, wt1, B, 16, 50, 50, 48, 48);
    // o1 = pool(psp(spike(c1))): 36864 outputs
    hipLaunchKernelGGL(spikepsppool_kernel, dim3(36864 / 16), dim3(512), 0, stream,
                       B, A, HQ, rk, 16, 24, 24);
    // p2 = psp(spike(o1)): 36864 series
    hipLaunchKernelGGL((spikepsp_kernel<true>), dim3(36864 / 64), dim3(512), 0, stream,
                       A, B, HQ, rk, 36864);
    // c2 = conv2(p2): (4,32,24,24,200)
    hipLaunchKernelGGL((conv3_kernel<16, 8>), dim3(576 / 4, 4, 4), dim3(256), 0, stream,
                       B, wt2, C, 32, 24, 24);
    // o2 = pool(psp(spike(c2))): 18432 outputs
    hipLaunchKernelGGL(spikepsppool_kernel, dim3(18432 / 16), dim3(512), 0, stream,
                       C, A, HQ, rk, 32, 12, 12);
    // p4 = psp(spike(o2)): 18432 series
    hipLaunchKernelGGL((spikepsp_kernel<true>), dim3(18432 / 64), dim3(512), 0, stream,
                       A, B, HQ, rk, 18432);
    // c3 = conv3(p4): (4,64,12,12,200)
    hipLaunchKernelGGL((conv3_kernel<32, 8>), dim3(144 / 4, 8, 4), dim3(256), 0, stream,
                       B, wt3, C, 64, 12, 12);
    // o3 = pool(psp(spike(c3))): 9216 outputs
    hipLaunchKernelGGL(spikepsppool_kernel, dim3(9216 / 16), dim3(512), 0, stream,
                       C, A, HQ, rk, 64, 6, 6);
    // p6 = psp(spike(o3)): 9216 series
    hipLaunchKernelGGL((spikepsp_kernel<true>), dim3(9216 / 64), dim3(512), 0, stream,
                       A, B, HQ, rk, 9216);
    // c4 = conv4(p6): (4,64,6,6,200)
    hipLaunchKernelGGL((conv3_kernel<64, 4>), dim3(36 / 4, 16, 4), dim3(256), 0, stream,
                       B, wt4, C, 64, 6, 6);
    // p7 = psp(spike(c4)): 9216 series
    hipLaunchKernelGGL((spikepsp_kernel<true>), dim3(9216 / 64), dim3(512), 0, stream,
                       C, B, HQ, rk, 9216);
    // fc: (4,10,200) — block per (b, 8-t chunk), 128 threads
    hipLaunchKernelGGL(fc_kernel, dim3(4, 25), dim3(128), 0, stream, B, Wfc, A);
    // final spike -> d_out: 40 series
    hipLaunchKernelGGL(spike_kernel, dim3(1), dim3(256), 0, stream, A, outp, rk, 40);
    (void)in_sizes; (void)n_in; (void)out_size; (void)ws_size;
}